// Round 7
// baseline (391.130 us; speedup 1.0000x reference)
//
#include <hip/hip_runtime.h>
#include <stdint.h>

#define B_     8
#define LQ_    4096
#define S_     77
#define SP_    80
#define D_     1024
#define H_     16
#define HD_    64
#define NC_    1280   // H_*SP_
#define NSUBJ_ 32

typedef __attribute__((ext_vector_type(4))) float  f4;
typedef __attribute__((ext_vector_type(8))) short  short8;
typedef __attribute__((ext_vector_type(8))) unsigned short us8;
typedef __attribute__((ext_vector_type(4))) unsigned short us4;

__device__ __forceinline__ unsigned short f2bf(float f) {
  union { float f; unsigned u; } x; x.f = f;
  unsigned r = x.u + 0x7FFFu + ((x.u >> 16) & 1u);
  return (unsigned short)(r >> 16);
}

__device__ __forceinline__ void gload16(const void* g, void* s) {
  __builtin_amdgcn_global_load_lds((const __attribute__((address_space(1))) void*)g,
                                   (__attribute__((address_space(3))) void*)s, 16, 0, 0);
}

// ---------------- hssum partials + hs -> bf16 convert ----------------
__global__ __launch_bounds__(256) void k_hssum(const float* __restrict__ hs,
                                               float* __restrict__ part,
                                               unsigned short* __restrict__ hsb) {
  int b = blockIdx.y;
  size_t base = ((size_t)b * LQ_ + (size_t)blockIdx.x * 64) * D_ + threadIdx.x * 4;
  f4 acc = {0.f, 0.f, 0.f, 0.f};
  for (int l = 0; l < 64; ++l) {
    f4 v = *(const f4*)(hs + base + (size_t)l * D_);
    acc += v;
    if (hsb) {
      us4 o;
#pragma unroll
      for (int j = 0; j < 4; ++j) o[j] = f2bf(v[j]);
      *(us4*)(hsb + base + (size_t)l * D_) = o;
    }
  }
  *(f4*)(part + (size_t)blockIdx.x * (B_ * D_) + b * D_ + threadIdx.x * 4) = acc;
}

__global__ __launch_bounds__(256) void k_hsred(const float* __restrict__ part,
                                               float* __restrict__ hssum) {
  int i = blockIdx.x * 256 + threadIdx.x;   // [0, 8192)
  float s = 0.f;
  for (int x = 0; x < 64; ++x) s += part[(size_t)x * (B_ * D_) + i];
  hssum[i] = s;
}

// ---------------- 2 transposes (Wq 1024x1024, Ao 192x1024) in one launch ----------------
__global__ __launch_bounds__(256) void k_tr2(const float* __restrict__ Wq, const float* __restrict__ Ao,
                                             float* __restrict__ wqT, float* __restrict__ aoT) {
  int z = blockIdx.z;
  const float* in = z == 0 ? Wq : Ao;
  float* out = z == 0 ? wqT : aoT;
  int R = z == 0 ? 1024 : 192;
  const int C = 1024;
  int c0 = blockIdx.x * 32, r0 = blockIdx.y * 32;
  if (r0 >= R) return;
  __shared__ float tile[32][33];
  int tx = threadIdx.x & 31, ty = threadIdx.x >> 5;
#pragma unroll
  for (int k = 0; k < 4; ++k)
    tile[ty + 8 * k][tx] = in[(size_t)(r0 + ty + 8 * k) * C + c0 + tx];
  __syncthreads();
#pragma unroll
  for (int k = 0; k < 4; ++k)
    out[(size_t)(c0 + ty + 8 * k) * R + r0 + tx] = tile[tx][ty + 8 * k];
}

// ---------------- shared 64x64-tile GEMM body: C = alpha*(A @ Bt^T) [+ Dm] ----------------
template <bool OBF>
__device__ __forceinline__ void gemm64_body(
    const float* __restrict__ A, int lda, const float* __restrict__ Bt, int ldb,
    void* __restrict__ Cv, int ldc, long cbase, const float* __restrict__ Dm, int ldd,
    int M, int Mv, int N, int K, float alpha, int m0, int n0,
    short* As, short* Bs) {
  int t = threadIdx.x, lane = t & 63, wid = t >> 6;
  int wm = wid >> 1, wn = wid & 1;
  f4 acc[2][2] = {};
  int srow = t >> 2, skc = (t & 3) * 8;
  for (int k0 = 0; k0 < K; k0 += 32) {
    __syncthreads();
    f4 a0 = {0,0,0,0}, a1 = {0,0,0,0}, b0 = {0,0,0,0}, b1 = {0,0,0,0};
    if (m0 + srow < Mv) {
      const float* p = A + (size_t)(m0 + srow) * lda + k0 + skc;
      a0 = *(const f4*)p; a1 = *(const f4*)(p + 4);
    }
    if (n0 + srow < N) {
      const float* p = Bt + (size_t)(n0 + srow) * ldb + k0 + skc;
      b0 = *(const f4*)p; b1 = *(const f4*)(p + 4);
    }
    us8 ua, ub;
#pragma unroll
    for (int j = 0; j < 4; ++j) {
      ua[j] = f2bf(a0[j]); ua[4 + j] = f2bf(a1[j]);
      ub[j] = f2bf(b0[j]); ub[4 + j] = f2bf(b1[j]);
    }
    *(us8*)(As + srow * 40 + skc) = ua;
    *(us8*)(Bs + srow * 40 + skc) = ub;
    __syncthreads();
    short8 fa[2], fb[2];
#pragma unroll
    for (int i = 0; i < 2; ++i) {
      fa[i] = *(const short8*)(As + (wm * 32 + i * 16 + (lane & 15)) * 40 + (lane >> 4) * 8);
      fb[i] = *(const short8*)(Bs + (wn * 32 + i * 16 + (lane & 15)) * 40 + (lane >> 4) * 8);
    }
#pragma unroll
    for (int mi = 0; mi < 2; ++mi)
#pragma unroll
      for (int ni = 0; ni < 2; ++ni)
        acc[mi][ni] = __builtin_amdgcn_mfma_f32_16x16x32_bf16(fa[mi], fb[ni], acc[mi][ni], 0, 0, 0);
  }
#pragma unroll
  for (int mi = 0; mi < 2; ++mi)
#pragma unroll
    for (int ni = 0; ni < 2; ++ni)
#pragma unroll
      for (int j = 0; j < 4; ++j) {
        int row = m0 + wm * 32 + mi * 16 + (lane >> 4) * 4 + j;
        int col = n0 + wn * 32 + ni * 16 + (lane & 15);
        if (row < M && col < N) {
          float val = acc[mi][ni][j] * alpha;
          if (Dm) val += Dm[(size_t)row * ldd + col];
          size_t idx = (size_t)cbase + (size_t)row * ldc + col;
          if (OBF) ((unsigned short*)Cv)[idx] = f2bf(val);
          else     ((float*)Cv)[idx] = val;
        }
      }
}

template <bool OBF>
__global__ __launch_bounds__(256) void k_gemm_small(
    const float* __restrict__ A, int lda, long sA1, long sA2,
    const float* __restrict__ Bt, int ldb, long sB1, long sB2,
    void* __restrict__ Cv, int ldc, long sC1, long sC2,
    const float* __restrict__ Dm, int ldd,
    int M, int Mv, int N, int K, float alpha, int Z2) {
  int z = blockIdx.z, z1 = z / Z2, z2 = z - z1 * Z2;
  __shared__ short As[64 * 40];
  __shared__ short Bs[64 * 40];
  gemm64_body<OBF>(A + z1 * sA1 + z2 * sA2, lda, Bt + z1 * sB1 + z2 * sB2, ldb,
                   Cv, ldc, z1 * sC1 + z2 * sC2, Dm, ldd, M, Mv, N, K, alpha,
                   blockIdx.x * 64, blockIdx.y * 64, As, Bs);
}

// ---------------- eA = LS * ehs @ [Ak;Av]^T  (fp32 out [b][80][384]) ----------------
// FIX (R6 bug): pass n0=nl so gemm64_body offsets BOTH the B-rows and the
// C-columns consistently (R6 offset Bt but wrote all blocks to cols 0..63).
__global__ __launch_bounds__(256) void k_eA(const float* __restrict__ ehs,
                                            const float* __restrict__ Ak, const float* __restrict__ Av,
                                            float* __restrict__ eA, float alpha) {
  int b = blockIdx.z;
  int m0 = blockIdx.x * 64;
  int n0 = blockIdx.y * 64;            // 0..383
  bool sel = n0 >= 192;
  int nl = n0 - (sel ? 192 : 0);       // 0,64,128
  const float* Bt = sel ? Av : Ak;
  __shared__ short As[64 * 40];
  __shared__ short Bs[64 * 40];
  gemm64_body<false>(ehs + (size_t)b * S_ * D_, 1024, Bt, 1024,
                     eA + (size_t)b * 80 * 384 + (sel ? 192 : 0), 384, 0, nullptr, 0,
                     80, S_, 192, 1024, alpha, m0, nl, As, Bs);
}

// ---------------- kv = ehs @ [Wk;Wv]^T + eA_scaled @ blkdiag(Bk,Bv)^T ----------------
// out fp32 [b][80][2048]; rows 77..79 zero.
__global__ __launch_bounds__(256) void k_kv(const float* __restrict__ ehs,
                                            const float* __restrict__ Wk, const float* __restrict__ Wv,
                                            const float* __restrict__ eA,
                                            const float* __restrict__ Bk, const float* __restrict__ Bv,
                                            float* __restrict__ kvbuf) {
  int b = blockIdx.z;
  int m0 = blockIdx.x * 64, n0 = blockIdx.y * 64;   // n0 in [0,2048)
  bool vh = n0 >= 1024;
  int nl = n0 & 1023;
  const float* A1 = ehs + (size_t)b * S_ * D_;
  const float* Bt1 = (vh ? Wv : Wk) + (size_t)nl * 1024;
  const float* A2 = eA + (size_t)b * 80 * 384 + (vh ? 192 : 0);
  const float* Bt2 = (vh ? Bv : Bk) + (size_t)nl * 192;
  float* C = kvbuf + (size_t)b * 80 * 2048;

  __shared__ short As[64 * 40];
  __shared__ short Bs[64 * 40];
  int t = threadIdx.x, lane = t & 63, wid = t >> 6;
  int wm = wid >> 1, wn = wid & 1;
  f4 acc[2][2] = {};
  int srow = t >> 2, skc = (t & 3) * 8;

  // loop 1: K=1024 over (ehs, Wsel); loop 2: K=192 over (eA, Bsel)
#pragma unroll 1
  for (int pass = 0; pass < 2; ++pass) {
    const float* A = pass ? A2 : A1;
    const float* Bt = pass ? Bt2 : Bt1;
    int lda = pass ? 384 : 1024, ldb = pass ? 192 : 1024;
    int K = pass ? 192 : 1024;
    for (int k0 = 0; k0 < K; k0 += 32) {
      __syncthreads();
      f4 a0 = {0,0,0,0}, a1 = {0,0,0,0}, b0, b1;
      if (m0 + srow < S_) {
        const float* p = A + (size_t)(m0 + srow) * lda + k0 + skc;
        a0 = *(const f4*)p; a1 = *(const f4*)(p + 4);
      }
      {
        const float* p = Bt + (size_t)srow * ldb + k0 + skc;
        b0 = *(const f4*)p; b1 = *(const f4*)(p + 4);
      }
      us8 ua, ub;
#pragma unroll
      for (int j = 0; j < 4; ++j) {
        ua[j] = f2bf(a0[j]); ua[4 + j] = f2bf(a1[j]);
        ub[j] = f2bf(b0[j]); ub[4 + j] = f2bf(b1[j]);
      }
      *(us8*)(As + srow * 40 + skc) = ua;
      *(us8*)(Bs + srow * 40 + skc) = ub;
      __syncthreads();
      short8 fa[2], fb[2];
#pragma unroll
      for (int i = 0; i < 2; ++i) {
        fa[i] = *(const short8*)(As + (wm * 32 + i * 16 + (lane & 15)) * 40 + (lane >> 4) * 8);
        fb[i] = *(const short8*)(Bs + (wn * 32 + i * 16 + (lane & 15)) * 40 + (lane >> 4) * 8);
      }
#pragma unroll
      for (int mi = 0; mi < 2; ++mi)
#pragma unroll
        for (int ni = 0; ni < 2; ++ni)
          acc[mi][ni] = __builtin_amdgcn_mfma_f32_16x16x32_bf16(fa[mi], fb[ni], acc[mi][ni], 0, 0, 0);
    }
  }
#pragma unroll
  for (int mi = 0; mi < 2; ++mi)
#pragma unroll
    for (int ni = 0; ni < 2; ++ni)
#pragma unroll
      for (int j = 0; j < 4; ++j) {
        int row = m0 + wm * 32 + mi * 16 + (lane >> 4) * 4 + j;
        int col = n0 + wn * 32 + ni * 16 + (lane & 15);
        if (row < 80) C[(size_t)row * 2048 + col] = acc[mi][ni][j];
      }
}

// ---------------- mu/alpha/beta per (b,h,s), with qmean GEMM fused ----------------
__global__ void k_mubeta(const float* __restrict__ hssum, const float* __restrict__ Wq,
                         const float* __restrict__ kv,
                         const int* __restrict__ sb, const int* __restrict__ sn,
                         const float* __restrict__ csf_p,
                         float* __restrict__ alphav, float* __restrict__ betav) {
  int h = blockIdx.x, b = blockIdx.y;
  int t = threadIdx.x;                       // 128 threads
  __shared__ float qp[64];
  {
    int hd = t >> 1, half = t & 1;
    const float* wr = Wq + (size_t)(h * 64 + hd) * D_ + half * 512;
    const float* hp = hssum + b * D_ + half * 512;
    float s = 0.f;
    for (int d = 0; d < 512; d += 4) {
      f4 w = *(const f4*)(wr + d);
      f4 x = *(const f4*)(hp + d);
      s += w[0] * x[0] + w[1] * x[1] + w[2] * x[2] + w[3] * x[3];
    }
    s += __shfl_xor(s, 1, 64);
    if (half == 0) qp[hd] = s * (1.f / 4096.f);
  }
  __syncthreads();
  int s = t;
  if (s >= SP_) return;
  const float* kp = kv + ((size_t)(b * SP_ + s)) * 2048 + h * HD_;
  float mu = 0.f;
#pragma unroll 8
  for (int hd = 0; hd < HD_; ++hd) mu += qp[hd] * kp[hd];
  mu *= 0.125f;
  bool subj = false;
  for (int i = 0; i < NSUBJ_; ++i) subj = subj || (sb[i] == b && sn[i] == s);
  float csf = *csf_p;
  int c = b * NC_ + h * SP_ + s;
  alphav[c] = subj ? csf : 1.f;
  betav[c] = (s >= S_) ? -1e30f : (subj ? -mu * csf : 0.f);
}

// ---------------- big score GEMM 256x320, 8-phase, reads-before-barrier ----------------
// Tile-end vmcnt(0)+barrier proves buf[nxt] complete -> next tile's phases read
// with NO wait; per-phase ds_reads issue BEFORE the phase barrier so their
// latency overlaps barrier sync + stage issue (m196/m201 fine-interleave).
__global__ __launch_bounds__(512, 2) void k_score_big(
    const unsigned short* __restrict__ hsb, const unsigned short* __restrict__ Mt,
    const float* __restrict__ alphav, const float* __restrict__ betav,
    unsigned short* __restrict__ P) {
  extern __shared__ short lds[];
  const int ASZ = 256 * 64;   // shorts
  const int BSZ = 320 * 64;
  int id = blockIdx.x;
  int x = id & 7, idp = id >> 3;
  int nt = idp & 3;
  int pid = (idp >> 2) * 8 + x;    // [0,128)
  int b = pid >> 4, mt = pid & 15;
  int m0 = mt * 256, n0 = nt * 320;

  const unsigned short* Ab = hsb + (size_t)b * LQ_ * D_;
  const unsigned short* Bb = Mt + (size_t)b * NC_ * D_;
  const float* alp = alphav + b * NC_;
  const float* bet = betav + b * NC_;
  unsigned short* Pb = P + (size_t)b * LQ_ * NC_;

  int t = threadIdx.x, lane = t & 63, wid = t >> 6;   // 8 waves
  int wm = wid >> 2, wn = wid & 3;
  int r = lane & 15, q = lane >> 4;
  f4 acc[8][5] = {};

  auto SA = [&](int bf, int k0, int p) {
    int cb = p * 512 + wid * 64;
    int cc = cb + lane;
    int row = cc >> 3, col = ((cc & 7) ^ (row & 7)) * 8;
    gload16(Ab + (size_t)(m0 + row) * D_ + k0 + col, (char*)(lds + bf * ASZ) + cb * 16);
  };
  auto SB = [&](int bf, int k0, int p) {
    int cb = p * 512 + wid * 64;
    int cc = cb + lane;
    int row = cc >> 3, col = ((cc & 7) ^ (row & 7)) * 8;
    gload16(Bb + (size_t)(n0 + row) * D_ + k0 + col, (char*)(lds + 2 * ASZ + bf * BSZ) + cb * 16);
  };

  // prologue: tile 0 fully staged, drained, visible
#pragma unroll
  for (int p = 0; p < 4; ++p) SA(0, 0, p);
#pragma unroll
  for (int p = 0; p < 5; ++p) SB(0, 0, p);
  asm volatile("s_waitcnt vmcnt(0)" ::: "memory");
  asm volatile("s_barrier" ::: "memory");

  for (int kt = 0; kt < 16; ++kt) {
    int cur = kt & 1;
    const short* Ar = lds + cur * ASZ;
    const short* Br = lds + 2 * ASZ + cur * BSZ;
    int k1 = (kt + 1) * 64;
    bool pre = kt < 15;
    int co0 = (q ^ (lane & 7)) * 8;
    int co1 = ((4 + q) ^ (lane & 7)) * 8;
    short8 fb[5], fa[4];

    // ---- P0: reads (fb0 + fa0lo) || stage 5; barrier; MFMA lo x fb0 ----
#pragma unroll
    for (int ni = 0; ni < 5; ++ni) fb[ni] = *(const short8*)(Br + (wn * 80 + ni * 16 + r) * 64 + co0);
#pragma unroll
    for (int mi = 0; mi < 4; ++mi) fa[mi] = *(const short8*)(Ar + (wm * 128 + mi * 16 + r) * 64 + co0);
    __builtin_amdgcn_sched_barrier(0);
    if (pre) { SA(cur ^ 1, k1, 0); SA(cur ^ 1, k1, 1); SA(cur ^ 1, k1, 2); SA(cur ^ 1, k1, 3); SB(cur ^ 1, k1, 0); }
    __builtin_amdgcn_sched_barrier(0);
    __builtin_amdgcn_s_barrier();
    asm volatile("s_waitcnt lgkmcnt(0)");
    __builtin_amdgcn_s_setprio(1);
#pragma unroll
    for (int mi = 0; mi < 4; ++mi)
#pragma unroll
      for (int ni = 0; ni < 5; ++ni)
        acc[mi][ni] = __builtin_amdgcn_mfma_f32_16x16x32_bf16(fa[mi], fb[ni], acc[mi][ni], 0, 0, 0);
    __builtin_amdgcn_s_setprio(0);
    __builtin_amdgcn_s_barrier();

    // ---- P1: reads fa0hi || stage 4; MFMA hi x fb0 ----
#pragma unroll
    for (int mi = 0; mi < 4; ++mi) fa[mi] = *(const short8*)(Ar + (wm * 128 + (4 + mi) * 16 + r) * 64 + co0);
    __builtin_amdgcn_sched_barrier(0);
    if (pre) { SB(cur ^ 1, k1, 1); SB(cur ^ 1, k1, 2); SB(cur ^ 1, k1, 3); SB(cur ^ 1, k1, 4); }
    __builtin_amdgcn_sched_barrier(0);
    __builtin_amdgcn_s_barrier();
    asm volatile("s_waitcnt lgkmcnt(0)");
    __builtin_amdgcn_s_setprio(1);
#pragma unroll
    for (int mi = 0; mi < 4; ++mi)
#pragma unroll
      for (int ni = 0; ni < 5; ++ni)
        acc[4 + mi][ni] = __builtin_amdgcn_mfma_f32_16x16x32_bf16(fa[mi], fb[ni], acc[4 + mi][ni], 0, 0, 0);
    __builtin_amdgcn_s_setprio(0);
    __builtin_amdgcn_s_barrier();

    // ---- P2: reads fb1 + fa1lo; MFMA lo x fb1 ----
#pragma unroll
    for (int ni = 0; ni < 5; ++ni) fb[ni] = *(const short8*)(Br + (wn * 80 + ni * 16 + r) * 64 + co1);
#pragma unroll
    for (int mi = 0; mi < 4; ++mi) fa[mi] = *(const short8*)(Ar + (wm * 128 + mi * 16 + r) * 64 + co1);
    __builtin_amdgcn_sched_barrier(0);
    __builtin_amdgcn_s_barrier();
    asm volatile("s_waitcnt lgkmcnt(0)");
    __builtin_amdgcn_s_setprio(1);
#pragma unroll
    for (int mi = 0; mi < 4; ++mi)
#pragma unroll
      for (int ni = 0; ni < 5; ++ni)
        acc[mi][ni] = __builtin_amdgcn_mfma_f32_16x16x32_bf16(fa[mi], fb[ni], acc[mi][ni], 0, 0, 0);
    __builtin_amdgcn_s_setprio(0);
    __builtin_amdgcn_s_barrier();

    // ---- P3: reads fa1hi; MFMA hi x fb1; tile-end drain ----
#pragma unroll
    for (int mi = 0; mi < 4; ++mi) fa[mi] = *(const short8*)(Ar + (wm * 128 + (4 + mi) * 16 + r) * 64 + co1);
    __builtin_amdgcn_sched_barrier(0);
    __builtin_amdgcn_s_barrier();
    asm volatile("s_waitcnt lgkmcnt(0)");
    __builtin_amdgcn_s_setprio(1);
#pragma unroll
    for (int mi = 0; mi < 4; ++mi)
#pragma unroll
      for (int ni = 0; ni < 5; ++ni)
        acc[4 + mi][ni] = __builtin_amdgcn_mfma_f32_16x16x32_bf16(fa[mi], fb[ni], acc[4 + mi][ni], 0, 0, 0);
    __builtin_amdgcn_s_setprio(0);
    if (pre) {
      asm volatile("s_waitcnt vmcnt(0)" ::: "memory");   // buf[nxt] fully staged
      asm volatile("s_barrier" ::: "memory");            // visible to all waves
    }
  }

  // epilogue: alpha*score + beta, per-head softmax (wave owns one 80-col head)
  float al[5], be[5];
#pragma unroll
  for (int ni = 0; ni < 5; ++ni) {
    int cc = n0 + wn * 80 + ni * 16 + (lane & 15);
    al[ni] = alp[cc]; be[ni] = bet[cc];
  }
#pragma unroll
  for (int mi = 0; mi < 8; ++mi) {
#pragma unroll
    for (int j = 0; j < 4; ++j) {
      float v[5];
      float m = -3.0e38f;
#pragma unroll
      for (int ni = 0; ni < 5; ++ni) { v[ni] = acc[mi][ni][j] * al[ni] + be[ni]; m = fmaxf(m, v[ni]); }
#pragma unroll
      for (int off = 1; off < 16; off <<= 1) m = fmaxf(m, __shfl_xor(m, off, 64));
      float ssum = 0.f;
#pragma unroll
      for (int ni = 0; ni < 5; ++ni) { v[ni] = __expf(v[ni] - m); ssum += v[ni]; }
#pragma unroll
      for (int off = 1; off < 16; off <<= 1) ssum += __shfl_xor(ssum, off, 64);
      float inv = 1.f / ssum;
      int row = m0 + wm * 128 + mi * 16 + (lane >> 4) * 4 + j;
      size_t rb = (size_t)row * NC_ + n0 + wn * 80 + (lane & 15);
#pragma unroll
      for (int ni = 0; ni < 5; ++ni)
        Pb[rb + ni * 16] = f2bf(v[ni] * inv);
    }
  }
}

// ---------------- fallback score GEMM (fp32 A, reg-staged), 128x160, 256 thr ----------------
__global__ __launch_bounds__(256) void k_score_f32(
    const float* __restrict__ hs, const unsigned short* __restrict__ Mt,
    const float* __restrict__ alphav, const float* __restrict__ betav,
    unsigned short* __restrict__ P) {
  int id = blockIdx.x;
  int x = id & 7, idp = id >> 3;
  int n_t = idp & 7;
  int pid = (idp >> 3) * 8 + x;
  int b = pid >> 5, m_t = pid & 31;
  int m0 = m_t * 128, n0 = n_t * 160;
  const float* Af = hs + (size_t)b * LQ_ * D_;
  const unsigned short* Bb = Mt + (size_t)b * NC_ * D_;
  const float* alp = alphav + b * NC_;
  const float* bet = betav + b * NC_;
  unsigned short* Pb = P + (size_t)b * LQ_ * NC_;
  __shared__ short As[128 * 64];
  __shared__ short Bs[160 * 64];
  int t = threadIdx.x, lane = t & 63, wid = t >> 6;
  int wm = wid >> 1, wn = wid & 1;
  int srow = lane >> 3;
  int schunk = (lane & 7) ^ srow;
  f4 acc[4][5] = {};
  for (int k0 = 0; k0 < D_; k0 += 64) {
    __syncthreads();
    for (int i = wid; i < 20; i += 4)
      gload16(Bb + (size_t)(n0 + i * 8 + srow) * D_ + k0 + schunk * 8, (char*)Bs + i * 1024);
    int arow = t >> 3, ac = t & 7;
    int awc = ac ^ (arow & 7);
#pragma unroll
    for (int p = 0; p < 4; ++p) {
      int row = p * 32 + arow;
      const float* src = Af + (size_t)(m0 + row) * D_ + k0 + ac * 8;
      f4 v0 = *(const f4*)src;
      f4 v1 = *(const f4*)(src + 4);
      us8 u;
#pragma unroll
      for (int j = 0; j < 4; ++j) { u[j] = f2bf(v0[j]); u[4 + j] = f2bf(v1[j]); }
      *(us8*)(As + row * 64 + awc * 8) = u;
    }
    __syncthreads();
#pragma unroll
    for (int kk = 0; kk < 2; ++kk) {
      int co = ((kk * 4 + (lane >> 4)) ^ (lane & 7)) * 8;
      short8 fa[4], fb[5];
#pragma unroll
      for (int mi = 0; mi < 4; ++mi)
        fa[mi] = *(const short8*)(As + (wm * 64 + mi * 16 + (lane & 15)) * 64 + co);
#pragma unroll
      for (int ni = 0; ni < 5; ++ni)
        fb[ni] = *(const short8*)(Bs + (wn * 80 + ni * 16 + (lane & 15)) * 64 + co);
#pragma unroll
      for (int mi = 0; mi < 4; ++mi)
#pragma unroll
        for (int ni = 0; ni < 5; ++ni)
          acc[mi][ni] = __builtin_amdgcn_mfma_f32_16x16x32_bf16(fa[mi], fb[ni], acc[mi][ni], 0, 0, 0);
    }
  }
  float al[5], be[5];
#pragma unroll
  for (int ni = 0; ni < 5; ++ni) {
    int cc = n0 + wn * 80 + ni * 16 + (lane & 15);
    al[ni] = alp[cc]; be[ni] = bet[cc];
  }
#pragma unroll
  for (int mi = 0; mi < 4; ++mi) {
#pragma unroll
    for (int j = 0; j < 4; ++j) {
      float v[5];
      float m = -3.0e38f;
#pragma unroll
      for (int ni = 0; ni < 5; ++ni) { v[ni] = acc[mi][ni][j] * al[ni] + be[ni]; m = fmaxf(m, v[ni]); }
#pragma unroll
      for (int off = 1; off < 16; off <<= 1) m = fmaxf(m, __shfl_xor(m, off, 64));
      float ssum = 0.f;
#pragma unroll
      for (int ni = 0; ni < 5; ++ni) { v[ni] = __expf(v[ni] - m); ssum += v[ni]; }
#pragma unroll
      for (int off = 1; off < 16; off <<= 1) ssum += __shfl_xor(ssum, off, 64);
      float inv = 1.f / ssum;
      int row = m0 + wm * 64 + mi * 16 + (lane >> 4) * 4 + j;
      size_t rb = (size_t)row * NC_ + n0 + wn * 80 + (lane & 15);
#pragma unroll
      for (int ni = 0; ni < 5; ++ni)
        Pb[rb + ni * 16] = f2bf(v[ni] * inv);
    }
  }
}

// ---------------- big out GEMM 256x256, 8-phase, reads-before-barrier ----------------
__global__ __launch_bounds__(512, 2) void k_out_big(
    const unsigned short* __restrict__ P, const unsigned short* __restrict__ Ut,
    const float* __restrict__ bo, float* __restrict__ out) {
  extern __shared__ short lds[];
  const int ASZ = 256 * 64;
  int id = blockIdx.x;
  int x = id & 7, idp = id >> 3;
  int nt = idp & 3;
  int pid = (idp >> 2) * 8 + x;
  int b = pid >> 4, mt = pid & 15;
  int m0 = mt * 256, n0 = nt * 256;

  const unsigned short* Ab = P + (size_t)b * LQ_ * NC_;
  const unsigned short* Bb = Ut + (size_t)b * D_ * NC_;
  float* ob = out + (size_t)b * LQ_ * D_;

  int t = threadIdx.x, lane = t & 63, wid = t >> 6;
  int wm = wid >> 2, wn = wid & 3;
  int r = lane & 15, q = lane >> 4;
  f4 acc[8][4] = {};
  const int T = NC_ / 64;   // 20

  auto SA = [&](int bf, int k0, int p) {
    int cb = p * 512 + wid * 64;
    int cc = cb + lane;
    int row = cc >> 3, col = ((cc & 7) ^ (row & 7)) * 8;
    gload16(Ab + (size_t)(m0 + row) * NC_ + k0 + col, (char*)(lds + bf * ASZ) + cb * 16);
  };
  auto SB = [&](int bf, int k0, int p) {
    int cb = p * 512 + wid * 64;
    int cc = cb + lane;
    int row = cc >> 3, col = ((cc & 7) ^ (row & 7)) * 8;
    gload16(Bb + (size_t)(n0 + row) * NC_ + k0 + col, (char*)(lds + 2 * ASZ + bf * ASZ) + cb * 16);
  };

#pragma unroll
  for (int p = 0; p < 4; ++p) SA(0, 0, p);
#pragma unroll
  for (int p = 0; p < 4; ++p) SB(0, 0, p);
  asm volatile("s_waitcnt vmcnt(0)" ::: "memory");
  asm volatile("s_barrier" ::: "memory");

  for (int kt = 0; kt < T; ++kt) {
    int cur = kt & 1;
    const short* Ar = lds + cur * ASZ;
    const short* Br = lds + 2 * ASZ + cur * ASZ;
    int k1 = (kt + 1) * 64;
    bool pre = kt + 1 < T;
    int co0 = (q ^ (lane & 7)) * 8;
    int co1 = ((4 + q) ^ (lane & 7)) * 8;
    short8 fb[4], fa[4];

    // ---- P0 ----
#pragma unroll
    for (int ni = 0; ni < 4; ++ni) fb[ni] = *(const short8*)(Br + (wn * 64 + ni * 16 + r) * 64 + co0);
#pragma unroll
    for (int mi = 0; mi < 4; ++mi) fa[mi] = *(const short8*)(Ar + (wm * 128 + mi * 16 + r) * 64 + co0);
    __builtin_amdgcn_sched_barrier(0);
    if (pre) { SA(cur ^ 1, k1, 0); SA(cur ^ 1, k1, 1); SA(cur ^ 1, k1, 2); SA(cur ^ 1, k1, 3); }
    __builtin_amdgcn_sched_barrier(0);
    __builtin_amdgcn_s_barrier();
    asm volatile("s_waitcnt lgkmcnt(0)");
    __builtin_amdgcn_s_setprio(1);
#pragma unroll
    for (int mi = 0; mi < 4; ++mi)
#pragma unroll
      for (int ni = 0; ni < 4; ++ni)
        acc[mi][ni] = __builtin_amdgcn_mfma_f32_16x16x32_bf16(fa[mi], fb[ni], acc[mi][ni], 0, 0, 0);
    __builtin_amdgcn_s_setprio(0);
    __builtin_amdgcn_s_barrier();

    // ---- P1 ----
#pragma unroll
    for (int mi = 0; mi < 4; ++mi) fa[mi] = *(const short8*)(Ar + (wm * 128 + (4 + mi) * 16 + r) * 64 + co0);
    __builtin_amdgcn_sched_barrier(0);
    if (pre) { SB(cur ^ 1, k1, 0); SB(cur ^ 1, k1, 1); SB(cur ^ 1, k1, 2); SB(cur ^ 1, k1, 3); }
    __builtin_amdgcn_sched_barrier(0);
    __builtin_amdgcn_s_barrier();
    asm volatile("s_waitcnt lgkmcnt(0)");
    __builtin_amdgcn_s_setprio(1);
#pragma unroll
    for (int mi = 0; mi < 4; ++mi)
#pragma unroll
      for (int ni = 0; ni < 4; ++ni)
        acc[4 + mi][ni] = __builtin_amdgcn_mfma_f32_16x16x32_bf16(fa[mi], fb[ni], acc[4 + mi][ni], 0, 0, 0);
    __builtin_amdgcn_s_setprio(0);
    __builtin_amdgcn_s_barrier();

    // ---- P2 ----
#pragma unroll
    for (int ni = 0; ni < 4; ++ni) fb[ni] = *(const short8*)(Br + (wn * 64 + ni * 16 + r) * 64 + co1);
#pragma unroll
    for (int mi = 0; mi < 4; ++mi) fa[mi] = *(const short8*)(Ar + (wm * 128 + mi * 16 + r) * 64 + co1);
    __builtin_amdgcn_sched_barrier(0);
    __builtin_amdgcn_s_barrier();
    asm volatile("s_waitcnt lgkmcnt(0)");
    __builtin_amdgcn_s_setprio(1);
#pragma unroll
    for (int mi = 0; mi < 4; ++mi)
#pragma unroll
      for (int ni = 0; ni < 4; ++ni)
        acc[mi][ni] = __builtin_amdgcn_mfma_f32_16x16x32_bf16(fa[mi], fb[ni], acc[mi][ni], 0, 0, 0);
    __builtin_amdgcn_s_setprio(0);
    __builtin_amdgcn_s_barrier();

    // ---- P3 ----
#pragma unroll
    for (int mi = 0; mi < 4; ++mi) fa[mi] = *(const short8*)(Ar + (wm * 128 + (4 + mi) * 16 + r) * 64 + co1);
    __builtin_amdgcn_sched_barrier(0);
    __builtin_amdgcn_s_barrier();
    asm volatile("s_waitcnt lgkmcnt(0)");
    __builtin_amdgcn_s_setprio(1);
#pragma unroll
    for (int mi = 0; mi < 4; ++mi)
#pragma unroll
      for (int ni = 0; ni < 4; ++ni)
        acc[4 + mi][ni] = __builtin_amdgcn_mfma_f32_16x16x32_bf16(fa[mi], fb[ni], acc[4 + mi][ni], 0, 0, 0);
    __builtin_amdgcn_s_setprio(0);
    if (pre) {
      asm volatile("s_waitcnt vmcnt(0)" ::: "memory");
      asm volatile("s_barrier" ::: "memory");
    }
  }

#pragma unroll
  for (int ni = 0; ni < 4; ++ni) {
    int col = n0 + wn * 64 + ni * 16 + (lane & 15);
    float bov = bo[col];
#pragma unroll
    for (int mi = 0; mi < 8; ++mi)
#pragma unroll
      for (int j = 0; j < 4; ++j) {
        int row = m0 + wm * 128 + mi * 16 + (lane >> 4) * 4 + j;
        ob[(size_t)row * D_ + col] = acc[mi][ni][j] + bov;
      }
  }
}

extern "C" void kernel_launch(void* const* d_in, const int* in_sizes, int n_in,
                              void* d_out, int out_size, void* d_ws, size_t ws_size,
                              hipStream_t stream) {
  const float* hs  = (const float*)d_in[0];
  const float* ehs = (const float*)d_in[1];
  const float* Wq  = (const float*)d_in[2];
  const float* Wk  = (const float*)d_in[3];
  const float* Wv  = (const float*)d_in[4];
  const float* Wo  = (const float*)d_in[5];
  const float* bo  = (const float*)d_in[6];
  const float* Ak  = (const float*)d_in[7];
  const float* Bk  = (const float*)d_in[8];
  const float* Av  = (const float*)d_in[9];
  const float* Bv  = (const float*)d_in[10];
  const float* Ao  = (const float*)d_in[11];
  const float* Bo  = (const float*)d_in[12];
  const float* csf = (const float*)d_in[13];
  const int*   sb  = (const int*)d_in[14];
  const int*   sn  = (const int*)d_in[15];
  float* out = (float*)d_out;

  hipFuncSetAttribute(reinterpret_cast<const void*>(k_score_big),
                      hipFuncAttributeMaxDynamicSharedMemorySize, 147456);
  hipFuncSetAttribute(reinterpret_cast<const void*>(k_out_big),
                      hipFuncAttributeMaxDynamicSharedMemorySize, 131072);

  char* ws = (char*)d_ws;
  unsigned short* P  = (unsigned short*)ws;                   // 83,886,080
  unsigned short* Mt = (unsigned short*)(ws + 83886080);      // 20,971,520
  unsigned short* Ut = (unsigned short*)(ws + 104857600);     // 20,971,520
  const size_t NEED_HSB = 125829120ULL + 67108864ULL + 81920ULL; // 193,019,904
  bool useHsb = ws_size >= NEED_HSB;
  unsigned short* hsb = useHsb ? (unsigned short*)(ws + 125829120) : nullptr;
  char* tail = useHsb ? (ws + 192937984) : (ws + 125829120);
  float* alphav = (float*)tail;
  float* betav  = (float*)(tail + 40960);
  // temporaries overlapped into P's region (all dead before k_score writes P):
  float* kvbuf = (float*)(ws + 0);            //  5,242,880  [b][80][2048] (k|v)
  float* woE   = (float*)(ws + 5242880);      //  4,194,304
  float* wqT   = (float*)(ws + 9437184);      //  4,194,304
  float* aoT   = (float*)(ws + 13631488);     //    786,432
  float* eA    = (float*)(ws + 14417920);     //    983,040  [b][80][384]
  float* part  = (float*)(ws + 15400960);     //  2,097,152
  float* hssum = (float*)(ws + 17498112);     //     32,768

  const float LS = 16.0f / 192.0f;

  // hs row-sums (deterministic two-stage) + bf16 conversion of hs
  k_hssum<<<dim3(64, 8), 256, 0, stream>>>(hs, part, hsb);
  k_hsred<<<32, 256, 0, stream>>>(part, hssum);

  // transposes: only Wq^T (for Mt GEMM) and Ao^T (for woE) are needed now
  k_tr2<<<dim3(32, 32, 2), 256, 0, stream>>>(Wq, Ao, wqT, aoT);

  // woE = Wo + LS * Bo @ Ao
  k_gemm_small<false><<<dim3(16, 16, 1), 256, 0, stream>>>(
      Bo, 192, 0, 0, aoT, 192, 0, 0, woE, 1024, 0, 0, Wo, 1024,
      1024, 1024, 1024, 192, LS, 1);

  // eA = LS * ehs @ [Ak;Av]^T   (LoRA down-projections, native layouts)
  k_eA<<<dim3(2, 6, 8), 256, 0, stream>>>(ehs, Ak, Av, eA, LS);

  // kv = ehs @ [Wk;Wv]^T + eA @ blkdiag(Bk,Bv)^T   (native layouts, no W_eff)
  k_kv<<<dim3(2, 32, 8), 256, 0, stream>>>(ehs, Wk, Wv, eA, Bk, Bv, kvbuf);

  // Mt[b,h] = 0.125 * k_bh @ Wq_h   (bf16, [b][h*80+s][d])
  k_gemm_small<true><<<dim3(2, 16, 128), 256, 0, stream>>>(
      kvbuf, 2048, 80L * 2048, 64L, wqT, 1024, 0, 64L,
      Mt, 1024, (long)NC_ * 1024, 80L * 1024, nullptr, 0,
      80, 80, 1024, 64, 0.125f, 16);

  // Ut[b,h] = woE_h @ v_bh^T   (bf16, [b][e][h*80+s])
  k_gemm_small<true><<<dim3(16, 2, 128), 256, 0, stream>>>(
      woE, 1024, 0, 64L, kvbuf + 1024, 2048, 80L * 2048, 64L,
      Ut, NC_, 1024L * NC_, 80L, nullptr, 0,
      1024, 1024, 80, 64, 1.f, 16);

  // per-(b,h,s) column mean (qmean fused) + subject alpha/beta
  k_mubeta<<<dim3(16, 8), 128, 0, stream>>>(hssum, Wq, kvbuf, sb, sn, csf, alphav, betav);

  // big fused GEMMs
  if (useHsb)
    k_score_big<<<512, 512, 147456, stream>>>(hsb, Mt, alphav, betav, P);
  else
    k_score_f32<<<2048, 256, 0, stream>>>(hs, Mt, alphav, betav, P);
  k_out_big<<<512, 512, 131072, stream>>>(P, Ut, bo, out);

  (void)in_sizes; (void)n_in; (void)out_size; (void)ws_size;
}

// Round 8
// 383.409 us; speedup vs baseline: 1.0201x; 1.0201x over previous
//
#include <hip/hip_runtime.h>
#include <stdint.h>

#define B_     8
#define LQ_    4096
#define S_     77
#define SP_    80
#define D_     1024
#define H_     16
#define HD_    64
#define NC_    1280   // H_*SP_
#define NSUBJ_ 32

typedef __attribute__((ext_vector_type(4))) float  f4;
typedef __attribute__((ext_vector_type(8))) short  short8;
typedef __attribute__((ext_vector_type(8))) unsigned short us8;
typedef __attribute__((ext_vector_type(4))) unsigned short us4;

__device__ __forceinline__ unsigned short f2bf(float f) {
  union { float f; unsigned u; } x; x.f = f;
  unsigned r = x.u + 0x7FFFu + ((x.u >> 16) & 1u);
  return (unsigned short)(r >> 16);
}

__device__ __forceinline__ void gload16(const void* g, void* s) {
  __builtin_amdgcn_global_load_lds((const __attribute__((address_space(1))) void*)g,
                                   (__attribute__((address_space(3))) void*)s, 16, 0, 0);
}

// ---------------- hssum partials + hs -> bf16 convert ----------------
__global__ __launch_bounds__(256) void k_hssum(const float* __restrict__ hs,
                                               float* __restrict__ part,
                                               unsigned short* __restrict__ hsb) {
  int b = blockIdx.y;
  size_t base = ((size_t)b * LQ_ + (size_t)blockIdx.x * 64) * D_ + threadIdx.x * 4;
  f4 acc = {0.f, 0.f, 0.f, 0.f};
  for (int l = 0; l < 64; ++l) {
    f4 v = *(const f4*)(hs + base + (size_t)l * D_);
    acc += v;
    if (hsb) {
      us4 o;
#pragma unroll
      for (int j = 0; j < 4; ++j) o[j] = f2bf(v[j]);
      *(us4*)(hsb + base + (size_t)l * D_) = o;
    }
  }
  *(f4*)(part + (size_t)blockIdx.x * (B_ * D_) + b * D_ + threadIdx.x * 4) = acc;
}

__global__ __launch_bounds__(256) void k_hsred(const float* __restrict__ part,
                                               float* __restrict__ hssum) {
  int i = blockIdx.x * 256 + threadIdx.x;   // [0, 8192)
  float s = 0.f;
  for (int x = 0; x < 64; ++x) s += part[(size_t)x * (B_ * D_) + i];
  hssum[i] = s;
}

// ---------------- 4 transposes (Wq 1024x1024, Ak/Av/Ao 192x1024) in one launch ----------------
__global__ __launch_bounds__(256) void k_tr4(const float* __restrict__ Wq, const float* __restrict__ Ak,
                                             const float* __restrict__ Av, const float* __restrict__ Ao,
                                             float* __restrict__ wqT, float* __restrict__ akT,
                                             float* __restrict__ avT, float* __restrict__ aoT) {
  int z = blockIdx.z;
  const float* in = z == 0 ? Wq : (z == 1 ? Ak : (z == 2 ? Av : Ao));
  float* out = z == 0 ? wqT : (z == 1 ? akT : (z == 2 ? avT : aoT));
  int R = z == 0 ? 1024 : 192;
  const int C = 1024;
  int c0 = blockIdx.x * 32, r0 = blockIdx.y * 32;
  if (r0 >= R) return;
  __shared__ float tile[32][33];
  int tx = threadIdx.x & 31, ty = threadIdx.x >> 5;
#pragma unroll
  for (int k = 0; k < 4; ++k)
    tile[ty + 8 * k][tx] = in[(size_t)(r0 + ty + 8 * k) * C + c0 + tx];
  __syncthreads();
#pragma unroll
  for (int k = 0; k < 4; ++k)
    out[(size_t)(c0 + ty + 8 * k) * R + r0 + tx] = tile[tx][ty + 8 * k];
}

// ---------------- shared 64x64-tile GEMM body: C = alpha*(A @ Bt^T) [+ Dm] ----------------
template <bool OBF>
__device__ __forceinline__ void gemm64_body(
    const float* __restrict__ A, int lda, const float* __restrict__ Bt, int ldb,
    void* __restrict__ Cv, int ldc, long cbase, const float* __restrict__ Dm, int ldd,
    int M, int Mv, int N, int K, float alpha, int m0, int n0,
    short* As, short* Bs) {
  int t = threadIdx.x, lane = t & 63, wid = t >> 6;
  int wm = wid >> 1, wn = wid & 1;
  f4 acc[2][2] = {};
  int srow = t >> 2, skc = (t & 3) * 8;
  for (int k0 = 0; k0 < K; k0 += 32) {
    __syncthreads();
    f4 a0 = {0,0,0,0}, a1 = {0,0,0,0}, b0 = {0,0,0,0}, b1 = {0,0,0,0};
    if (m0 + srow < Mv) {
      const float* p = A + (size_t)(m0 + srow) * lda + k0 + skc;
      a0 = *(const f4*)p; a1 = *(const f4*)(p + 4);
    }
    if (n0 + srow < N) {
      const float* p = Bt + (size_t)(n0 + srow) * ldb + k0 + skc;
      b0 = *(const f4*)p; b1 = *(const f4*)(p + 4);
    }
    us8 ua, ub;
#pragma unroll
    for (int j = 0; j < 4; ++j) {
      ua[j] = f2bf(a0[j]); ua[4 + j] = f2bf(a1[j]);
      ub[j] = f2bf(b0[j]); ub[4 + j] = f2bf(b1[j]);
    }
    *(us8*)(As + srow * 40 + skc) = ua;
    *(us8*)(Bs + srow * 40 + skc) = ub;
    __syncthreads();
    short8 fa[2], fb[2];
#pragma unroll
    for (int i = 0; i < 2; ++i) {
      fa[i] = *(const short8*)(As + (wm * 32 + i * 16 + (lane & 15)) * 40 + (lane >> 4) * 8);
      fb[i] = *(const short8*)(Bs + (wn * 32 + i * 16 + (lane & 15)) * 40 + (lane >> 4) * 8);
    }
#pragma unroll
    for (int mi = 0; mi < 2; ++mi)
#pragma unroll
      for (int ni = 0; ni < 2; ++ni)
        acc[mi][ni] = __builtin_amdgcn_mfma_f32_16x16x32_bf16(fa[mi], fb[ni], acc[mi][ni], 0, 0, 0);
  }
#pragma unroll
  for (int mi = 0; mi < 2; ++mi)
#pragma unroll
    for (int ni = 0; ni < 2; ++ni)
#pragma unroll
      for (int j = 0; j < 4; ++j) {
        int row = m0 + wm * 32 + mi * 16 + (lane >> 4) * 4 + j;
        int col = n0 + wn * 32 + ni * 16 + (lane & 15);
        if (row < M && col < N) {
          float val = acc[mi][ni][j] * alpha;
          if (Dm) val += Dm[(size_t)row * ldd + col];
          size_t idx = (size_t)cbase + (size_t)row * ldc + col;
          if (OBF) ((unsigned short*)Cv)[idx] = f2bf(val);
          else     ((float*)Cv)[idx] = val;
        }
      }
}

template <bool OBF>
__global__ __launch_bounds__(256) void k_gemm_small(
    const float* __restrict__ A, int lda, long sA1, long sA2,
    const float* __restrict__ Bt, int ldb, long sB1, long sB2,
    void* __restrict__ Cv, int ldc, long sC1, long sC2,
    const float* __restrict__ Dm, int ldd,
    int M, int Mv, int N, int K, float alpha, int Z2) {
  int z = blockIdx.z, z1 = z / Z2, z2 = z - z1 * Z2;
  __shared__ short As[64 * 40];
  __shared__ short Bs[64 * 40];
  gemm64_body<OBF>(A + z1 * sA1 + z2 * sA2, lda, Bt + z1 * sB1 + z2 * sB2, ldb,
                   Cv, ldc, z1 * sC1 + z2 * sC2, Dm, ldd, M, Mv, N, K, alpha,
                   blockIdx.x * 64, blockIdx.y * 64, As, Bs);
}

// W_eff = W + (1/12) Bx@Ax : three GEMMs in one launch (z selects k/v/o)
__global__ __launch_bounds__(256) void k_weff(
    const float* __restrict__ Bk, const float* __restrict__ Bv, const float* __restrict__ Bo,
    const float* __restrict__ akT, const float* __restrict__ avT, const float* __restrict__ aoT,
    const float* __restrict__ Wk, const float* __restrict__ Wv, const float* __restrict__ Wo,
    float* __restrict__ weff, float alpha) {
  int z = blockIdx.z;
  const float* A  = z == 0 ? Bk : (z == 1 ? Bv : Bo);
  const float* Bt = z == 0 ? akT : (z == 1 ? avT : aoT);
  const float* Dm = z == 0 ? Wk : (z == 1 ? Wv : Wo);
  __shared__ short As[64 * 40];
  __shared__ short Bs[64 * 40];
  gemm64_body<false>(A, 192, Bt, 192, weff + (size_t)z * 1048576, 1024, 0, Dm, 1024,
                     1024, 1024, 1024, 192, alpha, blockIdx.x * 64, blockIdx.y * 64, As, Bs);
}

// ---------------- mu/alpha/beta per (b,h,s), with qmean GEMM fused ----------------
__global__ void k_mubeta(const float* __restrict__ hssum, const float* __restrict__ Wq,
                         const float* __restrict__ kv,
                         const int* __restrict__ sb, const int* __restrict__ sn,
                         const float* __restrict__ csf_p,
                         float* __restrict__ alphav, float* __restrict__ betav) {
  int h = blockIdx.x, b = blockIdx.y;
  int t = threadIdx.x;                       // 128 threads
  __shared__ float qp[64];
  {
    int hd = t >> 1, half = t & 1;
    const float* wr = Wq + (size_t)(h * 64 + hd) * D_ + half * 512;
    const float* hp = hssum + b * D_ + half * 512;
    float s = 0.f;
    for (int d = 0; d < 512; d += 4) {
      f4 w = *(const f4*)(wr + d);
      f4 x = *(const f4*)(hp + d);
      s += w[0] * x[0] + w[1] * x[1] + w[2] * x[2] + w[3] * x[3];
    }
    s += __shfl_xor(s, 1, 64);
    if (half == 0) qp[hd] = s * (1.f / 4096.f);
  }
  __syncthreads();
  int s = t;
  if (s >= SP_) return;
  const float* kp = kv + ((size_t)(b * SP_ + s)) * 2048 + h * HD_;
  float mu = 0.f;
#pragma unroll 8
  for (int hd = 0; hd < HD_; ++hd) mu += qp[hd] * kp[hd];
  mu *= 0.125f;
  bool subj = false;
  for (int i = 0; i < NSUBJ_; ++i) subj = subj || (sb[i] == b && sn[i] == s);
  float csf = *csf_p;
  int c = b * NC_ + h * SP_ + s;
  alphav[c] = subj ? csf : 1.f;
  betav[c] = (s >= S_) ? -1e30f : (subj ? -mu * csf : 0.f);
}

// ---------------- score GEMM 256x160, BK=32, 2 blocks/CU, 2-phase counted-vmcnt ----------------
// 8 waves 4M x 2N, wave tile 64x80 (one head per wave). LDS 52KB; regs capped
// by __launch_bounds__(512,4) -> 16 waves/CU from TWO independent blocks:
// when one block stalls on barrier/vmcnt, the other's MFMAs fill the SIMD (m114).
// XOR chunk swizzle c^( (row>>1)&3 ) on 4 chunks/row: ~2-way conflicts (free).
__global__ __launch_bounds__(512, 4) void k_score_big(
    const unsigned short* __restrict__ hsb, const unsigned short* __restrict__ Mt,
    const float* __restrict__ alphav, const float* __restrict__ betav,
    unsigned short* __restrict__ P) {
  extern __shared__ short lds[];
  short* A0 = lds;             // 8192 shorts per buffer
  short* B0 = lds + 16384;     // 5120 shorts per buffer
  int id = blockIdx.x;
  int x = id & 7, idp = id >> 3;
  int nt = idp & 7;                 // 8 n-tiles of 160
  int pid = (idp >> 3) * 8 + x;     // [0,128)
  int b = pid >> 4, mt = pid & 15;
  int m0 = mt * 256, n0 = nt * 160;

  const unsigned short* Ab = hsb + (size_t)b * LQ_ * D_;
  const unsigned short* Bb = Mt + (size_t)b * NC_ * D_;
  const float* alp = alphav + b * NC_;
  const float* bet = betav + b * NC_;
  unsigned short* Pb = P + (size_t)b * LQ_ * NC_;

  int t = threadIdx.x, lane = t & 63, wid = t >> 6;   // 8 waves
  int wm = wid >> 1, wn = wid & 1;                    // 4M x 2N
  int r = lane & 15, q = lane >> 4;
  f4 acc[4][5] = {};

  // per-thread staging descriptors (chunk -> row/global-chunk, pre-swizzled src)
  auto SA = [&](int bf, int k0, int p) {   // p in {0,1}; A: 1024 chunks/buffer
    int cb = p * 512 + wid * 64;           // wave-uniform LDS chunk base
    int cc = cb + lane;
    int row = cc >> 2, gc = (cc & 3) ^ ((row >> 1) & 3);
    gload16(Ab + (size_t)(m0 + row) * D_ + k0 + gc * 8, (char*)(A0 + bf * 8192) + cb * 16);
  };
  auto SB = [&](int bf, int k0, int p) {   // B: 640 chunks/buffer (p1: waves 0,1 only)
    int cb = p * 512 + wid * 64;
    int cc = cb + lane;
    int row = cc >> 2, gc = (cc & 3) ^ ((row >> 1) & 3);
    gload16(Bb + (size_t)(n0 + row) * D_ + k0 + gc * 8, (char*)(B0 + bf * 5120) + cb * 16);
  };
  auto STAGE = [&](int bf, int k0) {       // waves 0,1: 4 loads; waves 2-7: 3 loads
    SA(bf, k0, 0); SA(bf, k0, 1);
    SB(bf, k0, 0);
    if (wid < 2) SB(bf, k0, 1);
  };

  STAGE(0, 0);
  int cur = 0;
  for (int kt = 0; kt < 32; ++kt) {
    if (kt < 31) {
      STAGE(cur ^ 1, (kt + 1) * 32);
      if (wid < 2) asm volatile("s_waitcnt vmcnt(4)" ::: "memory");
      else         asm volatile("s_waitcnt vmcnt(3)" ::: "memory");
    } else {
      asm volatile("s_waitcnt vmcnt(0)" ::: "memory");
    }
    __builtin_amdgcn_s_barrier();
    const short* Ar = A0 + cur * 8192;
    const short* Br = B0 + cur * 5120;
    short8 fa[4], fb[5];
#pragma unroll
    for (int ni = 0; ni < 5; ++ni) {
      int row = wn * 80 + ni * 16 + r;
      fb[ni] = *(const short8*)(Br + row * 32 + ((q ^ ((row >> 1) & 3)) * 8));
    }
#pragma unroll
    for (int mi = 0; mi < 4; ++mi) {
      int row = wm * 64 + mi * 16 + r;
      fa[mi] = *(const short8*)(Ar + row * 32 + ((q ^ ((row >> 1) & 3)) * 8));
    }
    __builtin_amdgcn_s_setprio(1);
#pragma unroll
    for (int mi = 0; mi < 4; ++mi)
#pragma unroll
      for (int ni = 0; ni < 5; ++ni)
        acc[mi][ni] = __builtin_amdgcn_mfma_f32_16x16x32_bf16(fa[mi], fb[ni], acc[mi][ni], 0, 0, 0);
    __builtin_amdgcn_s_setprio(0);
    __builtin_amdgcn_s_barrier();
    cur ^= 1;
  }

  // epilogue: alpha*score + beta, per-head softmax (wave owns one 80-col head)
  float al[5], be[5];
#pragma unroll
  for (int ni = 0; ni < 5; ++ni) {
    int cc = n0 + wn * 80 + ni * 16 + r;
    al[ni] = alp[cc]; be[ni] = bet[cc];
  }
#pragma unroll
  for (int mi = 0; mi < 4; ++mi) {
#pragma unroll
    for (int j = 0; j < 4; ++j) {
      float v[5];
      float m = -3.0e38f;
#pragma unroll
      for (int ni = 0; ni < 5; ++ni) { v[ni] = acc[mi][ni][j] * al[ni] + be[ni]; m = fmaxf(m, v[ni]); }
#pragma unroll
      for (int off = 1; off < 16; off <<= 1) m = fmaxf(m, __shfl_xor(m, off, 64));
      float ssum = 0.f;
#pragma unroll
      for (int ni = 0; ni < 5; ++ni) { v[ni] = __expf(v[ni] - m); ssum += v[ni]; }
#pragma unroll
      for (int off = 1; off < 16; off <<= 1) ssum += __shfl_xor(ssum, off, 64);
      float inv = 1.f / ssum;
      int row = m0 + wm * 64 + mi * 16 + q * 4 + j;
      size_t rb = (size_t)row * NC_ + n0 + wn * 80 + r;
#pragma unroll
      for (int ni = 0; ni < 5; ++ni)
        Pb[rb + ni * 16] = f2bf(v[ni] * inv);
    }
  }
}

// ---------------- fallback score GEMM (fp32 A, reg-staged), 128x160, 256 thr ----------------
__global__ __launch_bounds__(256) void k_score_f32(
    const float* __restrict__ hs, const unsigned short* __restrict__ Mt,
    const float* __restrict__ alphav, const float* __restrict__ betav,
    unsigned short* __restrict__ P) {
  int id = blockIdx.x;
  int x = id & 7, idp = id >> 3;
  int n_t = idp & 7;
  int pid = (idp >> 3) * 8 + x;
  int b = pid >> 5, m_t = pid & 31;
  int m0 = m_t * 128, n0 = n_t * 160;
  const float* Af = hs + (size_t)b * LQ_ * D_;
  const unsigned short* Bb = Mt + (size_t)b * NC_ * D_;
  const float* alp = alphav + b * NC_;
  const float* bet = betav + b * NC_;
  unsigned short* Pb = P + (size_t)b * LQ_ * NC_;
  __shared__ short As[128 * 64];
  __shared__ short Bs[160 * 64];
  int t = threadIdx.x, lane = t & 63, wid = t >> 6;
  int wm = wid >> 1, wn = wid & 1;
  int srow = lane >> 3;
  int schunk = (lane & 7) ^ srow;
  f4 acc[4][5] = {};
  for (int k0 = 0; k0 < D_; k0 += 64) {
    __syncthreads();
    for (int i = wid; i < 20; i += 4)
      gload16(Bb + (size_t)(n0 + i * 8 + srow) * D_ + k0 + schunk * 8, (char*)Bs + i * 1024);
    int arow = t >> 3, ac = t & 7;
    int awc = ac ^ (arow & 7);
#pragma unroll
    for (int p = 0; p < 4; ++p) {
      int row = p * 32 + arow;
      const float* src = Af + (size_t)(m0 + row) * D_ + k0 + ac * 8;
      f4 v0 = *(const f4*)src;
      f4 v1 = *(const f4*)(src + 4);
      us8 u;
#pragma unroll
      for (int j = 0; j < 4; ++j) { u[j] = f2bf(v0[j]); u[4 + j] = f2bf(v1[j]); }
      *(us8*)(As + row * 64 + awc * 8) = u;
    }
    __syncthreads();
#pragma unroll
    for (int kk = 0; kk < 2; ++kk) {
      int co = ((kk * 4 + (lane >> 4)) ^ (lane & 7)) * 8;
      short8 fa[4], fb[5];
#pragma unroll
      for (int mi = 0; mi < 4; ++mi)
        fa[mi] = *(const short8*)(As + (wm * 64 + mi * 16 + (lane & 15)) * 64 + co);
#pragma unroll
      for (int ni = 0; ni < 5; ++ni)
        fb[ni] = *(const short8*)(Bs + (wn * 80 + ni * 16 + (lane & 15)) * 64 + co);
#pragma unroll
      for (int mi = 0; mi < 4; ++mi)
#pragma unroll
        for (int ni = 0; ni < 5; ++ni)
          acc[mi][ni] = __builtin_amdgcn_mfma_f32_16x16x32_bf16(fa[mi], fb[ni], acc[mi][ni], 0, 0, 0);
    }
  }
  float al[5], be[5];
#pragma unroll
  for (int ni = 0; ni < 5; ++ni) {
    int cc = n0 + wn * 80 + ni * 16 + (lane & 15);
    al[ni] = alp[cc]; be[ni] = bet[cc];
  }
#pragma unroll
  for (int mi = 0; mi < 4; ++mi) {
#pragma unroll
    for (int j = 0; j < 4; ++j) {
      float v[5];
      float m = -3.0e38f;
#pragma unroll
      for (int ni = 0; ni < 5; ++ni) { v[ni] = acc[mi][ni][j] * al[ni] + be[ni]; m = fmaxf(m, v[ni]); }
#pragma unroll
      for (int off = 1; off < 16; off <<= 1) m = fmaxf(m, __shfl_xor(m, off, 64));
      float ssum = 0.f;
#pragma unroll
      for (int ni = 0; ni < 5; ++ni) { v[ni] = __expf(v[ni] - m); ssum += v[ni]; }
#pragma unroll
      for (int off = 1; off < 16; off <<= 1) ssum += __shfl_xor(ssum, off, 64);
      float inv = 1.f / ssum;
      int row = m0 + wm * 64 + mi * 16 + (lane >> 4) * 4 + j;
      size_t rb = (size_t)row * NC_ + n0 + wn * 80 + (lane & 15);
#pragma unroll
      for (int ni = 0; ni < 5; ++ni)
        Pb[rb + ni * 16] = f2bf(v[ni] * inv);
    }
  }
}

// ---------------- out GEMM 256x128, BK=32, 2 blocks/CU: out = P @ Ut^T + bo ----------------
__global__ __launch_bounds__(512, 4) void k_out_big(
    const unsigned short* __restrict__ P, const unsigned short* __restrict__ Ut,
    const float* __restrict__ bo, float* __restrict__ out) {
  extern __shared__ short lds[];
  short* A0 = lds;             // 8192 shorts per buffer
  short* B0 = lds + 16384;     // 4096 shorts per buffer
  int id = blockIdx.x;
  int x = id & 7, idp = id >> 3;
  int nt = idp & 7;                 // 8 n-tiles of 128
  int pid = (idp >> 3) * 8 + x;
  int b = pid >> 4, mt = pid & 15;
  int m0 = mt * 256, n0 = nt * 128;

  const unsigned short* Ab = P + (size_t)b * LQ_ * NC_;
  const unsigned short* Bb = Ut + (size_t)b * D_ * NC_;
  float* ob = out + (size_t)b * LQ_ * D_;

  int t = threadIdx.x, lane = t & 63, wid = t >> 6;
  int wm = wid >> 1, wn = wid & 1;
  int r = lane & 15, q = lane >> 4;
  f4 acc[4][4] = {};
  const int T = NC_ / 32;   // 40

  auto SA = [&](int bf, int k0, int p) {
    int cb = p * 512 + wid * 64;
    int cc = cb + lane;
    int row = cc >> 2, gc = (cc & 3) ^ ((row >> 1) & 3);
    gload16(Ab + (size_t)(m0 + row) * NC_ + k0 + gc * 8, (char*)(A0 + bf * 8192) + cb * 16);
  };
  auto SB = [&](int bf, int k0) {          // 512 chunks: one issue, all waves
    int cb = wid * 64;
    int cc = cb + lane;
    int row = cc >> 2, gc = (cc & 3) ^ ((row >> 1) & 3);
    gload16(Bb + (size_t)(n0 + row) * NC_ + k0 + gc * 8, (char*)(B0 + bf * 4096) + cb * 16);
  };
  auto STAGE = [&](int bf, int k0) { SA(bf, k0, 0); SA(bf, k0, 1); SB(bf, k0); };

  STAGE(0, 0);
  int cur = 0;
  for (int kt = 0; kt < T; ++kt) {
    if (kt + 1 < T) {
      STAGE(cur ^ 1, (kt + 1) * 32);
      asm volatile("s_waitcnt vmcnt(3)" ::: "memory");
    } else {
      asm volatile("s_waitcnt vmcnt(0)" ::: "memory");
    }
    __builtin_amdgcn_s_barrier();
    const short* Ar = A0 + cur * 8192;
    const short* Br = B0 + cur * 4096;
    short8 fa[4], fb[4];
#pragma unroll
    for (int ni = 0; ni < 4; ++ni) {
      int row = wn * 64 + ni * 16 + r;
      fb[ni] = *(const short8*)(Br + row * 32 + ((q ^ ((row >> 1) & 3)) * 8));
    }
#pragma unroll
    for (int mi = 0; mi < 4; ++mi) {
      int row = wm * 64 + mi * 16 + r;
      fa[mi] = *(const short8*)(Ar + row * 32 + ((q ^ ((row >> 1) & 3)) * 8));
    }
    __builtin_amdgcn_s_setprio(1);
#pragma unroll
    for (int mi = 0; mi < 4; ++mi)
#pragma unroll
      for (int ni = 0; ni < 4; ++ni)
        acc[mi][ni] = __builtin_amdgcn_mfma_f32_16x16x32_bf16(fa[mi], fb[ni], acc[mi][ni], 0, 0, 0);
    __builtin_amdgcn_s_setprio(0);
    __builtin_amdgcn_s_barrier();
    cur ^= 1;
  }

#pragma unroll
  for (int ni = 0; ni < 4; ++ni) {
    int col = n0 + wn * 64 + ni * 16 + r;
    float bov = bo[col];
#pragma unroll
    for (int mi = 0; mi < 4; ++mi)
#pragma unroll
      for (int j = 0; j < 4; ++j) {
        int row = m0 + wm * 64 + mi * 16 + q * 4 + j;
        ob[(size_t)row * D_ + col] = acc[mi][ni][j] + bov;
      }
  }
}

extern "C" void kernel_launch(void* const* d_in, const int* in_sizes, int n_in,
                              void* d_out, int out_size, void* d_ws, size_t ws_size,
                              hipStream_t stream) {
  const float* hs  = (const float*)d_in[0];
  const float* ehs = (const float*)d_in[1];
  const float* Wq  = (const float*)d_in[2];
  const float* Wk  = (const float*)d_in[3];
  const float* Wv  = (const float*)d_in[4];
  const float* Wo  = (const float*)d_in[5];
  const float* bo  = (const float*)d_in[6];
  const float* Ak  = (const float*)d_in[7];
  const float* Bk  = (const float*)d_in[8];
  const float* Av  = (const float*)d_in[9];
  const float* Bv  = (const float*)d_in[10];
  const float* Ao  = (const float*)d_in[11];
  const float* Bo  = (const float*)d_in[12];
  const float* csf = (const float*)d_in[13];
  const int*   sb  = (const int*)d_in[14];
  const int*   sn  = (const int*)d_in[15];
  float* out = (float*)d_out;

  hipFuncSetAttribute(reinterpret_cast<const void*>(k_score_big),
                      hipFuncAttributeMaxDynamicSharedMemorySize, 53248);
  hipFuncSetAttribute(reinterpret_cast<const void*>(k_out_big),
                      hipFuncAttributeMaxDynamicSharedMemorySize, 49152);

  char* ws = (char*)d_ws;
  unsigned short* P  = (unsigned short*)ws;                   // 83,886,080
  unsigned short* Mt = (unsigned short*)(ws + 83886080);      // 20,971,520
  unsigned short* Ut = (unsigned short*)(ws + 104857600);     // 20,971,520
  const size_t NEED_HSB = 125829120ULL + 67108864ULL + 81920ULL; // 193,019,904
  bool useHsb = ws_size >= NEED_HSB;
  unsigned short* hsb = useHsb ? (unsigned short*)(ws + 125829120) : nullptr;
  char* tail = useHsb ? (ws + 192937984) : (ws + 125829120);
  float* alphav = (float*)tail;
  float* betav  = (float*)(tail + 40960);
  // temporaries overlapped into P's region (all dead before k_score writes P):
  float* kvbuf = (float*)(ws + 0);            //  5,242,880  [b][80][2048] (k|v)
  float* weff  = (float*)(ws + 5242880);      // 12,582,912  [wkE;wvE;woE]
  float* wqT   = (float*)(ws + 17825792);     //  4,194,304
  float* aT    = (float*)(ws + 22020096);     //  2,359,296
  float* part  = (float*)(ws + 24379392);     //  2,097,152
  float* hssum = (float*)(ws + 26476544);     //     32,768

  float* woE = weff + 2097152;
  float* akT = aT;
  float* avT = aT + 196608;
  float* aoT = aT + 393216;

  const float LS = 16.0f / 192.0f;

  // hs row-sums (deterministic two-stage) + bf16 conversion of hs
  k_hssum<<<dim3(64, 8), 256, 0, stream>>>(hs, part, hsb);
  k_hsred<<<32, 256, 0, stream>>>(part, hssum);

  // all transposes in one launch
  k_tr4<<<dim3(32, 32, 4), 256, 0, stream>>>(Wq, Ak, Av, Ao, wqT, akT, avT, aoT);

  // W_eff (k,v,o) in one launch
  k_weff<<<dim3(16, 16, 3), 256, 0, stream>>>(Bk, Bv, Bo, akT, avT, aoT, Wk, Wv, Wo, weff, LS);

  // [k|v] = ehs @ [wkE;wvE]^T : N=2048, C row-stride 2048
  k_gemm_small<false><<<dim3(2, 32, 8), 256, 0, stream>>>(
      ehs, 1024, 77L * 1024, 0, weff, 1024, 0, 0, kvbuf, 2048, 80L * 2048, 0, nullptr, 0,
      80, 77, 2048, 1024, 1.f, 1);

  // Mt[b,h] = 0.125 * k_bh @ Wq_h   (bf16, [b][h*80+s][d])
  k_gemm_small<true><<<dim3(2, 16, 128), 256, 0, stream>>>(
      kvbuf, 2048, 80L * 2048, 64L, wqT, 1024, 0, 64L,
      Mt, 1024, (long)NC_ * 1024, 80L * 1024, nullptr, 0,
      80, 80, 1024, 64, 0.125f, 16);

  // Ut[b,h] = woE_h @ v_bh^T   (bf16, [b][e][h*80+s])
  k_gemm_small<true><<<dim3(16, 2, 128), 256, 0, stream>>>(
      woE, 1024, 0, 64L, kvbuf + 1024, 2048, 80L * 2048, 64L,
      Ut, NC_, 1024L * NC_, 80L, nullptr, 0,
      1024, 1024, 80, 64, 1.f, 16);

  // per-(b,h,s) column mean (qmean fused) + subject alpha/beta
  k_mubeta<<<dim3(16, 8), 128, 0, stream>>>(hssum, Wq, kvbuf, sb, sn, csf, alphav, betav);

  // big fused GEMMs
  if (useHsb)
    k_score_big<<<1024, 512, 53248, stream>>>(hsb, Mt, alphav, betav, P);
  else
    k_score_f32<<<2048, 256, 0, stream>>>(hs, Mt, alphav, betav, P);
  k_out_big<<<1024, 512, 49152, stream>>>(P, Ut, bo, out);

  (void)in_sizes; (void)n_in; (void)out_size; (void)ws_size;
}

// Round 9
// 378.748 us; speedup vs baseline: 1.0327x; 1.0123x over previous
//
#include <hip/hip_runtime.h>
#include <stdint.h>

#define B_     8
#define LQ_    4096
#define S_     77
#define SP_    80
#define D_     1024
#define H_     16
#define HD_    64
#define NC_    1280   // H_*SP_
#define NSUBJ_ 32

typedef __attribute__((ext_vector_type(4))) float  f4;
typedef __attribute__((ext_vector_type(8))) short  short8;
typedef __attribute__((ext_vector_type(8))) unsigned short us8;
typedef __attribute__((ext_vector_type(4))) unsigned short us4;

__device__ __forceinline__ unsigned short f2bf(float f) {
  union { float f; unsigned u; } x; x.f = f;
  unsigned r = x.u + 0x7FFFu + ((x.u >> 16) & 1u);
  return (unsigned short)(r >> 16);
}

__device__ __forceinline__ void gload16(const void* g, void* s) {
  __builtin_amdgcn_global_load_lds((const __attribute__((address_space(1))) void*)g,
                                   (__attribute__((address_space(3))) void*)s, 16, 0, 0);
}

// ---------------- hssum partials + hs -> bf16 convert ----------------
__global__ __launch_bounds__(256) void k_hssum(const float* __restrict__ hs,
                                               float* __restrict__ part,
                                               unsigned short* __restrict__ hsb) {
  int b = blockIdx.y;
  size_t base = ((size_t)b * LQ_ + (size_t)blockIdx.x * 64) * D_ + threadIdx.x * 4;
  f4 acc = {0.f, 0.f, 0.f, 0.f};
  for (int l = 0; l < 64; ++l) {
    f4 v = *(const f4*)(hs + base + (size_t)l * D_);
    acc += v;
    if (hsb) {
      us4 o;
#pragma unroll
      for (int j = 0; j < 4; ++j) o[j] = f2bf(v[j]);
      *(us4*)(hsb + base + (size_t)l * D_) = o;
    }
  }
  *(f4*)(part + (size_t)blockIdx.x * (B_ * D_) + b * D_ + threadIdx.x * 4) = acc;
}

__global__ __launch_bounds__(256) void k_hsred(const float* __restrict__ part,
                                               float* __restrict__ hssum) {
  int i = blockIdx.x * 256 + threadIdx.x;   // [0, 8192)
  float s = 0.f;
  for (int x = 0; x < 64; ++x) s += part[(size_t)x * (B_ * D_) + i];
  hssum[i] = s;
}

// ---------------- 4 transposes (Wq 1024x1024, Ak/Av/Ao 192x1024) in one launch ----------------
__global__ __launch_bounds__(256) void k_tr4(const float* __restrict__ Wq, const float* __restrict__ Ak,
                                             const float* __restrict__ Av, const float* __restrict__ Ao,
                                             float* __restrict__ wqT, float* __restrict__ akT,
                                             float* __restrict__ avT, float* __restrict__ aoT) {
  int z = blockIdx.z;
  const float* in = z == 0 ? Wq : (z == 1 ? Ak : (z == 2 ? Av : Ao));
  float* out = z == 0 ? wqT : (z == 1 ? akT : (z == 2 ? avT : aoT));
  int R = z == 0 ? 1024 : 192;
  const int C = 1024;
  int c0 = blockIdx.x * 32, r0 = blockIdx.y * 32;
  if (r0 >= R) return;
  __shared__ float tile[32][33];
  int tx = threadIdx.x & 31, ty = threadIdx.x >> 5;
#pragma unroll
  for (int k = 0; k < 4; ++k)
    tile[ty + 8 * k][tx] = in[(size_t)(r0 + ty + 8 * k) * C + c0 + tx];
  __syncthreads();
#pragma unroll
  for (int k = 0; k < 4; ++k)
    out[(size_t)(c0 + ty + 8 * k) * R + r0 + tx] = tile[tx][ty + 8 * k];
}

// ---------------- shared 64x64-tile GEMM body: C = alpha*(A @ Bt^T) [+ Dm] ----------------
template <bool OBF>
__device__ __forceinline__ void gemm64_body(
    const float* __restrict__ A, int lda, const float* __restrict__ Bt, int ldb,
    void* __restrict__ Cv, int ldc, long cbase, const float* __restrict__ Dm, int ldd,
    int M, int Mv, int N, int K, float alpha, int m0, int n0,
    short* As, short* Bs) {
  int t = threadIdx.x, lane = t & 63, wid = t >> 6;
  int wm = wid >> 1, wn = wid & 1;
  f4 acc[2][2] = {};
  int srow = t >> 2, skc = (t & 3) * 8;
  for (int k0 = 0; k0 < K; k0 += 32) {
    __syncthreads();
    f4 a0 = {0,0,0,0}, a1 = {0,0,0,0}, b0 = {0,0,0,0}, b1 = {0,0,0,0};
    if (m0 + srow < Mv) {
      const float* p = A + (size_t)(m0 + srow) * lda + k0 + skc;
      a0 = *(const f4*)p; a1 = *(const f4*)(p + 4);
    }
    if (n0 + srow < N) {
      const float* p = Bt + (size_t)(n0 + srow) * ldb + k0 + skc;
      b0 = *(const f4*)p; b1 = *(const f4*)(p + 4);
    }
    us8 ua, ub;
#pragma unroll
    for (int j = 0; j < 4; ++j) {
      ua[j] = f2bf(a0[j]); ua[4 + j] = f2bf(a1[j]);
      ub[j] = f2bf(b0[j]); ub[4 + j] = f2bf(b1[j]);
    }
    *(us8*)(As + srow * 40 + skc) = ua;
    *(us8*)(Bs + srow * 40 + skc) = ub;
    __syncthreads();
    short8 fa[2], fb[2];
#pragma unroll
    for (int i = 0; i < 2; ++i) {
      fa[i] = *(const short8*)(As + (wm * 32 + i * 16 + (lane & 15)) * 40 + (lane >> 4) * 8);
      fb[i] = *(const short8*)(Bs + (wn * 32 + i * 16 + (lane & 15)) * 40 + (lane >> 4) * 8);
    }
#pragma unroll
    for (int mi = 0; mi < 2; ++mi)
#pragma unroll
      for (int ni = 0; ni < 2; ++ni)
        acc[mi][ni] = __builtin_amdgcn_mfma_f32_16x16x32_bf16(fa[mi], fb[ni], acc[mi][ni], 0, 0, 0);
  }
#pragma unroll
  for (int mi = 0; mi < 2; ++mi)
#pragma unroll
    for (int ni = 0; ni < 2; ++ni)
#pragma unroll
      for (int j = 0; j < 4; ++j) {
        int row = m0 + wm * 32 + mi * 16 + (lane >> 4) * 4 + j;
        int col = n0 + wn * 32 + ni * 16 + (lane & 15);
        if (row < M && col < N) {
          float val = acc[mi][ni][j] * alpha;
          if (Dm) val += Dm[(size_t)row * ldd + col];
          size_t idx = (size_t)cbase + (size_t)row * ldc + col;
          if (OBF) ((unsigned short*)Cv)[idx] = f2bf(val);
          else     ((float*)Cv)[idx] = val;
        }
      }
}

template <bool OBF>
__global__ __launch_bounds__(256) void k_gemm_small(
    const float* __restrict__ A, int lda, long sA1, long sA2,
    const float* __restrict__ Bt, int ldb, long sB1, long sB2,
    void* __restrict__ Cv, int ldc, long sC1, long sC2,
    const float* __restrict__ Dm, int ldd,
    int M, int Mv, int N, int K, float alpha, int Z2) {
  int z = blockIdx.z, z1 = z / Z2, z2 = z - z1 * Z2;
  __shared__ short As[64 * 40];
  __shared__ short Bs[64 * 40];
  gemm64_body<OBF>(A + z1 * sA1 + z2 * sA2, lda, Bt + z1 * sB1 + z2 * sB2, ldb,
                   Cv, ldc, z1 * sC1 + z2 * sC2, Dm, ldd, M, Mv, N, K, alpha,
                   blockIdx.x * 64, blockIdx.y * 64, As, Bs);
}

// W_eff = W + (1/12) Bx@Ax : three GEMMs in one launch (z selects k/v/o)
__global__ __launch_bounds__(256) void k_weff(
    const float* __restrict__ Bk, const float* __restrict__ Bv, const float* __restrict__ Bo,
    const float* __restrict__ akT, const float* __restrict__ avT, const float* __restrict__ aoT,
    const float* __restrict__ Wk, const float* __restrict__ Wv, const float* __restrict__ Wo,
    float* __restrict__ weff, float alpha) {
  int z = blockIdx.z;
  const float* A  = z == 0 ? Bk : (z == 1 ? Bv : Bo);
  const float* Bt = z == 0 ? akT : (z == 1 ? avT : aoT);
  const float* Dm = z == 0 ? Wk : (z == 1 ? Wv : Wo);
  __shared__ short As[64 * 40];
  __shared__ short Bs[64 * 40];
  gemm64_body<false>(A, 192, Bt, 192, weff + (size_t)z * 1048576, 1024, 0, Dm, 1024,
                     1024, 1024, 1024, 192, alpha, blockIdx.x * 64, blockIdx.y * 64, As, Bs);
}

// ---------------- mu/alpha/beta per (b,h,s), with qmean GEMM fused ----------------
__global__ void k_mubeta(const float* __restrict__ hssum, const float* __restrict__ Wq,
                         const float* __restrict__ kv,
                         const int* __restrict__ sb, const int* __restrict__ sn,
                         const float* __restrict__ csf_p,
                         float* __restrict__ alphav, float* __restrict__ betav) {
  int h = blockIdx.x, b = blockIdx.y;
  int t = threadIdx.x;                       // 128 threads
  __shared__ float qp[64];
  {
    int hd = t >> 1, half = t & 1;
    const float* wr = Wq + (size_t)(h * 64 + hd) * D_ + half * 512;
    const float* hp = hssum + b * D_ + half * 512;
    float s = 0.f;
    for (int d = 0; d < 512; d += 4) {
      f4 w = *(const f4*)(wr + d);
      f4 x = *(const f4*)(hp + d);
      s += w[0] * x[0] + w[1] * x[1] + w[2] * x[2] + w[3] * x[3];
    }
    s += __shfl_xor(s, 1, 64);
    if (half == 0) qp[hd] = s * (1.f / 4096.f);
  }
  __syncthreads();
  int s = t;
  if (s >= SP_) return;
  const float* kp = kv + ((size_t)(b * SP_ + s)) * 2048 + h * HD_;
  float mu = 0.f;
#pragma unroll 8
  for (int hd = 0; hd < HD_; ++hd) mu += qp[hd] * kp[hd];
  mu *= 0.125f;
  bool subj = false;
  for (int i = 0; i < NSUBJ_; ++i) subj = subj || (sb[i] == b && sn[i] == s);
  float csf = *csf_p;
  int c = b * NC_ + h * SP_ + s;
  alphav[c] = subj ? csf : 1.f;
  betav[c] = (s >= S_) ? -1e30f : (subj ? -mu * csf : 0.f);
}

// ---------------- score GEMM 256x320, BK=32, 4-buffer deep pipeline ----------------
// 3 tiles in flight; counted vmcnt never reaches 0 until the tail, so memory
// service time amortizes across 3 tiles of MFMA (AITER pattern). 8 waves 2Mx4N,
// wave tile 128x80 (one head per wave). R8's verified BK=32 XOR swizzle.
__global__ __launch_bounds__(512, 2) void k_score_big(
    const unsigned short* __restrict__ hsb, const unsigned short* __restrict__ Mt,
    const float* __restrict__ alphav, const float* __restrict__ betav,
    unsigned short* __restrict__ P) {
  extern __shared__ short lds[];
  // A: 4 bufs x 8192 shorts at 0; B: 4 bufs x 10240 shorts at 32768
  int id = blockIdx.x;
  int x = id & 7, idp = id >> 3;
  int nt = idp & 3;
  int pid = (idp >> 2) * 8 + x;    // [0,128)
  int b = pid >> 4, mt = pid & 15;
  int m0 = mt * 256, n0 = nt * 320;

  const unsigned short* Ab = hsb + (size_t)b * LQ_ * D_;
  const unsigned short* Bb = Mt + (size_t)b * NC_ * D_;
  const float* alp = alphav + b * NC_;
  const float* bet = betav + b * NC_;
  unsigned short* Pb = P + (size_t)b * LQ_ * NC_;

  int t = threadIdx.x, lane = t & 63, wid = t >> 6;   // 8 waves
  int wm = wid >> 2, wn = wid & 3;                    // 2M x 4N
  int r = lane & 15, q = lane >> 4;
  f4 acc[8][5] = {};

  auto SA = [&](int bf, int k0, int p) {     // A: 1024 chunks/tile, p in {0,1}
    int cb = p * 512 + wid * 64;
    int cc = cb + lane;
    int row = cc >> 2, gc = (cc & 3) ^ ((row >> 1) & 3);
    gload16(Ab + (size_t)(m0 + row) * D_ + k0 + gc * 8, (char*)(lds + bf * 8192) + cb * 16);
  };
  auto SB = [&](int bf, int k0, int p) {     // B: 1280 chunks/tile, p in {0,1,2}
    int cb = p * 512 + wid * 64;
    int cc = cb + lane;
    int row = cc >> 2, gc = (cc & 3) ^ ((row >> 1) & 3);
    gload16(Bb + (size_t)(n0 + row) * D_ + k0 + gc * 8, (char*)(lds + 32768 + bf * 10240) + cb * 16);
  };
  auto STAGE = [&](int bf, int k0) {         // wid<4: 5 loads; wid>=4: 4 loads
    SA(bf, k0, 0); SA(bf, k0, 1);
    SB(bf, k0, 0); SB(bf, k0, 1);
    if (wid < 4) { int cb = 1024 + wid * 64; int cc = cb + lane;
      int row = cc >> 2, gc = (cc & 3) ^ ((row >> 1) & 3);
      gload16(Bb + (size_t)(n0 + row) * D_ + k0 + gc * 8, (char*)(lds + 32768) + (size_t)bf * 20480 + cb * 16);
    }
  };

  const int T = 32;
  STAGE(0, 0); STAGE(1, 32); STAGE(2, 64);
  for (int kt = 0; kt < T; ++kt) {
    if (kt + 3 < T) {
      STAGE((kt + 3) & 3, (kt + 3) * 32);
      if (wid < 4) asm volatile("s_waitcnt vmcnt(15)" ::: "memory");
      else         asm volatile("s_waitcnt vmcnt(12)" ::: "memory");
    } else if (kt + 2 < T) {
      if (wid < 4) asm volatile("s_waitcnt vmcnt(10)" ::: "memory");
      else         asm volatile("s_waitcnt vmcnt(8)" ::: "memory");
    } else if (kt + 1 < T) {
      if (wid < 4) asm volatile("s_waitcnt vmcnt(5)" ::: "memory");
      else         asm volatile("s_waitcnt vmcnt(4)" ::: "memory");
    } else {
      asm volatile("s_waitcnt vmcnt(0)" ::: "memory");
    }
    __builtin_amdgcn_s_barrier();
    int cur = kt & 3;
    const short* Ar = lds + cur * 8192;
    const short* Br = lds + 32768 + cur * 10240;
    short8 fa[8], fb[5];
#pragma unroll
    for (int ni = 0; ni < 5; ++ni) {
      int row = wn * 80 + ni * 16 + r;
      fb[ni] = *(const short8*)(Br + row * 32 + ((q ^ ((row >> 1) & 3)) * 8));
    }
#pragma unroll
    for (int mi = 0; mi < 8; ++mi) {
      int row = wm * 128 + mi * 16 + r;
      fa[mi] = *(const short8*)(Ar + row * 32 + ((q ^ ((row >> 1) & 3)) * 8));
    }
    __builtin_amdgcn_s_setprio(1);
#pragma unroll
    for (int mi = 0; mi < 8; ++mi)
#pragma unroll
      for (int ni = 0; ni < 5; ++ni)
        acc[mi][ni] = __builtin_amdgcn_mfma_f32_16x16x32_bf16(fa[mi], fb[ni], acc[mi][ni], 0, 0, 0);
    __builtin_amdgcn_s_setprio(0);
    __builtin_amdgcn_s_barrier();   // all waves done reading buf before re-stage
  }

  // epilogue: alpha*score + beta, per-head softmax (wave owns one 80-col head)
  float al[5], be[5];
#pragma unroll
  for (int ni = 0; ni < 5; ++ni) {
    int cc = n0 + wn * 80 + ni * 16 + r;
    al[ni] = alp[cc]; be[ni] = bet[cc];
  }
#pragma unroll
  for (int mi = 0; mi < 8; ++mi) {
#pragma unroll
    for (int j = 0; j < 4; ++j) {
      float v[5];
      float m = -3.0e38f;
#pragma unroll
      for (int ni = 0; ni < 5; ++ni) { v[ni] = acc[mi][ni][j] * al[ni] + be[ni]; m = fmaxf(m, v[ni]); }
#pragma unroll
      for (int off = 1; off < 16; off <<= 1) m = fmaxf(m, __shfl_xor(m, off, 64));
      float ssum = 0.f;
#pragma unroll
      for (int ni = 0; ni < 5; ++ni) { v[ni] = __expf(v[ni] - m); ssum += v[ni]; }
#pragma unroll
      for (int off = 1; off < 16; off <<= 1) ssum += __shfl_xor(ssum, off, 64);
      float inv = 1.f / ssum;
      int row = m0 + wm * 128 + mi * 16 + q * 4 + j;
      size_t rb = (size_t)row * NC_ + n0 + wn * 80 + r;
#pragma unroll
      for (int ni = 0; ni < 5; ++ni)
        Pb[rb + ni * 16] = f2bf(v[ni] * inv);
    }
  }
}

// ---------------- fallback score GEMM (fp32 A, reg-staged), 128x160, 256 thr ----------------
__global__ __launch_bounds__(256) void k_score_f32(
    const float* __restrict__ hs, const unsigned short* __restrict__ Mt,
    const float* __restrict__ alphav, const float* __restrict__ betav,
    unsigned short* __restrict__ P) {
  int id = blockIdx.x;
  int x = id & 7, idp = id >> 3;
  int n_t = idp & 7;
  int pid = (idp >> 3) * 8 + x;
  int b = pid >> 5, m_t = pid & 31;
  int m0 = m_t * 128, n0 = n_t * 160;
  const float* Af = hs + (size_t)b * LQ_ * D_;
  const unsigned short* Bb = Mt + (size_t)b * NC_ * D_;
  const float* alp = alphav + b * NC_;
  const float* bet = betav + b * NC_;
  unsigned short* Pb = P + (size_t)b * LQ_ * NC_;
  __shared__ short As[128 * 64];
  __shared__ short Bs[160 * 64];
  int t = threadIdx.x, lane = t & 63, wid = t >> 6;
  int wm = wid >> 1, wn = wid & 1;
  int srow = lane >> 3;
  int schunk = (lane & 7) ^ srow;
  f4 acc[4][5] = {};
  for (int k0 = 0; k0 < D_; k0 += 64) {
    __syncthreads();
    for (int i = wid; i < 20; i += 4)
      gload16(Bb + (size_t)(n0 + i * 8 + srow) * D_ + k0 + schunk * 8, (char*)Bs + i * 1024);
    int arow = t >> 3, ac = t & 7;
    int awc = ac ^ (arow & 7);
#pragma unroll
    for (int p = 0; p < 4; ++p) {
      int row = p * 32 + arow;
      const float* src = Af + (size_t)(m0 + row) * D_ + k0 + ac * 8;
      f4 v0 = *(const f4*)src;
      f4 v1 = *(const f4*)(src + 4);
      us8 u;
#pragma unroll
      for (int j = 0; j < 4; ++j) { u[j] = f2bf(v0[j]); u[4 + j] = f2bf(v1[j]); }
      *(us8*)(As + row * 64 + awc * 8) = u;
    }
    __syncthreads();
#pragma unroll
    for (int kk = 0; kk < 2; ++kk) {
      int co = ((kk * 4 + (lane >> 4)) ^ (lane & 7)) * 8;
      short8 fa[4], fb[5];
#pragma unroll
      for (int mi = 0; mi < 4; ++mi)
        fa[mi] = *(const short8*)(As + (wm * 64 + mi * 16 + (lane & 15)) * 64 + co);
#pragma unroll
      for (int ni = 0; ni < 5; ++ni)
        fb[ni] = *(const short8*)(Bs + (wn * 80 + ni * 16 + (lane & 15)) * 64 + co);
#pragma unroll
      for (int mi = 0; mi < 4; ++mi)
#pragma unroll
        for (int ni = 0; ni < 5; ++ni)
          acc[mi][ni] = __builtin_amdgcn_mfma_f32_16x16x32_bf16(fa[mi], fb[ni], acc[mi][ni], 0, 0, 0);
    }
  }
  float al[5], be[5];
#pragma unroll
  for (int ni = 0; ni < 5; ++ni) {
    int cc = n0 + wn * 80 + ni * 16 + (lane & 15);
    al[ni] = alp[cc]; be[ni] = bet[cc];
  }
#pragma unroll
  for (int mi = 0; mi < 4; ++mi) {
#pragma unroll
    for (int j = 0; j < 4; ++j) {
      float v[5];
      float m = -3.0e38f;
#pragma unroll
      for (int ni = 0; ni < 5; ++ni) { v[ni] = acc[mi][ni][j] * al[ni] + be[ni]; m = fmaxf(m, v[ni]); }
#pragma unroll
      for (int off = 1; off < 16; off <<= 1) m = fmaxf(m, __shfl_xor(m, off, 64));
      float ssum = 0.f;
#pragma unroll
      for (int ni = 0; ni < 5; ++ni) { v[ni] = __expf(v[ni] - m); ssum += v[ni]; }
#pragma unroll
      for (int off = 1; off < 16; off <<= 1) ssum += __shfl_xor(ssum, off, 64);
      float inv = 1.f / ssum;
      int row = m0 + wm * 64 + mi * 16 + (lane >> 4) * 4 + j;
      size_t rb = (size_t)row * NC_ + n0 + wn * 80 + (lane & 15);
#pragma unroll
      for (int ni = 0; ni < 5; ++ni)
        Pb[rb + ni * 16] = f2bf(v[ni] * inv);
    }
  }
}

// ---------------- out GEMM 256x256, BK=32, 4-buffer deep pipeline ----------------
__global__ __launch_bounds__(512, 2) void k_out_big(
    const unsigned short* __restrict__ P, const unsigned short* __restrict__ Ut,
    const float* __restrict__ bo, float* __restrict__ out) {
  extern __shared__ short lds[];
  // A: 4 bufs x 8192 at 0; B: 4 bufs x 8192 at 32768
  int id = blockIdx.x;
  int x = id & 7, idp = id >> 3;
  int nt = idp & 3;
  int pid = (idp >> 2) * 8 + x;
  int b = pid >> 4, mt = pid & 15;
  int m0 = mt * 256, n0 = nt * 256;

  const unsigned short* Ab = P + (size_t)b * LQ_ * NC_;
  const unsigned short* Bb = Ut + (size_t)b * D_ * NC_;
  float* ob = out + (size_t)b * LQ_ * D_;

  int t = threadIdx.x, lane = t & 63, wid = t >> 6;
  int wm = wid >> 2, wn = wid & 3;
  int r = lane & 15, q = lane >> 4;
  f4 acc[8][4] = {};
  const int T = NC_ / 32;   // 40

  auto SA = [&](int bf, int k0, int p) {
    int cb = p * 512 + wid * 64;
    int cc = cb + lane;
    int row = cc >> 2, gc = (cc & 3) ^ ((row >> 1) & 3);
    gload16(Ab + (size_t)(m0 + row) * NC_ + k0 + gc * 8, (char*)(lds + bf * 8192) + cb * 16);
  };
  auto SB = [&](int bf, int k0, int p) {
    int cb = p * 512 + wid * 64;
    int cc = cb + lane;
    int row = cc >> 2, gc = (cc & 3) ^ ((row >> 1) & 3);
    gload16(Bb + (size_t)(n0 + row) * NC_ + k0 + gc * 8, (char*)(lds + 32768 + bf * 8192) + cb * 16);
  };
  auto STAGE = [&](int bf, int k0) { SA(bf, k0, 0); SA(bf, k0, 1); SB(bf, k0, 0); SB(bf, k0, 1); };

  STAGE(0, 0); STAGE(1, 32); STAGE(2, 64);
  for (int kt = 0; kt < T; ++kt) {
    if (kt + 3 < T) {
      STAGE((kt + 3) & 3, (kt + 3) * 32);
      asm volatile("s_waitcnt vmcnt(12)" ::: "memory");
    } else if (kt + 2 < T) {
      asm volatile("s_waitcnt vmcnt(8)" ::: "memory");
    } else if (kt + 1 < T) {
      asm volatile("s_waitcnt vmcnt(4)" ::: "memory");
    } else {
      asm volatile("s_waitcnt vmcnt(0)" ::: "memory");
    }
    __builtin_amdgcn_s_barrier();
    int cur = kt & 3;
    const short* Ar = lds + cur * 8192;
    const short* Br = lds + 32768 + cur * 8192;
    short8 fa[8], fb[4];
#pragma unroll
    for (int ni = 0; ni < 4; ++ni) {
      int row = wn * 64 + ni * 16 + r;
      fb[ni] = *(const short8*)(Br + row * 32 + ((q ^ ((row >> 1) & 3)) * 8));
    }
#pragma unroll
    for (int mi = 0; mi < 8; ++mi) {
      int row = wm * 128 + mi * 16 + r;
      fa[mi] = *(const short8*)(Ar + row * 32 + ((q ^ ((row >> 1) & 3)) * 8));
    }
    __builtin_amdgcn_s_setprio(1);
#pragma unroll
    for (int mi = 0; mi < 8; ++mi)
#pragma unroll
      for (int ni = 0; ni < 4; ++ni)
        acc[mi][ni] = __builtin_amdgcn_mfma_f32_16x16x32_bf16(fa[mi], fb[ni], acc[mi][ni], 0, 0, 0);
    __builtin_amdgcn_s_setprio(0);
    __builtin_amdgcn_s_barrier();
  }

#pragma unroll
  for (int ni = 0; ni < 4; ++ni) {
    int col = n0 + wn * 64 + ni * 16 + r;
    float bov = bo[col];
#pragma unroll
    for (int mi = 0; mi < 8; ++mi)
#pragma unroll
      for (int j = 0; j < 4; ++j) {
        int row = m0 + wm * 128 + mi * 16 + q * 4 + j;
        ob[(size_t)row * D_ + col] = acc[mi][ni][j] + bov;
      }
  }
}

extern "C" void kernel_launch(void* const* d_in, const int* in_sizes, int n_in,
                              void* d_out, int out_size, void* d_ws, size_t ws_size,
                              hipStream_t stream) {
  const float* hs  = (const float*)d_in[0];
  const float* ehs = (const float*)d_in[1];
  const float* Wq  = (const float*)d_in[2];
  const float* Wk  = (const float*)d_in[3];
  const float* Wv  = (const float*)d_in[4];
  const float* Wo  = (const float*)d_in[5];
  const float* bo  = (const float*)d_in[6];
  const float* Ak  = (const float*)d_in[7];
  const float* Bk  = (const float*)d_in[8];
  const float* Av  = (const float*)d_in[9];
  const float* Bv  = (const float*)d_in[10];
  const float* Ao  = (const float*)d_in[11];
  const float* Bo  = (const float*)d_in[12];
  const float* csf = (const float*)d_in[13];
  const int*   sb  = (const int*)d_in[14];
  const int*   sn  = (const int*)d_in[15];
  float* out = (float*)d_out;

  hipFuncSetAttribute(reinterpret_cast<const void*>(k_score_big),
                      hipFuncAttributeMaxDynamicSharedMemorySize, 147456);
  hipFuncSetAttribute(reinterpret_cast<const void*>(k_out_big),
                      hipFuncAttributeMaxDynamicSharedMemorySize, 131072);

  char* ws = (char*)d_ws;
  unsigned short* P  = (unsigned short*)ws;                   // 83,886,080
  unsigned short* Mt = (unsigned short*)(ws + 83886080);      // 20,971,520
  unsigned short* Ut = (unsigned short*)(ws + 104857600);     // 20,971,520
  const size_t NEED_HSB = 125829120ULL + 67108864ULL + 81920ULL; // 193,019,904
  bool useHsb = ws_size >= NEED_HSB;
  unsigned short* hsb = useHsb ? (unsigned short*)(ws + 125829120) : nullptr;
  char* tail = useHsb ? (ws + 192937984) : (ws + 125829120);
  float* alphav = (float*)tail;
  float* betav  = (float*)(tail + 40960);
  // temporaries overlapped into P's region (all dead before k_score writes P):
  float* kvbuf = (float*)(ws + 0);            //  5,242,880  [b][80][2048] (k|v)
  float* weff  = (float*)(ws + 5242880);      // 12,582,912  [wkE;wvE;woE]
  float* wqT   = (float*)(ws + 17825792);     //  4,194,304
  float* aT    = (float*)(ws + 22020096);     //  2,359,296
  float* part  = (float*)(ws + 24379392);     //  2,097,152
  float* hssum = (float*)(ws + 26476544);     //     32,768

  float* woE = weff + 2097152;
  float* akT = aT;
  float* avT = aT + 196608;
  float* aoT = aT + 393216;

  const float LS = 16.0f / 192.0f;

  // hs row-sums (deterministic two-stage) + bf16 conversion of hs
  k_hssum<<<dim3(64, 8), 256, 0, stream>>>(hs, part, hsb);
  k_hsred<<<32, 256, 0, stream>>>(part, hssum);

  // all transposes in one launch
  k_tr4<<<dim3(32, 32, 4), 256, 0, stream>>>(Wq, Ak, Av, Ao, wqT, akT, avT, aoT);

  // W_eff (k,v,o) in one launch
  k_weff<<<dim3(16, 16, 3), 256, 0, stream>>>(Bk, Bv, Bo, akT, avT, aoT, Wk, Wv, Wo, weff, LS);

  // [k|v] = ehs @ [wkE;wvE]^T : N=2048, C row-stride 2048
  k_gemm_small<false><<<dim3(2, 32, 8), 256, 0, stream>>>(
      ehs, 1024, 77L * 1024, 0, weff, 1024, 0, 0, kvbuf, 2048, 80L * 2048, 0, nullptr, 0,
      80, 77, 2048, 1024, 1.f, 1);

  // Mt[b,h] = 0.125 * k_bh @ Wq_h   (bf16, [b][h*80+s][d])
  k_gemm_small<true><<<dim3(2, 16, 128), 256, 0, stream>>>(
      kvbuf, 2048, 80L * 2048, 64L, wqT, 1024, 0, 64L,
      Mt, 1024, (long)NC_ * 1024, 80L * 1024, nullptr, 0,
      80, 80, 1024, 64, 0.125f, 16);

  // Ut[b,h] = woE_h @ v_bh^T   (bf16, [b][e][h*80+s])
  k_gemm_small<true><<<dim3(16, 2, 128), 256, 0, stream>>>(
      woE, 1024, 0, 64L, kvbuf + 1024, 2048, 80L * 2048, 64L,
      Ut, NC_, 1024L * NC_, 80L, nullptr, 0,
      1024, 1024, 80, 64, 1.f, 16);

  // per-(b,h,s) column mean (qmean fused) + subject alpha/beta
  k_mubeta<<<dim3(16, 8), 128, 0, stream>>>(hssum, Wq, kvbuf, sb, sn, csf, alphav, betav);

  // big fused GEMMs
  if (useHsb)
    k_score_big<<<512, 512, 147456, stream>>>(hsb, Mt, alphav, betav, P);
  else
    k_score_f32<<<2048, 256, 0, stream>>>(hs, Mt, alphav, betav, P);
  k_out_big<<<512, 512, 131072, stream>>>(P, Ut, bo, out);

  (void)in_sizes; (void)n_in; (void)out_size; (void)ws_size;
}

// Round 10
// 376.187 us; speedup vs baseline: 1.0397x; 1.0068x over previous
//
#include <hip/hip_runtime.h>
#include <stdint.h>

#define B_     8
#define LQ_    4096
#define S_     77
#define SP_    80
#define D_     1024
#define H_     16
#define HD_    64
#define NC_    1280   // H_*SP_
#define NSUBJ_ 32

typedef __attribute__((ext_vector_type(4))) float  f4;
typedef __attribute__((ext_vector_type(8))) short  short8;
typedef __attribute__((ext_vector_type(8))) unsigned short us8;
typedef __attribute__((ext_vector_type(4))) unsigned short us4;

__device__ __forceinline__ unsigned short f2bf(float f) {
  union { float f; unsigned u; } x; x.f = f;
  unsigned r = x.u + 0x7FFFu + ((x.u >> 16) & 1u);
  return (unsigned short)(r >> 16);
}

__device__ __forceinline__ void gload16(const void* g, void* s) {
  __builtin_amdgcn_global_load_lds((const __attribute__((address_space(1))) void*)g,
                                   (__attribute__((address_space(3))) void*)s, 16, 0, 0);
}

// ---------------- hssum partials + hs -> bf16 convert ----------------
__global__ __launch_bounds__(256) void k_hssum(const float* __restrict__ hs,
                                               float* __restrict__ part,
                                               unsigned short* __restrict__ hsb) {
  int b = blockIdx.y;
  size_t base = ((size_t)b * LQ_ + (size_t)blockIdx.x * 64) * D_ + threadIdx.x * 4;
  f4 acc = {0.f, 0.f, 0.f, 0.f};
  for (int l = 0; l < 64; ++l) {
    f4 v = *(const f4*)(hs + base + (size_t)l * D_);
    acc += v;
    if (hsb) {
      us4 o;
#pragma unroll
      for (int j = 0; j < 4; ++j) o[j] = f2bf(v[j]);
      *(us4*)(hsb + base + (size_t)l * D_) = o;
    }
  }
  *(f4*)(part + (size_t)blockIdx.x * (B_ * D_) + b * D_ + threadIdx.x * 4) = acc;
}

__global__ __launch_bounds__(256) void k_hsred(const float* __restrict__ part,
                                               float* __restrict__ hssum) {
  int i = blockIdx.x * 256 + threadIdx.x;   // [0, 8192)
  float s = 0.f;
  for (int x = 0; x < 64; ++x) s += part[(size_t)x * (B_ * D_) + i];
  hssum[i] = s;
}

// ---------------- 4 transposes (Wq 1024x1024, Ak/Av/Ao 192x1024) in one launch ----------------
__global__ __launch_bounds__(256) void k_tr4(const float* __restrict__ Wq, const float* __restrict__ Ak,
                                             const float* __restrict__ Av, const float* __restrict__ Ao,
                                             float* __restrict__ wqT, float* __restrict__ akT,
                                             float* __restrict__ avT, float* __restrict__ aoT) {
  int z = blockIdx.z;
  const float* in = z == 0 ? Wq : (z == 1 ? Ak : (z == 2 ? Av : Ao));
  float* out = z == 0 ? wqT : (z == 1 ? akT : (z == 2 ? avT : aoT));
  int R = z == 0 ? 1024 : 192;
  const int C = 1024;
  int c0 = blockIdx.x * 32, r0 = blockIdx.y * 32;
  if (r0 >= R) return;
  __shared__ float tile[32][33];
  int tx = threadIdx.x & 31, ty = threadIdx.x >> 5;
#pragma unroll
  for (int k = 0; k < 4; ++k)
    tile[ty + 8 * k][tx] = in[(size_t)(r0 + ty + 8 * k) * C + c0 + tx];
  __syncthreads();
#pragma unroll
  for (int k = 0; k < 4; ++k)
    out[(size_t)(c0 + ty + 8 * k) * R + r0 + tx] = tile[tx][ty + 8 * k];
}

// ---------------- shared 64x64-tile GEMM body: C = alpha*(A @ Bt^T) [+ Dm] ----------------
template <bool OBF>
__device__ __forceinline__ void gemm64_body(
    const float* __restrict__ A, int lda, const float* __restrict__ Bt, int ldb,
    void* __restrict__ Cv, int ldc, long cbase, const float* __restrict__ Dm, int ldd,
    int M, int Mv, int N, int K, float alpha, int m0, int n0,
    short* As, short* Bs) {
  int t = threadIdx.x, lane = t & 63, wid = t >> 6;
  int wm = wid >> 1, wn = wid & 1;
  f4 acc[2][2] = {};
  int srow = t >> 2, skc = (t & 3) * 8;
  for (int k0 = 0; k0 < K; k0 += 32) {
    __syncthreads();
    f4 a0 = {0,0,0,0}, a1 = {0,0,0,0}, b0 = {0,0,0,0}, b1 = {0,0,0,0};
    if (m0 + srow < Mv) {
      const float* p = A + (size_t)(m0 + srow) * lda + k0 + skc;
      a0 = *(const f4*)p; a1 = *(const f4*)(p + 4);
    }
    if (n0 + srow < N) {
      const float* p = Bt + (size_t)(n0 + srow) * ldb + k0 + skc;
      b0 = *(const f4*)p; b1 = *(const f4*)(p + 4);
    }
    us8 ua, ub;
#pragma unroll
    for (int j = 0; j < 4; ++j) {
      ua[j] = f2bf(a0[j]); ua[4 + j] = f2bf(a1[j]);
      ub[j] = f2bf(b0[j]); ub[4 + j] = f2bf(b1[j]);
    }
    *(us8*)(As + srow * 40 + skc) = ua;
    *(us8*)(Bs + srow * 40 + skc) = ub;
    __syncthreads();
    short8 fa[2], fb[2];
#pragma unroll
    for (int i = 0; i < 2; ++i) {
      fa[i] = *(const short8*)(As + (wm * 32 + i * 16 + (lane & 15)) * 40 + (lane >> 4) * 8);
      fb[i] = *(const short8*)(Bs + (wn * 32 + i * 16 + (lane & 15)) * 40 + (lane >> 4) * 8);
    }
#pragma unroll
    for (int mi = 0; mi < 2; ++mi)
#pragma unroll
      for (int ni = 0; ni < 2; ++ni)
        acc[mi][ni] = __builtin_amdgcn_mfma_f32_16x16x32_bf16(fa[mi], fb[ni], acc[mi][ni], 0, 0, 0);
  }
#pragma unroll
  for (int mi = 0; mi < 2; ++mi)
#pragma unroll
    for (int ni = 0; ni < 2; ++ni)
#pragma unroll
      for (int j = 0; j < 4; ++j) {
        int row = m0 + wm * 32 + mi * 16 + (lane >> 4) * 4 + j;
        int col = n0 + wn * 32 + ni * 16 + (lane & 15);
        if (row < M && col < N) {
          float val = acc[mi][ni][j] * alpha;
          if (Dm) val += Dm[(size_t)row * ldd + col];
          size_t idx = (size_t)cbase + (size_t)row * ldc + col;
          if (OBF) ((unsigned short*)Cv)[idx] = f2bf(val);
          else     ((float*)Cv)[idx] = val;
        }
      }
}

template <bool OBF>
__global__ __launch_bounds__(256) void k_gemm_small(
    const float* __restrict__ A, int lda, long sA1, long sA2,
    const float* __restrict__ Bt, int ldb, long sB1, long sB2,
    void* __restrict__ Cv, int ldc, long sC1, long sC2,
    const float* __restrict__ Dm, int ldd,
    int M, int Mv, int N, int K, float alpha, int Z2) {
  int z = blockIdx.z, z1 = z / Z2, z2 = z - z1 * Z2;
  __shared__ short As[64 * 40];
  __shared__ short Bs[64 * 40];
  gemm64_body<OBF>(A + z1 * sA1 + z2 * sA2, lda, Bt + z1 * sB1 + z2 * sB2, ldb,
                   Cv, ldc, z1 * sC1 + z2 * sC2, Dm, ldd, M, Mv, N, K, alpha,
                   blockIdx.x * 64, blockIdx.y * 64, As, Bs);
}

// W_eff = W + (1/12) Bx@Ax : three GEMMs in one launch (z selects k/v/o)
__global__ __launch_bounds__(256) void k_weff(
    const float* __restrict__ Bk, const float* __restrict__ Bv, const float* __restrict__ Bo,
    const float* __restrict__ akT, const float* __restrict__ avT, const float* __restrict__ aoT,
    const float* __restrict__ Wk, const float* __restrict__ Wv, const float* __restrict__ Wo,
    float* __restrict__ weff, float alpha) {
  int z = blockIdx.z;
  const float* A  = z == 0 ? Bk : (z == 1 ? Bv : Bo);
  const float* Bt = z == 0 ? akT : (z == 1 ? avT : aoT);
  const float* Dm = z == 0 ? Wk : (z == 1 ? Wv : Wo);
  __shared__ short As[64 * 40];
  __shared__ short Bs[64 * 40];
  gemm64_body<false>(A, 192, Bt, 192, weff + (size_t)z * 1048576, 1024, 0, Dm, 1024,
                     1024, 1024, 1024, 192, alpha, blockIdx.x * 64, blockIdx.y * 64, As, Bs);
}

// ---------------- mu/alpha/beta per (b,h,s), with qmean GEMM fused ----------------
__global__ void k_mubeta(const float* __restrict__ hssum, const float* __restrict__ Wq,
                         const float* __restrict__ kv,
                         const int* __restrict__ sb, const int* __restrict__ sn,
                         const float* __restrict__ csf_p,
                         float* __restrict__ alphav, float* __restrict__ betav) {
  int h = blockIdx.x, b = blockIdx.y;
  int t = threadIdx.x;                       // 128 threads
  __shared__ float qp[64];
  {
    int hd = t >> 1, half = t & 1;
    const float* wr = Wq + (size_t)(h * 64 + hd) * D_ + half * 512;
    const float* hp = hssum + b * D_ + half * 512;
    float s = 0.f;
    for (int d = 0; d < 512; d += 4) {
      f4 w = *(const f4*)(wr + d);
      f4 x = *(const f4*)(hp + d);
      s += w[0] * x[0] + w[1] * x[1] + w[2] * x[2] + w[3] * x[3];
    }
    s += __shfl_xor(s, 1, 64);
    if (half == 0) qp[hd] = s * (1.f / 4096.f);
  }
  __syncthreads();
  int s = t;
  if (s >= SP_) return;
  const float* kp = kv + ((size_t)(b * SP_ + s)) * 2048 + h * HD_;
  float mu = 0.f;
#pragma unroll 8
  for (int hd = 0; hd < HD_; ++hd) mu += qp[hd] * kp[hd];
  mu *= 0.125f;
  bool subj = false;
  for (int i = 0; i < NSUBJ_; ++i) subj = subj || (sb[i] == b && sn[i] == s);
  float csf = *csf_p;
  int c = b * NC_ + h * SP_ + s;
  alphav[c] = subj ? csf : 1.f;
  betav[c] = (s >= S_) ? -1e30f : (subj ? -mu * csf : 0.f);
}

// ---------------- score GEMM 256x320, BK=32, 4-buffer deep pipeline ----------------
// 3 tiles in flight; counted vmcnt never reaches 0 until the tail, so memory
// service time amortizes across 3 tiles of MFMA (AITER pattern). 8 waves 2Mx4N,
// wave tile 128x80 (one head per wave). R8's verified BK=32 XOR swizzle.
__global__ __launch_bounds__(512, 2) void k_score_big(
    const unsigned short* __restrict__ hsb, const unsigned short* __restrict__ Mt,
    const float* __restrict__ alphav, const float* __restrict__ betav,
    unsigned short* __restrict__ P) {
  extern __shared__ short lds[];
  // A: 4 bufs x 8192 shorts at 0; B: 4 bufs x 10240 shorts at 32768
  int id = blockIdx.x;
  int x = id & 7, idp = id >> 3;
  int nt = idp & 3;
  int pid = (idp >> 2) * 8 + x;    // [0,128)
  int b = pid >> 4, mt = pid & 15;
  int m0 = mt * 256, n0 = nt * 320;

  const unsigned short* Ab = hsb + (size_t)b * LQ_ * D_;
  const unsigned short* Bb = Mt + (size_t)b * NC_ * D_;
  const float* alp = alphav + b * NC_;
  const float* bet = betav + b * NC_;
  unsigned short* Pb = P + (size_t)b * LQ_ * NC_;

  int t = threadIdx.x, lane = t & 63, wid = t >> 6;   // 8 waves
  int wm = wid >> 2, wn = wid & 3;                    // 2M x 4N
  int r = lane & 15, q = lane >> 4;
  f4 acc[8][5] = {};

  auto SA = [&](int bf, int k0, int p) {     // A: 1024 chunks/tile, p in {0,1}
    int cb = p * 512 + wid * 64;
    int cc = cb + lane;
    int row = cc >> 2, gc = (cc & 3) ^ ((row >> 1) & 3);
    gload16(Ab + (size_t)(m0 + row) * D_ + k0 + gc * 8, (char*)(lds + bf * 8192) + cb * 16);
  };
  auto SB = [&](int bf, int k0, int p) {     // B: 1280 chunks/tile, p in {0,1,2}
    int cb = p * 512 + wid * 64;
    int cc = cb + lane;
    int row = cc >> 2, gc = (cc & 3) ^ ((row >> 1) & 3);
    gload16(Bb + (size_t)(n0 + row) * D_ + k0 + gc * 8, (char*)(lds + 32768 + bf * 10240) + cb * 16);
  };
  auto STAGE = [&](int bf, int k0) {         // wid<4: 5 loads; wid>=4: 4 loads
    SA(bf, k0, 0); SA(bf, k0, 1);
    SB(bf, k0, 0); SB(bf, k0, 1);
    if (wid < 4) { int cb = 1024 + wid * 64; int cc = cb + lane;
      int row = cc >> 2, gc = (cc & 3) ^ ((row >> 1) & 3);
      gload16(Bb + (size_t)(n0 + row) * D_ + k0 + gc * 8, (char*)(lds + 32768) + (size_t)bf * 20480 + cb * 16);
    }
  };

  const int T = 32;
  STAGE(0, 0); STAGE(1, 32); STAGE(2, 64);
  for (int kt = 0; kt < T; ++kt) {
    if (kt + 3 < T) {
      STAGE((kt + 3) & 3, (kt + 3) * 32);
      if (wid < 4) asm volatile("s_waitcnt vmcnt(15)" ::: "memory");
      else         asm volatile("s_waitcnt vmcnt(12)" ::: "memory");
    } else if (kt + 2 < T) {
      if (wid < 4) asm volatile("s_waitcnt vmcnt(10)" ::: "memory");
      else         asm volatile("s_waitcnt vmcnt(8)" ::: "memory");
    } else if (kt + 1 < T) {
      if (wid < 4) asm volatile("s_waitcnt vmcnt(5)" ::: "memory");
      else         asm volatile("s_waitcnt vmcnt(4)" ::: "memory");
    } else {
      asm volatile("s_waitcnt vmcnt(0)" ::: "memory");
    }
    __builtin_amdgcn_s_barrier();
    int cur = kt & 3;
    const short* Ar = lds + cur * 8192;
    const short* Br = lds + 32768 + cur * 10240;
    short8 fa[8], fb[5];
#pragma unroll
    for (int ni = 0; ni < 5; ++ni) {
      int row = wn * 80 + ni * 16 + r;
      fb[ni] = *(const short8*)(Br + row * 32 + ((q ^ ((row >> 1) & 3)) * 8));
    }
#pragma unroll
    for (int mi = 0; mi < 8; ++mi) {
      int row = wm * 128 + mi * 16 + r;
      fa[mi] = *(const short8*)(Ar + row * 32 + ((q ^ ((row >> 1) & 3)) * 8));
    }
    __builtin_amdgcn_s_setprio(1);
#pragma unroll
    for (int mi = 0; mi < 8; ++mi)
#pragma unroll
      for (int ni = 0; ni < 5; ++ni)
        acc[mi][ni] = __builtin_amdgcn_mfma_f32_16x16x32_bf16(fa[mi], fb[ni], acc[mi][ni], 0, 0, 0);
    __builtin_amdgcn_s_setprio(0);
    __builtin_amdgcn_s_barrier();   // all waves done reading buf before re-stage
  }

  // epilogue: alpha*score + beta, per-head softmax (wave owns one 80-col head)
  float al[5], be[5];
#pragma unroll
  for (int ni = 0; ni < 5; ++ni) {
    int cc = n0 + wn * 80 + ni * 16 + r;
    al[ni] = alp[cc]; be[ni] = bet[cc];
  }
#pragma unroll
  for (int mi = 0; mi < 8; ++mi) {
#pragma unroll
    for (int j = 0; j < 4; ++j) {
      float v[5];
      float m = -3.0e38f;
#pragma unroll
      for (int ni = 0; ni < 5; ++ni) { v[ni] = acc[mi][ni][j] * al[ni] + be[ni]; m = fmaxf(m, v[ni]); }
#pragma unroll
      for (int off = 1; off < 16; off <<= 1) m = fmaxf(m, __shfl_xor(m, off, 64));
      float ssum = 0.f;
#pragma unroll
      for (int ni = 0; ni < 5; ++ni) { v[ni] = __expf(v[ni] - m); ssum += v[ni]; }
#pragma unroll
      for (int off = 1; off < 16; off <<= 1) ssum += __shfl_xor(ssum, off, 64);
      float inv = 1.f / ssum;
      int row = m0 + wm * 128 + mi * 16 + q * 4 + j;
      size_t rb = (size_t)row * NC_ + n0 + wn * 80 + r;
#pragma unroll
      for (int ni = 0; ni < 5; ++ni)
        Pb[rb + ni * 16] = f2bf(v[ni] * inv);
    }
  }
}

// ---------------- fallback score GEMM (fp32 A, reg-staged), 128x160, 256 thr ----------------
__global__ __launch_bounds__(256) void k_score_f32(
    const float* __restrict__ hs, const unsigned short* __restrict__ Mt,
    const float* __restrict__ alphav, const float* __restrict__ betav,
    unsigned short* __restrict__ P) {
  int id = blockIdx.x;
  int x = id & 7, idp = id >> 3;
  int n_t = idp & 7;
  int pid = (idp >> 3) * 8 + x;
  int b = pid >> 5, m_t = pid & 31;
  int m0 = m_t * 128, n0 = n_t * 160;
  const float* Af = hs + (size_t)b * LQ_ * D_;
  const unsigned short* Bb = Mt + (size_t)b * NC_ * D_;
  const float* alp = alphav + b * NC_;
  const float* bet = betav + b * NC_;
  unsigned short* Pb = P + (size_t)b * LQ_ * NC_;
  __shared__ short As[128 * 64];
  __shared__ short Bs[160 * 64];
  int t = threadIdx.x, lane = t & 63, wid = t >> 6;
  int wm = wid >> 1, wn = wid & 1;
  int srow = lane >> 3;
  int schunk = (lane & 7) ^ srow;
  f4 acc[4][5] = {};
  for (int k0 = 0; k0 < D_; k0 += 64) {
    __syncthreads();
    for (int i = wid; i < 20; i += 4)
      gload16(Bb + (size_t)(n0 + i * 8 + srow) * D_ + k0 + schunk * 8, (char*)Bs + i * 1024);
    int arow = t >> 3, ac = t & 7;
    int awc = ac ^ (arow & 7);
#pragma unroll
    for (int p = 0; p < 4; ++p) {
      int row = p * 32 + arow;
      const float* src = Af + (size_t)(m0 + row) * D_ + k0 + ac * 8;
      f4 v0 = *(const f4*)src;
      f4 v1 = *(const f4*)(src + 4);
      us8 u;
#pragma unroll
      for (int j = 0; j < 4; ++j) { u[j] = f2bf(v0[j]); u[4 + j] = f2bf(v1[j]); }
      *(us8*)(As + row * 64 + awc * 8) = u;
    }
    __syncthreads();
#pragma unroll
    for (int kk = 0; kk < 2; ++kk) {
      int co = ((kk * 4 + (lane >> 4)) ^ (lane & 7)) * 8;
      short8 fa[4], fb[5];
#pragma unroll
      for (int mi = 0; mi < 4; ++mi)
        fa[mi] = *(const short8*)(As + (wm * 64 + mi * 16 + (lane & 15)) * 64 + co);
#pragma unroll
      for (int ni = 0; ni < 5; ++ni)
        fb[ni] = *(const short8*)(Bs + (wn * 80 + ni * 16 + (lane & 15)) * 64 + co);
#pragma unroll
      for (int mi = 0; mi < 4; ++mi)
#pragma unroll
        for (int ni = 0; ni < 5; ++ni)
          acc[mi][ni] = __builtin_amdgcn_mfma_f32_16x16x32_bf16(fa[mi], fb[ni], acc[mi][ni], 0, 0, 0);
    }
  }
  float al[5], be[5];
#pragma unroll
  for (int ni = 0; ni < 5; ++ni) {
    int cc = n0 + wn * 80 + ni * 16 + (lane & 15);
    al[ni] = alp[cc]; be[ni] = bet[cc];
  }
#pragma unroll
  for (int mi = 0; mi < 4; ++mi) {
#pragma unroll
    for (int j = 0; j < 4; ++j) {
      float v[5];
      float m = -3.0e38f;
#pragma unroll
      for (int ni = 0; ni < 5; ++ni) { v[ni] = acc[mi][ni][j] * al[ni] + be[ni]; m = fmaxf(m, v[ni]); }
#pragma unroll
      for (int off = 1; off < 16; off <<= 1) m = fmaxf(m, __shfl_xor(m, off, 64));
      float ssum = 0.f;
#pragma unroll
      for (int ni = 0; ni < 5; ++ni) { v[ni] = __expf(v[ni] - m); ssum += v[ni]; }
#pragma unroll
      for (int off = 1; off < 16; off <<= 1) ssum += __shfl_xor(ssum, off, 64);
      float inv = 1.f / ssum;
      int row = m0 + wm * 64 + mi * 16 + (lane >> 4) * 4 + j;
      size_t rb = (size_t)row * NC_ + n0 + wn * 80 + (lane & 15);
#pragma unroll
      for (int ni = 0; ni < 5; ++ni)
        Pb[rb + ni * 16] = f2bf(v[ni] * inv);
    }
  }
}

// ---------------- out GEMM 256x256, BK=32, 4-buffer deep pipeline ----------------
__global__ __launch_bounds__(512, 2) void k_out_big(
    const unsigned short* __restrict__ P, const unsigned short* __restrict__ Ut,
    const float* __restrict__ bo, float* __restrict__ out) {
  extern __shared__ short lds[];
  // A: 4 bufs x 8192 at 0; B: 4 bufs x 8192 at 32768
  int id = blockIdx.x;
  int x = id & 7, idp = id >> 3;
  int nt = idp & 3;
  int pid = (idp >> 2) * 8 + x;
  int b = pid >> 4, mt = pid & 15;
  int m0 = mt * 256, n0 = nt * 256;

  const unsigned short* Ab = P + (size_t)b * LQ_ * NC_;
  const unsigned short* Bb = Ut + (size_t)b * D_ * NC_;
  float* ob = out + (size_t)b * LQ_ * D_;

  int t = threadIdx.x, lane = t & 63, wid = t >> 6;
  int wm = wid >> 2, wn = wid & 3;
  int r = lane & 15, q = lane >> 4;
  f4 acc[8][4] = {};
  const int T = NC_ / 32;   // 40

  auto SA = [&](int bf, int k0, int p) {
    int cb = p * 512 + wid * 64;
    int cc = cb + lane;
    int row = cc >> 2, gc = (cc & 3) ^ ((row >> 1) & 3);
    gload16(Ab + (size_t)(m0 + row) * NC_ + k0 + gc * 8, (char*)(lds + bf * 8192) + cb * 16);
  };
  auto SB = [&](int bf, int k0, int p) {
    int cb = p * 512 + wid * 64;
    int cc = cb + lane;
    int row = cc >> 2, gc = (cc & 3) ^ ((row >> 1) & 3);
    gload16(Bb + (size_t)(n0 + row) * NC_ + k0 + gc * 8, (char*)(lds + 32768 + bf * 8192) + cb * 16);
  };
  auto STAGE = [&](int bf, int k0) { SA(bf, k0, 0); SA(bf, k0, 1); SB(bf, k0, 0); SB(bf, k0, 1); };

  STAGE(0, 0); STAGE(1, 32); STAGE(2, 64);
  for (int kt = 0; kt < T; ++kt) {
    if (kt + 3 < T) {
      STAGE((kt + 3) & 3, (kt + 3) * 32);
      asm volatile("s_waitcnt vmcnt(12)" ::: "memory");
    } else if (kt + 2 < T) {
      asm volatile("s_waitcnt vmcnt(8)" ::: "memory");
    } else if (kt + 1 < T) {
      asm volatile("s_waitcnt vmcnt(4)" ::: "memory");
    } else {
      asm volatile("s_waitcnt vmcnt(0)" ::: "memory");
    }
    __builtin_amdgcn_s_barrier();
    int cur = kt & 3;
    const short* Ar = lds + cur * 8192;
    const short* Br = lds + 32768 + cur * 8192;
    short8 fa[8], fb[4];
#pragma unroll
    for (int ni = 0; ni < 4; ++ni) {
      int row = wn * 64 + ni * 16 + r;
      fb[ni] = *(const short8*)(Br + row * 32 + ((q ^ ((row >> 1) & 3)) * 8));
    }
#pragma unroll
    for (int mi = 0; mi < 8; ++mi) {
      int row = wm * 128 + mi * 16 + r;
      fa[mi] = *(const short8*)(Ar + row * 32 + ((q ^ ((row >> 1) & 3)) * 8));
    }
    __builtin_amdgcn_s_setprio(1);
#pragma unroll
    for (int mi = 0; mi < 8; ++mi)
#pragma unroll
      for (int ni = 0; ni < 4; ++ni)
        acc[mi][ni] = __builtin_amdgcn_mfma_f32_16x16x32_bf16(fa[mi], fb[ni], acc[mi][ni], 0, 0, 0);
    __builtin_amdgcn_s_setprio(0);
    __builtin_amdgcn_s_barrier();
  }

#pragma unroll
  for (int ni = 0; ni < 4; ++ni) {
    int col = n0 + wn * 64 + ni * 16 + r;
    float bov = bo[col];
#pragma unroll
    for (int mi = 0; mi < 8; ++mi)
#pragma unroll
      for (int j = 0; j < 4; ++j) {
        int row = m0 + wm * 128 + mi * 16 + q * 4 + j;
        ob[(size_t)row * D_ + col] = acc[mi][ni][j] + bov;
      }
  }
}

extern "C" void kernel_launch(void* const* d_in, const int* in_sizes, int n_in,
                              void* d_out, int out_size, void* d_ws, size_t ws_size,
                              hipStream_t stream) {
  const float* hs  = (const float*)d_in[0];
  const float* ehs = (const float*)d_in[1];
  const float* Wq  = (const float*)d_in[2];
  const float* Wk  = (const float*)d_in[3];
  const float* Wv  = (const float*)d_in[4];
  const float* Wo  = (const float*)d_in[5];
  const float* bo  = (const float*)d_in[6];
  const float* Ak  = (const float*)d_in[7];
  const float* Bk  = (const float*)d_in[8];
  const float* Av  = (const float*)d_in[9];
  const float* Bv  = (const float*)d_in[10];
  const float* Ao  = (const float*)d_in[11];
  const float* Bo  = (const float*)d_in[12];
  const float* csf = (const float*)d_in[13];
  const int*   sb  = (const int*)d_in[14];
  const int*   sn  = (const int*)d_in[15];
  float* out = (float*)d_out;

  hipFuncSetAttribute(reinterpret_cast<const void*>(k_score_big),
                      hipFuncAttributeMaxDynamicSharedMemorySize, 147456);
  hipFuncSetAttribute(reinterpret_cast<const void*>(k_out_big),
                      hipFuncAttributeMaxDynamicSharedMemorySize, 131072);

  char* ws = (char*)d_ws;
  unsigned short* P  = (unsigned short*)ws;                   // 83,886,080
  unsigned short* Mt = (unsigned short*)(ws + 83886080);      // 20,971,520
  unsigned short* Ut = (unsigned short*)(ws + 104857600);     // 20,971,520
  const size_t NEED_HSB = 125829120ULL + 67108864ULL + 81920ULL; // 193,019,904
  bool useHsb = ws_size >= NEED_HSB;
  unsigned short* hsb = useHsb ? (unsigned short*)(ws + 125829120) : nullptr;
  char* tail = useHsb ? (ws + 192937984) : (ws + 125829120);
  float* alphav = (float*)tail;
  float* betav  = (float*)(tail + 40960);
  // temporaries overlapped into P's region (all dead before k_score writes P):
  float* kvbuf = (float*)(ws + 0);            //  5,242,880  [b][80][2048] (k|v)
  float* weff  = (float*)(ws + 5242880);      // 12,582,912  [wkE;wvE;woE]
  float* wqT   = (float*)(ws + 17825792);     //  4,194,304
  float* aT    = (float*)(ws + 22020096);     //  2,359,296
  float* part  = (float*)(ws + 24379392);     //  2,097,152
  float* hssum = (float*)(ws + 26476544);     //     32,768

  float* woE = weff + 2097152;
  float* akT = aT;
  float* avT = aT + 196608;
  float* aoT = aT + 393216;

  const float LS = 16.0f / 192.0f;

  // hs row-sums (deterministic two-stage) + bf16 conversion of hs
  k_hssum<<<dim3(64, 8), 256, 0, stream>>>(hs, part, hsb);
  k_hsred<<<32, 256, 0, stream>>>(part, hssum);

  // all transposes in one launch
  k_tr4<<<dim3(32, 32, 4), 256, 0, stream>>>(Wq, Ak, Av, Ao, wqT, akT, avT, aoT);

  // W_eff (k,v,o) in one launch
  k_weff<<<dim3(16, 16, 3), 256, 0, stream>>>(Bk, Bv, Bo, akT, avT, aoT, Wk, Wv, Wo, weff, LS);

  // [k|v] = ehs @ [wkE;wvE]^T : N=2048, C row-stride 2048
  k_gemm_small<false><<<dim3(2, 32, 8), 256, 0, stream>>>(
      ehs, 1024, 77L * 1024, 0, weff, 1024, 0, 0, kvbuf, 2048, 80L * 2048, 0, nullptr, 0,
      80, 77, 2048, 1024, 1.f, 1);

  // Mt[b,h] = 0.125 * k_bh @ Wq_h   (bf16, [b][h*80+s][d])
  k_gemm_small<true><<<dim3(2, 16, 128), 256, 0, stream>>>(
      kvbuf, 2048, 80L * 2048, 64L, wqT, 1024, 0, 64L,
      Mt, 1024, (long)NC_ * 1024, 80L * 1024, nullptr, 0,
      80, 80, 1024, 64, 0.125f, 16);

  // Ut[b,h] = woE_h @ v_bh^T   (bf16, [b][e][h*80+s])
  k_gemm_small<true><<<dim3(16, 2, 128), 256, 0, stream>>>(
      woE, 1024, 0, 64L, kvbuf + 1024, 2048, 80L * 2048, 64L,
      Ut, NC_, 1024L * NC_, 80L, nullptr, 0,
      1024, 1024, 80, 64, 1.f, 16);

  // per-(b,h,s) column mean (qmean fused) + subject alpha/beta
  k_mubeta<<<dim3(16, 8), 128, 0, stream>>>(hssum, Wq, kvbuf, sb, sn, csf, alphav, betav);

  // big fused GEMMs
  if (useHsb)
    k_score_big<<<512, 512, 147456, stream>>>(hsb, Mt, alphav, betav, P);
  else
    k_score_f32<<<2048, 256, 0, stream>>>(hs, Mt, alphav, betav, P);
  k_out_big<<<512, 512, 131072, stream>>>(P, Ut, bo, out);

  (void)in_sizes; (void)n_in; (void)out_size; (void)ws_size;
}

// Round 12
// 373.446 us; speedup vs baseline: 1.0474x; 1.0073x over previous
//
#include <hip/hip_runtime.h>
#include <stdint.h>

#define B_     8
#define LQ_    4096
#define S_     77
#define SP_    80
#define D_     1024
#define H_     16
#define HD_    64
#define NC_    1280   // H_*SP_
#define NSUBJ_ 32

typedef __attribute__((ext_vector_type(4))) float  f4;
typedef __attribute__((ext_vector_type(8))) short  short8;
typedef __attribute__((ext_vector_type(8))) unsigned short us8;
typedef __attribute__((ext_vector_type(4))) unsigned short us4;

__device__ __forceinline__ unsigned short f2bf(float f) {
  union { float f; unsigned u; } x; x.f = f;
  unsigned r = x.u + 0x7FFFu + ((x.u >> 16) & 1u);
  return (unsigned short)(r >> 16);
}

__device__ __forceinline__ void gload16(const void* g, void* s) {
  __builtin_amdgcn_global_load_lds((const __attribute__((address_space(1))) void*)g,
                                   (__attribute__((address_space(3))) void*)s, 16, 0, 0);
}

// ---------------- hssum partials + hs -> bf16 convert ----------------
__global__ __launch_bounds__(256) void k_hssum(const float* __restrict__ hs,
                                               float* __restrict__ part,
                                               unsigned short* __restrict__ hsb) {
  int b = blockIdx.y;
  size_t base = ((size_t)b * LQ_ + (size_t)blockIdx.x * 64) * D_ + threadIdx.x * 4;
  f4 acc = {0.f, 0.f, 0.f, 0.f};
  for (int l = 0; l < 64; ++l) {
    f4 v = *(const f4*)(hs + base + (size_t)l * D_);
    acc += v;
    if (hsb) {
      us4 o;
#pragma unroll
      for (int j = 0; j < 4; ++j) o[j] = f2bf(v[j]);
      *(us4*)(hsb + base + (size_t)l * D_) = o;
    }
  }
  *(f4*)(part + (size_t)blockIdx.x * (B_ * D_) + b * D_ + threadIdx.x * 4) = acc;
}

__global__ __launch_bounds__(256) void k_hsred(const float* __restrict__ part,
                                               float* __restrict__ hssum) {
  int i = blockIdx.x * 256 + threadIdx.x;   // [0, 8192)
  float s = 0.f;
  for (int x = 0; x < 64; ++x) s += part[(size_t)x * (B_ * D_) + i];
  hssum[i] = s;
}

// ---------------- 4 transposes (Wq 1024x1024, Ak/Av/Ao 192x1024) in one launch ----------------
__global__ __launch_bounds__(256) void k_tr4(const float* __restrict__ Wq, const float* __restrict__ Ak,
                                             const float* __restrict__ Av, const float* __restrict__ Ao,
                                             float* __restrict__ wqT, float* __restrict__ akT,
                                             float* __restrict__ avT, float* __restrict__ aoT) {
  int z = blockIdx.z;
  const float* in = z == 0 ? Wq : (z == 1 ? Ak : (z == 2 ? Av : Ao));
  float* out = z == 0 ? wqT : (z == 1 ? akT : (z == 2 ? avT : aoT));
  int R = z == 0 ? 1024 : 192;
  const int C = 1024;
  int c0 = blockIdx.x * 32, r0 = blockIdx.y * 32;
  if (r0 >= R) return;
  __shared__ float tile[32][33];
  int tx = threadIdx.x & 31, ty = threadIdx.x >> 5;
#pragma unroll
  for (int k = 0; k < 4; ++k)
    tile[ty + 8 * k][tx] = in[(size_t)(r0 + ty + 8 * k) * C + c0 + tx];
  __syncthreads();
#pragma unroll
  for (int k = 0; k < 4; ++k)
    out[(size_t)(c0 + ty + 8 * k) * R + r0 + tx] = tile[tx][ty + 8 * k];
}

// ---------------- shared 64x64-tile GEMM body: C = alpha*(A @ Bt^T) [+ Dm] ----------------
template <bool OBF>
__device__ __forceinline__ void gemm64_body(
    const float* __restrict__ A, int lda, const float* __restrict__ Bt, int ldb,
    void* __restrict__ Cv, int ldc, long cbase, const float* __restrict__ Dm, int ldd,
    int M, int Mv, int N, int K, float alpha, int m0, int n0,
    short* As, short* Bs) {
  int t = threadIdx.x, lane = t & 63, wid = t >> 6;
  int wm = wid >> 1, wn = wid & 1;
  f4 acc[2][2] = {};
  int srow = t >> 2, skc = (t & 3) * 8;
  for (int k0 = 0; k0 < K; k0 += 32) {
    __syncthreads();
    f4 a0 = {0,0,0,0}, a1 = {0,0,0,0}, b0 = {0,0,0,0}, b1 = {0,0,0,0};
    if (m0 + srow < Mv) {
      const float* p = A + (size_t)(m0 + srow) * lda + k0 + skc;
      a0 = *(const f4*)p; a1 = *(const f4*)(p + 4);
    }
    if (n0 + srow < N) {
      const float* p = Bt + (size_t)(n0 + srow) * ldb + k0 + skc;
      b0 = *(const f4*)p; b1 = *(const f4*)(p + 4);
    }
    us8 ua, ub;
#pragma unroll
    for (int j = 0; j < 4; ++j) {
      ua[j] = f2bf(a0[j]); ua[4 + j] = f2bf(a1[j]);
      ub[j] = f2bf(b0[j]); ub[4 + j] = f2bf(b1[j]);
    }
    *(us8*)(As + srow * 40 + skc) = ua;
    *(us8*)(Bs + srow * 40 + skc) = ub;
    __syncthreads();
    short8 fa[2], fb[2];
#pragma unroll
    for (int i = 0; i < 2; ++i) {
      fa[i] = *(const short8*)(As + (wm * 32 + i * 16 + (lane & 15)) * 40 + (lane >> 4) * 8);
      fb[i] = *(const short8*)(Bs + (wn * 32 + i * 16 + (lane & 15)) * 40 + (lane >> 4) * 8);
    }
#pragma unroll
    for (int mi = 0; mi < 2; ++mi)
#pragma unroll
      for (int ni = 0; ni < 2; ++ni)
        acc[mi][ni] = __builtin_amdgcn_mfma_f32_16x16x32_bf16(fa[mi], fb[ni], acc[mi][ni], 0, 0, 0);
  }
#pragma unroll
  for (int mi = 0; mi < 2; ++mi)
#pragma unroll
    for (int ni = 0; ni < 2; ++ni)
#pragma unroll
      for (int j = 0; j < 4; ++j) {
        int row = m0 + wm * 32 + mi * 16 + (lane >> 4) * 4 + j;
        int col = n0 + wn * 32 + ni * 16 + (lane & 15);
        if (row < M && col < N) {
          float val = acc[mi][ni][j] * alpha;
          if (Dm) val += Dm[(size_t)row * ldd + col];
          size_t idx = (size_t)cbase + (size_t)row * ldc + col;
          if (OBF) ((unsigned short*)Cv)[idx] = f2bf(val);
          else     ((float*)Cv)[idx] = val;
        }
      }
}

template <bool OBF>
__global__ __launch_bounds__(256) void k_gemm_small(
    const float* __restrict__ A, int lda, long sA1, long sA2,
    const float* __restrict__ Bt, int ldb, long sB1, long sB2,
    void* __restrict__ Cv, int ldc, long sC1, long sC2,
    const float* __restrict__ Dm, int ldd,
    int M, int Mv, int N, int K, float alpha, int Z2) {
  int z = blockIdx.z, z1 = z / Z2, z2 = z - z1 * Z2;
  __shared__ short As[64 * 40];
  __shared__ short Bs[64 * 40];
  gemm64_body<OBF>(A + z1 * sA1 + z2 * sA2, lda, Bt + z1 * sB1 + z2 * sB2, ldb,
                   Cv, ldc, z1 * sC1 + z2 * sC2, Dm, ldd, M, Mv, N, K, alpha,
                   blockIdx.x * 64, blockIdx.y * 64, As, Bs);
}

// W_eff = W + (1/12) Bx@Ax : three GEMMs in one launch (z selects k/v/o)
__global__ __launch_bounds__(256) void k_weff(
    const float* __restrict__ Bk, const float* __restrict__ Bv, const float* __restrict__ Bo,
    const float* __restrict__ akT, const float* __restrict__ avT, const float* __restrict__ aoT,
    const float* __restrict__ Wk, const float* __restrict__ Wv, const float* __restrict__ Wo,
    float* __restrict__ weff, float alpha) {
  int z = blockIdx.z;
  const float* A  = z == 0 ? Bk : (z == 1 ? Bv : Bo);
  const float* Bt = z == 0 ? akT : (z == 1 ? avT : aoT);
  const float* Dm = z == 0 ? Wk : (z == 1 ? Wv : Wo);
  __shared__ short As[64 * 40];
  __shared__ short Bs[64 * 40];
  gemm64_body<false>(A, 192, Bt, 192, weff + (size_t)z * 1048576, 1024, 0, Dm, 1024,
                     1024, 1024, 1024, 192, alpha, blockIdx.x * 64, blockIdx.y * 64, As, Bs);
}

// ---------------- mu/alpha/beta per (b,h,s), with qmean GEMM fused ----------------
__global__ void k_mubeta(const float* __restrict__ hssum, const float* __restrict__ Wq,
                         const float* __restrict__ kv,
                         const int* __restrict__ sb, const int* __restrict__ sn,
                         const float* __restrict__ csf_p,
                         float* __restrict__ alphav, float* __restrict__ betav) {
  int h = blockIdx.x, b = blockIdx.y;
  int t = threadIdx.x;                       // 128 threads
  __shared__ float qp[64];
  {
    int hd = t >> 1, half = t & 1;
    const float* wr = Wq + (size_t)(h * 64 + hd) * D_ + half * 512;
    const float* hp = hssum + b * D_ + half * 512;
    float s = 0.f;
    for (int d = 0; d < 512; d += 4) {
      f4 w = *(const f4*)(wr + d);
      f4 x = *(const f4*)(hp + d);
      s += w[0] * x[0] + w[1] * x[1] + w[2] * x[2] + w[3] * x[3];
    }
    s += __shfl_xor(s, 1, 64);
    if (half == 0) qp[hd] = s * (1.f / 4096.f);
  }
  __syncthreads();
  int s = t;
  if (s >= SP_) return;
  const float* kp = kv + ((size_t)(b * SP_ + s)) * 2048 + h * HD_;
  float mu = 0.f;
#pragma unroll 8
  for (int hd = 0; hd < HD_; ++hd) mu += qp[hd] * kp[hd];
  mu *= 0.125f;
  bool subj = false;
  for (int i = 0; i < NSUBJ_; ++i) subj = subj || (sb[i] == b && sn[i] == s);
  float csf = *csf_p;
  int c = b * NC_ + h * SP_ + s;
  alphav[c] = subj ? csf : 1.f;
  betav[c] = (s >= S_) ? -1e30f : (subj ? -mu * csf : 0.f);
}

// ---------------- score GEMM 256x320, m201 cell: half-K(32) x 4 bufs, ----------------
// 2 phases/half-tile {reads-before-barrier; stage-part; barrier; lgkm0; setprio MFMA},
// ONE counted vmcnt per half-tile proving the NEXT half-tile — never 0 in the loop.
__global__ __launch_bounds__(512, 2) void k_score_big(
    const unsigned short* __restrict__ hsb, const unsigned short* __restrict__ Mt,
    const float* __restrict__ alphav, const float* __restrict__ betav,
    unsigned short* __restrict__ P) {
  extern __shared__ short lds[];
  // A: 4 bufs x 8192 shorts at 0; B: 4 bufs x 10240 shorts at 32768 (144KB)
  int id = blockIdx.x;
  int x = id & 7, idp = id >> 3;
  int nt = idp & 3;
  int pid = (idp >> 2) * 8 + x;    // [0,128)
  int b = pid >> 4, mt = pid & 15;
  int m0 = mt * 256, n0 = nt * 320;

  const unsigned short* Ab = hsb + (size_t)b * LQ_ * D_;
  const unsigned short* Bb = Mt + (size_t)b * NC_ * D_;
  const float* alp = alphav + b * NC_;
  const float* bet = betav + b * NC_;
  unsigned short* Pb = P + (size_t)b * LQ_ * NC_;

  int t = threadIdx.x, lane = t & 63, wid = t >> 6;   // 8 waves
  int wm = wid >> 2, wn = wid & 3;                    // 2M x 4N, wave tile 128x80
  int r = lane & 15, q = lane >> 4;
  f4 acc[8][5] = {};

  auto SA = [&](int bf, int k0, int p) {     // A: 1024 chunks/half-tile
    int cb = p * 512 + wid * 64;
    int cc = cb + lane;
    int row = cc >> 2, gc = (cc & 3) ^ ((row >> 1) & 3);
    gload16(Ab + (size_t)(m0 + row) * D_ + k0 + gc * 8, (char*)(lds + bf * 8192) + cb * 16);
  };
  auto SB = [&](int bf, int k0, int p) {     // B: chunks p*512..p*512+511
    int cb = p * 512 + wid * 64;
    int cc = cb + lane;
    int row = cc >> 2, gc = (cc & 3) ^ ((row >> 1) & 3);
    gload16(Bb + (size_t)(n0 + row) * D_ + k0 + gc * 8, (char*)(lds + 32768 + bf * 10240) + cb * 16);
  };
  auto SBx = [&](int bf, int k0) {           // B: chunks 1024..1279 (wid<4)
    if (wid < 4) {
      int cb = 1024 + wid * 64;
      int cc = cb + lane;
      int row = cc >> 2, gc = (cc & 3) ^ ((row >> 1) & 3);
      gload16(Bb + (size_t)(n0 + row) * D_ + k0 + gc * 8, (char*)(lds + 32768 + bf * 10240) + cb * 16);
    }
  };
  // per-thread loads per full stage: wid<4: 5, wid>=4: 4
  auto STAGE_P1 = [&](int h) { if (h < 32) { int bf = h & 3, k0 = h * 32; SA(bf, k0, 0); SA(bf, k0, 1); SB(bf, k0, 0); } };
  auto STAGE_P2 = [&](int h) { if (h < 32) { int bf = h & 3, k0 = h * 32; SB(bf, k0, 1); SBx(bf, k0); } };

  // prologue: stage h=0,1,2 fully; prove h=0 (counted); sync
  STAGE_P1(0); STAGE_P2(0);
  STAGE_P1(1); STAGE_P2(1);
  STAGE_P1(2); STAGE_P2(2);
  if (wid < 4) asm volatile("s_waitcnt vmcnt(10)" ::: "memory");
  else         asm volatile("s_waitcnt vmcnt(8)" ::: "memory");
  __builtin_amdgcn_s_barrier();

#pragma unroll 1
  for (int h = 0; h < 32; ++h) {
    int bf = h & 3;
    const short* Ar = lds + bf * 8192;
    const short* Br = lds + 32768 + bf * 10240;
    short8 fa[4], fb[5];

    // ---- phase A: reads || stage part1; barrier; lgkm0; MFMA lo ----
#pragma unroll
    for (int ni = 0; ni < 5; ++ni) {
      int row = wn * 80 + ni * 16 + r;
      fb[ni] = *(const short8*)(Br + row * 32 + ((q ^ ((row >> 1) & 3)) * 8));
    }
#pragma unroll
    for (int mi = 0; mi < 4; ++mi) {
      int row = wm * 128 + mi * 16 + r;
      fa[mi] = *(const short8*)(Ar + row * 32 + ((q ^ ((row >> 1) & 3)) * 8));
    }
    __builtin_amdgcn_sched_barrier(0);
    STAGE_P1(h + 3);
    __builtin_amdgcn_sched_barrier(0);
    __builtin_amdgcn_s_barrier();
    asm volatile("s_waitcnt lgkmcnt(0)");
    __builtin_amdgcn_s_setprio(1);
#pragma unroll
    for (int mi = 0; mi < 4; ++mi)
#pragma unroll
      for (int ni = 0; ni < 5; ++ni)
        acc[mi][ni] = __builtin_amdgcn_mfma_f32_16x16x32_bf16(fa[mi], fb[ni], acc[mi][ni], 0, 0, 0);
    __builtin_amdgcn_s_setprio(0);

    // ---- phase B: reads fa_hi || stage part2; barrier; lgkm0; MFMA hi ----
#pragma unroll
    for (int mi = 0; mi < 4; ++mi) {
      int row = wm * 128 + (4 + mi) * 16 + r;
      fa[mi] = *(const short8*)(Ar + row * 32 + ((q ^ ((row >> 1) & 3)) * 8));
    }
    __builtin_amdgcn_sched_barrier(0);
    STAGE_P2(h + 3);
    __builtin_amdgcn_sched_barrier(0);
    __builtin_amdgcn_s_barrier();
    asm volatile("s_waitcnt lgkmcnt(0)");
    __builtin_amdgcn_s_setprio(1);
#pragma unroll
    for (int mi = 0; mi < 4; ++mi)
#pragma unroll
      for (int ni = 0; ni < 5; ++ni)
        acc[4 + mi][ni] = __builtin_amdgcn_mfma_f32_16x16x32_bf16(fa[mi], fb[ni], acc[4 + mi][ni], 0, 0, 0);
    __builtin_amdgcn_s_setprio(0);

    // ---- half-tile end: prove S(h+1) with a COUNTED wait (never 0 until tail) ----
    if (h <= 28) {
      if (wid < 4) asm volatile("s_waitcnt vmcnt(10)" ::: "memory");
      else         asm volatile("s_waitcnt vmcnt(8)" ::: "memory");
    } else if (h == 29) {
      if (wid < 4) asm volatile("s_waitcnt vmcnt(5)" ::: "memory");
      else         asm volatile("s_waitcnt vmcnt(4)" ::: "memory");
    } else if (h == 30) {
      asm volatile("s_waitcnt vmcnt(0)" ::: "memory");
    }
    if (h < 31) __builtin_amdgcn_s_barrier();
  }

  // epilogue: alpha*score + beta, per-head softmax (wave owns one 80-col head)
  float al[5], be[5];
#pragma unroll
  for (int ni = 0; ni < 5; ++ni) {
    int cc = n0 + wn * 80 + ni * 16 + r;
    al[ni] = alp[cc]; be[ni] = bet[cc];
  }
#pragma unroll
  for (int mi = 0; mi < 8; ++mi) {
#pragma unroll
    for (int j = 0; j < 4; ++j) {
      float v[5];
      float m = -3.0e38f;
#pragma unroll
      for (int ni = 0; ni < 5; ++ni) { v[ni] = acc[mi][ni][j] * al[ni] + be[ni]; m = fmaxf(m, v[ni]); }
#pragma unroll
      for (int off = 1; off < 16; off <<= 1) m = fmaxf(m, __shfl_xor(m, off, 64));
      float ssum = 0.f;
#pragma unroll
      for (int ni = 0; ni < 5; ++ni) { v[ni] = __expf(v[ni] - m); ssum += v[ni]; }
#pragma unroll
      for (int off = 1; off < 16; off <<= 1) ssum += __shfl_xor(ssum, off, 64);
      float inv = 1.f / ssum;
      int row = m0 + wm * 128 + mi * 16 + q * 4 + j;
      size_t rb = (size_t)row * NC_ + n0 + wn * 80 + r;
#pragma unroll
      for (int ni = 0; ni < 5; ++ni)
        Pb[rb + ni * 16] = f2bf(v[ni] * inv);
    }
  }
}

// ---------------- fallback score GEMM (fp32 A, reg-staged), 128x160, 256 thr ----------------
__global__ __launch_bounds__(256) void k_score_f32(
    const float* __restrict__ hs, const unsigned short* __restrict__ Mt,
    const float* __restrict__ alphav, const float* __restrict__ betav,
    unsigned short* __restrict__ P) {
  int id = blockIdx.x;
  int x = id & 7, idp = id >> 3;
  int n_t = idp & 7;
  int pid = (idp >> 3) * 8 + x;
  int b = pid >> 5, m_t = pid & 31;
  int m0 = m_t * 128, n0 = n_t * 160;
  const float* Af = hs + (size_t)b * LQ_ * D_;
  const unsigned short* Bb = Mt + (size_t)b * NC_ * D_;
  const float* alp = alphav + b * NC_;
  const float* bet = betav + b * NC_;
  unsigned short* Pb = P + (size_t)b * LQ_ * NC_;
  __shared__ short As[128 * 64];
  __shared__ short Bs[160 * 64];
  int t = threadIdx.x, lane = t & 63, wid = t >> 6;
  int wm = wid >> 1, wn = wid & 1;
  int srow = lane >> 3;
  int schunk = (lane & 7) ^ srow;
  f4 acc[4][5] = {};
  for (int k0 = 0; k0 < D_; k0 += 64) {
    __syncthreads();
    for (int i = wid; i < 20; i += 4)
      gload16(Bb + (size_t)(n0 + i * 8 + srow) * D_ + k0 + schunk * 8, (char*)Bs + i * 1024);
    int arow = t >> 3, ac = t & 7;
    int awc = ac ^ (arow & 7);
#pragma unroll
    for (int p = 0; p < 4; ++p) {
      int row = p * 32 + arow;
      const float* src = Af + (size_t)(m0 + row) * D_ + k0 + ac * 8;
      f4 v0 = *(const f4*)src;
      f4 v1 = *(const f4*)(src + 4);
      us8 u;
#pragma unroll
      for (int j = 0; j < 4; ++j) { u[j] = f2bf(v0[j]); u[4 + j] = f2bf(v1[j]); }
      *(us8*)(As + row * 64 + awc * 8) = u;
    }
    __syncthreads();
#pragma unroll
    for (int kk = 0; kk < 2; ++kk) {
      int co = ((kk * 4 + (lane >> 4)) ^ (lane & 7)) * 8;
      short8 fa[4], fb[5];
#pragma unroll
      for (int mi = 0; mi < 4; ++mi)
        fa[mi] = *(const short8*)(As + (wm * 64 + mi * 16 + (lane & 15)) * 64 + co);
#pragma unroll
      for (int ni = 0; ni < 5; ++ni)
        fb[ni] = *(const short8*)(Bs + (wn * 80 + ni * 16 + (lane & 15)) * 64 + co);
#pragma unroll
      for (int mi = 0; mi < 4; ++mi)
#pragma unroll
        for (int ni = 0; ni < 5; ++ni)
          acc[mi][ni] = __builtin_amdgcn_mfma_f32_16x16x32_bf16(fa[mi], fb[ni], acc[mi][ni], 0, 0, 0);
    }
  }
  float al[5], be[5];
#pragma unroll
  for (int ni = 0; ni < 5; ++ni) {
    int cc = n0 + wn * 80 + ni * 16 + (lane & 15);
    al[ni] = alp[cc]; be[ni] = bet[cc];
  }
#pragma unroll
  for (int mi = 0; mi < 4; ++mi) {
#pragma unroll
    for (int j = 0; j < 4; ++j) {
      float v[5];
      float m = -3.0e38f;
#pragma unroll
      for (int ni = 0; ni < 5; ++ni) { v[ni] = acc[mi][ni][j] * al[ni] + be[ni]; m = fmaxf(m, v[ni]); }
#pragma unroll
      for (int off = 1; off < 16; off <<= 1) m = fmaxf(m, __shfl_xor(m, off, 64));
      float ssum = 0.f;
#pragma unroll
      for (int ni = 0; ni < 5; ++ni) { v[ni] = __expf(v[ni] - m); ssum += v[ni]; }
#pragma unroll
      for (int off = 1; off < 16; off <<= 1) ssum += __shfl_xor(ssum, off, 64);
      float inv = 1.f / ssum;
      int row = m0 + wm * 64 + mi * 16 + (lane >> 4) * 4 + j;
      size_t rb = (size_t)row * NC_ + n0 + wn * 80 + (lane & 15);
#pragma unroll
      for (int ni = 0; ni < 5; ++ni)
        Pb[rb + ni * 16] = f2bf(v[ni] * inv);
    }
  }
}

// ---------------- out GEMM 256x256, same m201 cell: out = P @ Ut^T + bo ----------------
__global__ __launch_bounds__(512, 2) void k_out_big(
    const unsigned short* __restrict__ P, const unsigned short* __restrict__ Ut,
    const float* __restrict__ bo, float* __restrict__ out) {
  extern __shared__ short lds[];
  // A: 4 bufs x 8192 at 0; B: 4 bufs x 8192 at 32768 (128KB)
  int id = blockIdx.x;
  int x = id & 7, idp = id >> 3;
  int nt = idp & 3;
  int pid = (idp >> 2) * 8 + x;
  int b = pid >> 4, mt = pid & 15;
  int m0 = mt * 256, n0 = nt * 256;

  const unsigned short* Ab = P + (size_t)b * LQ_ * NC_;
  const unsigned short* Bb = Ut + (size_t)b * D_ * NC_;
  float* ob = out + (size_t)b * LQ_ * D_;

  int t = threadIdx.x, lane = t & 63, wid = t >> 6;
  int wm = wid >> 2, wn = wid & 3;     // wave tile 128x64
  int r = lane & 15, q = lane >> 4;
  f4 acc[8][4] = {};
  const int T = NC_ / 32;   // 40 half-tiles

  auto SA = [&](int bf, int k0, int p) {
    int cb = p * 512 + wid * 64;
    int cc = cb + lane;
    int row = cc >> 2, gc = (cc & 3) ^ ((row >> 1) & 3);
    gload16(Ab + (size_t)(m0 + row) * NC_ + k0 + gc * 8, (char*)(lds + bf * 8192) + cb * 16);
  };
  auto SB = [&](int bf, int k0, int p) {
    int cb = p * 512 + wid * 64;
    int cc = cb + lane;
    int row = cc >> 2, gc = (cc & 3) ^ ((row >> 1) & 3);
    gload16(Bb + (size_t)(n0 + row) * NC_ + k0 + gc * 8, (char*)(lds + 32768 + bf * 8192) + cb * 16);
  };
  auto STAGE_P1 = [&](int h) { if (h < T) { int bf = h & 3, k0 = h * 32; SA(bf, k0, 0); SA(bf, k0, 1); } };
  auto STAGE_P2 = [&](int h) { if (h < T) { int bf = h & 3, k0 = h * 32; SB(bf, k0, 0); SB(bf, k0, 1); } };

  STAGE_P1(0); STAGE_P2(0);
  STAGE_P1(1); STAGE_P2(1);
  STAGE_P1(2); STAGE_P2(2);
  asm volatile("s_waitcnt vmcnt(8)" ::: "memory");   // prove h=0 (4 loads/stage)
  __builtin_amdgcn_s_barrier();

#pragma unroll 1
  for (int h = 0; h < T; ++h) {
    int bf = h & 3;
    const short* Ar = lds + bf * 8192;
    const short* Br = lds + 32768 + bf * 8192;
    short8 fa[4], fb[4];

    // ---- phase A ----
#pragma unroll
    for (int ni = 0; ni < 4; ++ni) {
      int row = wn * 64 + ni * 16 + r;
      fb[ni] = *(const short8*)(Br + row * 32 + ((q ^ ((row >> 1) & 3)) * 8));
    }
#pragma unroll
    for (int mi = 0; mi < 4; ++mi) {
      int row = wm * 128 + mi * 16 + r;
      fa[mi] = *(const short8*)(Ar + row * 32 + ((q ^ ((row >> 1) & 3)) * 8));
    }
    __builtin_amdgcn_sched_barrier(0);
    STAGE_P1(h + 3);
    __builtin_amdgcn_sched_barrier(0);
    __builtin_amdgcn_s_barrier();
    asm volatile("s_waitcnt lgkmcnt(0)");
    __builtin_amdgcn_s_setprio(1);
#pragma unroll
    for (int mi = 0; mi < 4; ++mi)
#pragma unroll
      for (int ni = 0; ni < 4; ++ni)
        acc[mi][ni] = __builtin_amdgcn_mfma_f32_16x16x32_bf16(fa[mi], fb[ni], acc[mi][ni], 0, 0, 0);
    __builtin_amdgcn_s_setprio(0);

    // ---- phase B ----
#pragma unroll
    for (int mi = 0; mi < 4; ++mi) {
      int row = wm * 128 + (4 + mi) * 16 + r;
      fa[mi] = *(const short8*)(Ar + row * 32 + ((q ^ ((row >> 1) & 3)) * 8));
    }
    __builtin_amdgcn_sched_barrier(0);
    STAGE_P2(h + 3);
    __builtin_amdgcn_sched_barrier(0);
    __builtin_amdgcn_s_barrier();
    asm volatile("s_waitcnt lgkmcnt(0)");
    __builtin_amdgcn_s_setprio(1);
#pragma unroll
    for (int mi = 0; mi < 4; ++mi)
#pragma unroll
      for (int ni = 0; ni < 4; ++ni)
        acc[4 + mi][ni] = __builtin_amdgcn_mfma_f32_16x16x32_bf16(fa[mi], fb[ni], acc[4 + mi][ni], 0, 0, 0);
    __builtin_amdgcn_s_setprio(0);

    // ---- half-tile end: counted proof of S(h+1) ----
    if (h <= T - 4) {
      asm volatile("s_waitcnt vmcnt(8)" ::: "memory");
    } else if (h == T - 3) {
      asm volatile("s_waitcnt vmcnt(4)" ::: "memory");
    } else if (h == T - 2) {
      asm volatile("s_waitcnt vmcnt(0)" ::: "memory");
    }
    if (h < T - 1) __builtin_amdgcn_s_barrier();
  }

#pragma unroll
  for (int ni = 0; ni < 4; ++ni) {
    int col = n0 + wn * 64 + ni * 16 + r;
    float bov = bo[col];
#pragma unroll
    for (int mi = 0; mi < 8; ++mi)
#pragma unroll
      for (int j = 0; j < 4; ++j) {
        int row = m0 + wm * 128 + mi * 16 + q * 4 + j;
        ob[(size_t)row * D_ + col] = acc[mi][ni][j] + bov;
      }
  }
}

extern "C" void kernel_launch(void* const* d_in, const int* in_sizes, int n_in,
                              void* d_out, int out_size, void* d_ws, size_t ws_size,
                              hipStream_t stream) {
  const float* hs  = (const float*)d_in[0];
  const float* ehs = (const float*)d_in[1];
  const float* Wq  = (const float*)d_in[2];
  const float* Wk  = (const float*)d_in[3];
  const float* Wv  = (const float*)d_in[4];
  const float* Wo  = (const float*)d_in[5];
  const float* bo  = (const float*)d_in[6];
  const float* Ak  = (const float*)d_in[7];
  const float* Bk  = (const float*)d_in[8];
  const float* Av  = (const float*)d_in[9];
  const float* Bv  = (const float*)d_in[10];
  const float* Ao  = (const float*)d_in[11];
  const float* Bo  = (const float*)d_in[12];
  const float* csf = (const float*)d_in[13];
  const int*   sb  = (const int*)d_in[14];
  const int*   sn  = (const int*)d_in[15];
  float* out = (float*)d_out;

  hipFuncSetAttribute(reinterpret_cast<const void*>(k_score_big),
                      hipFuncAttributeMaxDynamicSharedMemorySize, 147456);
  hipFuncSetAttribute(reinterpret_cast<const void*>(k_out_big),
                      hipFuncAttributeMaxDynamicSharedMemorySize, 131072);

  char* ws = (char*)d_ws;
  unsigned short* P  = (unsigned short*)ws;                   // 83,886,080
  unsigned short* Mt = (unsigned short*)(ws + 83886080);      // 20,971,520
  unsigned short* Ut = (unsigned short*)(ws + 104857600);     // 20,971,520
  const size_t NEED_HSB = 125829120ULL + 67108864ULL + 81920ULL; // 193,019,904
  bool useHsb = ws_size >= NEED_HSB;
  unsigned short* hsb = useHsb ? (unsigned short*)(ws + 125829120) : nullptr;
  char* tail = useHsb ? (ws + 192937984) : (ws + 125829120);
  float* alphav = (float*)tail;
  float* betav  = (float*)(tail + 40960);
  // temporaries overlapped into P's region (all dead before k_score writes P):
  float* kvbuf = (float*)(ws + 0);            //  5,242,880  [b][80][2048] (k|v)
  float* weff  = (float*)(ws + 5242880);      // 12,582,912  [wkE;wvE;woE]
  float* wqT   = (float*)(ws + 17825792);     //  4,194,304
  float* aT    = (float*)(ws + 22020096);     //  2,359,296
  float* part  = (float*)(ws + 24379392);     //  2,097,152
  float* hssum = (float*)(ws + 26476544);     //     32,768

  float* woE = weff + 2097152;
  float* akT = aT;
  float* avT = aT + 196608;
  float* aoT = aT + 393216;

  const float LS = 16.0f / 192.0f;

  // hs row-sums (deterministic two-stage) + bf16 conversion of hs
  k_hssum<<<dim3(64, 8), 256, 0, stream>>>(hs, part, hsb);
  k_hsred<<<32, 256, 0, stream>>>(part, hssum);

  // all transposes in one launch
  k_tr4<<<dim3(32, 32, 4), 256, 0, stream>>>(Wq, Ak, Av, Ao, wqT, akT, avT, aoT);

  // W_eff (k,v,o) in one launch
  k_weff<<<dim3(16, 16, 3), 256, 0, stream>>>(Bk, Bv, Bo, akT, avT, aoT, Wk, Wv, Wo, weff, LS);

  // [k|v] = ehs @ [wkE;wvE]^T : N=2048, C row-stride 2048
  k_gemm_small<false><<<dim3(2, 32, 8), 256, 0, stream>>>(
      ehs, 1024, 77L * 1024, 0, weff, 1024, 0, 0, kvbuf, 2048, 80L * 2048, 0, nullptr, 0,
      80, 77, 2048, 1024, 1.f, 1);

  // Mt[b,h] = 0.125 * k_bh @ Wq_h   (bf16, [b][h*80+s][e]) — N=1024 (e-dim), y=16 REQUIRED
  k_gemm_small<true><<<dim3(2, 16, 128), 256, 0, stream>>>(
      kvbuf, 2048, 80L * 2048, 64L, wqT, 1024, 0, 64L,
      Mt, 1024, (long)NC_ * 1024, 80L * 1024, nullptr, 0,
      80, 80, 1024, 64, 0.125f, 16);

  // Ut[b,h] = woE_h @ v_bh^T   (bf16, [b][e][h*80+s])
  k_gemm_small<true><<<dim3(16, 2, 128), 256, 0, stream>>>(
      woE, 1024, 0, 64L, kvbuf + 1024, 2048, 80L * 2048, 64L,
      Ut, NC_, 1024L * NC_, 80L, nullptr, 0,
      1024, 1024, 80, 64, 1.f, 16);

  // per-(b,h,s) column mean (qmean fused) + subject alpha/beta
  k_mubeta<<<dim3(16, 8), 128, 0, stream>>>(hssum, Wq, kvbuf, sb, sn, csf, alphav, betav);

  // big fused GEMMs
  if (useHsb)
    k_score_big<<<512, 512, 147456, stream>>>(hsb, Mt, alphav, betav, P);
  else
    k_score_f32<<<2048, 256, 0, stream>>>(hs, Mt, alphav, betav, P);
  k_out_big<<<512, 512, 131072, stream>>>(P, Ut, bo, out);

  (void)in_sizes; (void)n_in; (void)out_size; (void)ws_size;
}

// Round 13
// 344.196 us; speedup vs baseline: 1.1364x; 1.0850x over previous
//
#include <hip/hip_runtime.h>
#include <stdint.h>

#define B_     8
#define LQ_    4096
#define S_     77
#define SP_    80
#define D_     1024
#define H_     16
#define HD_    64
#define NC_    1280   // H_*SP_
#define NSUBJ_ 32

typedef __attribute__((ext_vector_type(4))) float  f4;
typedef __attribute__((ext_vector_type(8))) short  short8;
typedef __attribute__((ext_vector_type(8))) unsigned short us8;
typedef __attribute__((ext_vector_type(4))) unsigned short us4;

__device__ __forceinline__ unsigned short f2bf(float f) {
  union { float f; unsigned u; } x; x.f = f;
  unsigned r = x.u + 0x7FFFu + ((x.u >> 16) & 1u);
  return (unsigned short)(r >> 16);
}
__device__ __forceinline__ float bf2f(unsigned short v) {
  union { unsigned u; float f; } x; x.u = ((unsigned)v) << 16;
  return x.f;
}

__device__ __forceinline__ void gload16(const void* g, void* s) {
  __builtin_amdgcn_global_load_lds((const __attribute__((address_space(1))) void*)g,
                                   (__attribute__((address_space(3))) void*)s, 16, 0, 0);
}

// ---------------- hssum partials + hs -> bf16 convert ----------------
__global__ __launch_bounds__(256) void k_hssum(const float* __restrict__ hs,
                                               float* __restrict__ part,
                                               unsigned short* __restrict__ hsb) {
  int b = blockIdx.y;
  size_t base = ((size_t)b * LQ_ + (size_t)blockIdx.x * 64) * D_ + threadIdx.x * 4;
  f4 acc = {0.f, 0.f, 0.f, 0.f};
  for (int l = 0; l < 64; ++l) {
    f4 v = *(const f4*)(hs + base + (size_t)l * D_);
    acc += v;
    if (hsb) {
      us4 o;
#pragma unroll
      for (int j = 0; j < 4; ++j) o[j] = f2bf(v[j]);
      *(us4*)(hsb + base + (size_t)l * D_) = o;
    }
  }
  *(f4*)(part + (size_t)blockIdx.x * (B_ * D_) + b * D_ + threadIdx.x * 4) = acc;
}

__global__ __launch_bounds__(256) void k_hsred(const float* __restrict__ part,
                                               float* __restrict__ hssum) {
  int i = blockIdx.x * 256 + threadIdx.x;   // [0, 8192)
  float s = 0.f;
  for (int x = 0; x < 64; ++x) s += part[(size_t)x * (B_ * D_) + i];
  hssum[i] = s;
}

// ---------------- ehs -> bf16 padded [8][80][1024] (rows 77..79 zero) ----------------
__global__ __launch_bounds__(256) void k_ehsb(const float* __restrict__ ehs,
                                              unsigned short* __restrict__ ehsb) {
  int s = blockIdx.x, b = blockIdx.y;
  int i = threadIdx.x * 4;
  us4 o = {0, 0, 0, 0};
  if (s < S_) {
    f4 v = *(const f4*)(ehs + ((size_t)b * S_ + s) * D_ + i);
#pragma unroll
    for (int j = 0; j < 4; ++j) o[j] = f2bf(v[j]);
  }
  *(us4*)(ehsb + ((size_t)b * SP_ + s) * D_ + i) = o;
}

// ---------------- 4 transposes: Wq -> wqTb (bf16), Ak/Av/Ao -> fp32 ----------------
__global__ __launch_bounds__(256) void k_tr4(const float* __restrict__ Wq, const float* __restrict__ Ak,
                                             const float* __restrict__ Av, const float* __restrict__ Ao,
                                             unsigned short* __restrict__ wqTb, float* __restrict__ akT,
                                             float* __restrict__ avT, float* __restrict__ aoT) {
  int z = blockIdx.z;
  const float* in = z == 0 ? Wq : (z == 1 ? Ak : (z == 2 ? Av : Ao));
  float* outf = z == 1 ? akT : (z == 2 ? avT : aoT);
  int R = z == 0 ? 1024 : 192;
  const int C = 1024;
  int c0 = blockIdx.x * 32, r0 = blockIdx.y * 32;
  if (r0 >= R) return;
  __shared__ float tile[32][33];
  int tx = threadIdx.x & 31, ty = threadIdx.x >> 5;
#pragma unroll
  for (int k = 0; k < 4; ++k)
    tile[ty + 8 * k][tx] = in[(size_t)(r0 + ty + 8 * k) * C + c0 + tx];
  __syncthreads();
#pragma unroll
  for (int k = 0; k < 4; ++k) {
    size_t idx = (size_t)(c0 + ty + 8 * k) * R + r0 + tx;
    float v = tile[tx][ty + 8 * k];
    if (z == 0) wqTb[idx] = f2bf(v);
    else        outf[idx] = v;
  }
}

// ---------------- shared 64x64-tile GEMM body: C = alpha*(A @ Bt^T) [+ Dm] ----------------
template <bool OBF>
__device__ __forceinline__ void gemm64_body(
    const float* __restrict__ A, int lda, const float* __restrict__ Bt, int ldb,
    void* __restrict__ Cv, int ldc, long cbase, const float* __restrict__ Dm, int ldd,
    int M, int Mv, int N, int K, float alpha, int m0, int n0,
    short* As, short* Bs) {
  int t = threadIdx.x, lane = t & 63, wid = t >> 6;
  int wm = wid >> 1, wn = wid & 1;
  f4 acc[2][2] = {};
  int srow = t >> 2, skc = (t & 3) * 8;
  for (int k0 = 0; k0 < K; k0 += 32) {
    __syncthreads();
    f4 a0 = {0,0,0,0}, a1 = {0,0,0,0}, b0 = {0,0,0,0}, b1 = {0,0,0,0};
    if (m0 + srow < Mv) {
      const float* p = A + (size_t)(m0 + srow) * lda + k0 + skc;
      a0 = *(const f4*)p; a1 = *(const f4*)(p + 4);
    }
    if (n0 + srow < N) {
      const float* p = Bt + (size_t)(n0 + srow) * ldb + k0 + skc;
      b0 = *(const f4*)p; b1 = *(const f4*)(p + 4);
    }
    us8 ua, ub;
#pragma unroll
    for (int j = 0; j < 4; ++j) {
      ua[j] = f2bf(a0[j]); ua[4 + j] = f2bf(a1[j]);
      ub[j] = f2bf(b0[j]); ub[4 + j] = f2bf(b1[j]);
    }
    *(us8*)(As + srow * 40 + skc) = ua;
    *(us8*)(Bs + srow * 40 + skc) = ub;
    __syncthreads();
    short8 fa[2], fb[2];
#pragma unroll
    for (int i = 0; i < 2; ++i) {
      fa[i] = *(const short8*)(As + (wm * 32 + i * 16 + (lane & 15)) * 40 + (lane >> 4) * 8);
      fb[i] = *(const short8*)(Bs + (wn * 32 + i * 16 + (lane & 15)) * 40 + (lane >> 4) * 8);
    }
#pragma unroll
    for (int mi = 0; mi < 2; ++mi)
#pragma unroll
      for (int ni = 0; ni < 2; ++ni)
        acc[mi][ni] = __builtin_amdgcn_mfma_f32_16x16x32_bf16(fa[mi], fb[ni], acc[mi][ni], 0, 0, 0);
  }
#pragma unroll
  for (int mi = 0; mi < 2; ++mi)
#pragma unroll
    for (int ni = 0; ni < 2; ++ni)
#pragma unroll
      for (int j = 0; j < 4; ++j) {
        int row = m0 + wm * 32 + mi * 16 + (lane >> 4) * 4 + j;
        int col = n0 + wn * 32 + ni * 16 + (lane & 15);
        if (row < M && col < N) {
          float val = acc[mi][ni][j] * alpha;
          if (Dm) val += Dm[(size_t)row * ldd + col];
          size_t idx = (size_t)cbase + (size_t)row * ldc + col;
          if (OBF) ((unsigned short*)Cv)[idx] = f2bf(val);
          else     ((float*)Cv)[idx] = val;
        }
      }
}

// W_eff = W + (1/12) Bx@Ax -> bf16 wEb[3*1024][1024] (z selects k/v/o)
__global__ __launch_bounds__(256) void k_weff(
    const float* __restrict__ Bk, const float* __restrict__ Bv, const float* __restrict__ Bo,
    const float* __restrict__ akT, const float* __restrict__ avT, const float* __restrict__ aoT,
    const float* __restrict__ Wk, const float* __restrict__ Wv, const float* __restrict__ Wo,
    unsigned short* __restrict__ wEb, float alpha) {
  int z = blockIdx.z;
  const float* A  = z == 0 ? Bk : (z == 1 ? Bv : Bo);
  const float* Bt = z == 0 ? akT : (z == 1 ? avT : aoT);
  const float* Dm = z == 0 ? Wk : (z == 1 ? Wv : Wo);
  __shared__ short As[64 * 40];
  __shared__ short Bs[64 * 40];
  gemm64_body<true>(A, 192, Bt, 192, wEb + (size_t)z * 1048576, 1024, 0, Dm, 1024,
                    1024, 1024, 1024, 192, alpha, blockIdx.x * 64, blockIdx.y * 64, As, Bs);
}

// ---------------- kv = ehsb @ wEb[k|v]^T  (bf16 in/out, [b][80][2048]) ----------------
// 64 blocks: (b, nt) tile 80x256, K=1024, single-buffer 2-barrier, gload_lds staging.
__global__ __launch_bounds__(512) void k_kv(const unsigned short* __restrict__ ehsb,
                                            const unsigned short* __restrict__ wEb,
                                            unsigned short* __restrict__ kvb) {
  __shared__ short As[80 * 64];    // 10 KB
  __shared__ short Bs[256 * 64];   // 32 KB
  int b = blockIdx.x >> 3, nt = blockIdx.x & 7;
  int n0 = nt * 256;
  const unsigned short* Ab = ehsb + (size_t)b * SP_ * D_;
  int t = threadIdx.x, lane = t & 63, w = t >> 6;
  int r = lane & 15, q = lane >> 4;
  f4 acc[5][2] = {};

  for (int k0 = 0; k0 < 1024; k0 += 64) {
    __syncthreads();
    // stage 2688 chunks: A 0..639, B 640..2687 (instruction-uniform split: 640 % 64 == 0)
#pragma unroll
    for (int p = 0; p < 6; ++p) {
      int cb = p * 512 + w * 64;           // wave-uniform LDS chunk base
      if (cb < 2688) {
        int cc = cb + lane;
        if (cb < 640) {
          int row = cc >> 3, gc = (cc & 7) ^ (row & 7);
          gload16(Ab + (size_t)row * D_ + k0 + gc * 8, (char*)As + cb * 16);
        } else {
          int bc = cc - 640, row = bc >> 3, gc = (bc & 7) ^ (row & 7);
          gload16(wEb + (size_t)(n0 + row) * D_ + k0 + gc * 8, (char*)Bs + (cb - 640) * 16);
        }
      }
    }
    __syncthreads();
#pragma unroll
    for (int kk = 0; kk < 2; ++kk) {
      int co = ((kk * 4 + q) ^ (r & 7)) * 8;
      short8 fa[5], fb[2];
#pragma unroll
      for (int mi = 0; mi < 5; ++mi)
        fa[mi] = *(const short8*)(As + (mi * 16 + r) * 64 + co);
#pragma unroll
      for (int ni = 0; ni < 2; ++ni)
        fb[ni] = *(const short8*)(Bs + (w * 32 + ni * 16 + r) * 64 + co);
#pragma unroll
      for (int mi = 0; mi < 5; ++mi)
#pragma unroll
        for (int ni = 0; ni < 2; ++ni)
          acc[mi][ni] = __builtin_amdgcn_mfma_f32_16x16x32_bf16(fa[mi], fb[ni], acc[mi][ni], 0, 0, 0);
    }
  }
#pragma unroll
  for (int mi = 0; mi < 5; ++mi)
#pragma unroll
    for (int ni = 0; ni < 2; ++ni)
#pragma unroll
      for (int j = 0; j < 4; ++j) {
        int s = mi * 16 + q * 4 + j;
        int col = n0 + w * 32 + ni * 16 + r;
        kvb[((size_t)b * SP_ + s) * 2048 + col] = f2bf(acc[mi][ni][j]);
      }
}

// ---------------- Mt + Ut: one block per (b,h) panel ----------------
// z<128: Mt[b,(h,s),e] = 0.125 * kvb_k[b,s,h64:] @ wqTb[e,h64:]^T
// z>=128: Ut[b,e,(h,s)] = wEb_o[e,h64:] @ kvb_v[b,s,h64:]^T
__global__ __launch_bounds__(512) void k_mtut(const unsigned short* __restrict__ kvb,
                                              const unsigned short* __restrict__ wqTb,
                                              const unsigned short* __restrict__ wEb,
                                              unsigned short* __restrict__ Mt,
                                              unsigned short* __restrict__ Ut) {
  __shared__ short Ss[80 * 64];    // small operand (staged once)
  __shared__ short Ls[256 * 64];   // large operand chunk
  int z = blockIdx.x;
  bool mt = z < 128;
  int zz = mt ? z : z - 128;
  int b = zz >> 4, h = zz & 15;
  const unsigned short* small_src = kvb + (size_t)b * SP_ * 2048 + (mt ? h * 64 : 1024 + h * 64);
  const unsigned short* large_src = mt ? (wqTb + h * 64) : (wEb + (size_t)2048 * 1024 + h * 64);
  int t = threadIdx.x, lane = t & 63, w = t >> 6;
  int r = lane & 15, q = lane >> 4;

  // stage small operand (80x64, 640 chunks) once
#pragma unroll
  for (int p = 0; p < 2; ++p) {
    int cb = p * 512 + w * 64;
    if (cb < 640) {
      int cc = cb + lane, row = cc >> 3, gc = (cc & 7) ^ (row & 7);
      gload16(small_src + (size_t)row * 2048 + gc * 8, (char*)Ss + cb * 16);
    }
  }

  for (int mc = 0; mc < 4; ++mc) {
    __syncthreads();   // prev compute done (and first-iter ordering)
#pragma unroll
    for (int p = 0; p < 4; ++p) {
      int cb = p * 512 + w * 64;
      int cc = cb + lane, row = cc >> 3, gc = (cc & 7) ^ (row & 7);
      gload16(large_src + (size_t)(mc * 256 + row) * 1024 + gc * 8, (char*)Ls + cb * 16);
    }
    __syncthreads();   // drains vmcnt: Ss (first iter) + Ls ready

    if (mt) {
      f4 acc[5][2] = {};
#pragma unroll
      for (int kk = 0; kk < 2; ++kk) {
        int co = ((kk * 4 + q) ^ (r & 7)) * 8;
        short8 fa[5], fb[2];
#pragma unroll
        for (int mi = 0; mi < 5; ++mi)
          fa[mi] = *(const short8*)(Ss + (mi * 16 + r) * 64 + co);
#pragma unroll
        for (int ni = 0; ni < 2; ++ni)
          fb[ni] = *(const short8*)(Ls + (w * 32 + ni * 16 + r) * 64 + co);
#pragma unroll
        for (int mi = 0; mi < 5; ++mi)
#pragma unroll
          for (int ni = 0; ni < 2; ++ni)
            acc[mi][ni] = __builtin_amdgcn_mfma_f32_16x16x32_bf16(fa[mi], fb[ni], acc[mi][ni], 0, 0, 0);
      }
#pragma unroll
      for (int mi = 0; mi < 5; ++mi)
#pragma unroll
        for (int ni = 0; ni < 2; ++ni)
#pragma unroll
          for (int j = 0; j < 4; ++j) {
            int s = mi * 16 + q * 4 + j;
            int e = mc * 256 + w * 32 + ni * 16 + r;
            Mt[((size_t)b * NC_ + h * SP_ + s) * 1024 + e] = f2bf(acc[mi][ni][j] * 0.125f);
          }
    } else {
      f4 acc[2][5] = {};
#pragma unroll
      for (int kk = 0; kk < 2; ++kk) {
        int co = ((kk * 4 + q) ^ (r & 7)) * 8;
        short8 fa[2], fb[5];
#pragma unroll
        for (int mi = 0; mi < 2; ++mi)
          fa[mi] = *(const short8*)(Ls + (w * 32 + mi * 16 + r) * 64 + co);
#pragma unroll
        for (int ni = 0; ni < 5; ++ni)
          fb[ni] = *(const short8*)(Ss + (ni * 16 + r) * 64 + co);
#pragma unroll
        for (int mi = 0; mi < 2; ++mi)
#pragma unroll
          for (int ni = 0; ni < 5; ++ni)
            acc[mi][ni] = __builtin_amdgcn_mfma_f32_16x16x32_bf16(fa[mi], fb[ni], acc[mi][ni], 0, 0, 0);
      }
#pragma unroll
      for (int mi = 0; mi < 2; ++mi)
#pragma unroll
        for (int ni = 0; ni < 5; ++ni)
#pragma unroll
          for (int j = 0; j < 4; ++j) {
            int e = mc * 256 + w * 32 + mi * 16 + q * 4 + j;
            int col = h * SP_ + ni * 16 + r;
            Ut[((size_t)b * D_ + e) * NC_ + col] = f2bf(acc[mi][ni][j]);
          }
    }
  }
}

// ---------------- mu/alpha/beta per (b,h,s), qmean fused; kv in bf16 ----------------
__global__ void k_mubeta(const float* __restrict__ hssum, const float* __restrict__ Wq,
                         const unsigned short* __restrict__ kvb,
                         const int* __restrict__ sb, const int* __restrict__ sn,
                         const float* __restrict__ csf_p,
                         float* __restrict__ alphav, float* __restrict__ betav) {
  int h = blockIdx.x, b = blockIdx.y;
  int t = threadIdx.x;                       // 128 threads
  __shared__ float qp[64];
  {
    int hd = t >> 1, half = t & 1;
    const float* wr = Wq + (size_t)(h * 64 + hd) * D_ + half * 512;
    const float* hp = hssum + b * D_ + half * 512;
    float s = 0.f;
    for (int d = 0; d < 512; d += 4) {
      f4 w = *(const f4*)(wr + d);
      f4 x = *(const f4*)(hp + d);
      s += w[0] * x[0] + w[1] * x[1] + w[2] * x[2] + w[3] * x[3];
    }
    s += __shfl_xor(s, 1, 64);
    if (half == 0) qp[hd] = s * (1.f / 4096.f);
  }
  __syncthreads();
  int s = t;
  if (s >= SP_) return;
  const unsigned short* kp = kvb + ((size_t)(b * SP_ + s)) * 2048 + h * HD_;
  float mu = 0.f;
#pragma unroll
  for (int hd = 0; hd < HD_; hd += 4) {
    us4 kv = *(const us4*)(kp + hd);
#pragma unroll
    for (int j = 0; j < 4; ++j) mu += qp[hd + j] * bf2f(kv[j]);
  }
  mu *= 0.125f;
  bool subj = false;
  for (int i = 0; i < NSUBJ_; ++i) subj = subj || (sb[i] == b && sn[i] == s);
  float csf = *csf_p;
  int c = b * NC_ + h * SP_ + s;
  alphav[c] = subj ? csf : 1.f;
  betav[c] = (s >= S_) ? -1e30f : (subj ? -mu * csf : 0.f);
}

// ---------------- score GEMM 256x320 (UNCHANGED from R11) ----------------
__global__ __launch_bounds__(512, 2) void k_score_big(
    const unsigned short* __restrict__ hsb, const unsigned short* __restrict__ Mt,
    const float* __restrict__ alphav, const float* __restrict__ betav,
    unsigned short* __restrict__ P) {
  extern __shared__ short lds[];
  int id = blockIdx.x;
  int x = id & 7, idp = id >> 3;
  int nt = idp & 3;
  int pid = (idp >> 2) * 8 + x;    // [0,128)
  int b = pid >> 4, mt = pid & 15;
  int m0 = mt * 256, n0 = nt * 320;

  const unsigned short* Ab = hsb + (size_t)b * LQ_ * D_;
  const unsigned short* Bb = Mt + (size_t)b * NC_ * D_;
  const float* alp = alphav + b * NC_;
  const float* bet = betav + b * NC_;
  unsigned short* Pb = P + (size_t)b * LQ_ * NC_;

  int t = threadIdx.x, lane = t & 63, wid = t >> 6;
  int wm = wid >> 2, wn = wid & 3;
  int r = lane & 15, q = lane >> 4;
  f4 acc[8][5] = {};

  auto SA = [&](int bf, int k0, int p) {
    int cb = p * 512 + wid * 64;
    int cc = cb + lane;
    int row = cc >> 2, gc = (cc & 3) ^ ((row >> 1) & 3);
    gload16(Ab + (size_t)(m0 + row) * D_ + k0 + gc * 8, (char*)(lds + bf * 8192) + cb * 16);
  };
  auto SB = [&](int bf, int k0, int p) {
    int cb = p * 512 + wid * 64;
    int cc = cb + lane;
    int row = cc >> 2, gc = (cc & 3) ^ ((row >> 1) & 3);
    gload16(Bb + (size_t)(n0 + row) * D_ + k0 + gc * 8, (char*)(lds + 32768 + bf * 10240) + cb * 16);
  };
  auto SBx = [&](int bf, int k0) {
    if (wid < 4) {
      int cb = 1024 + wid * 64;
      int cc = cb + lane;
      int row = cc >> 2, gc = (cc & 3) ^ ((row >> 1) & 3);
      gload16(Bb + (size_t)(n0 + row) * D_ + k0 + gc * 8, (char*)(lds + 32768 + bf * 10240) + cb * 16);
    }
  };
  auto STAGE_P1 = [&](int h) { if (h < 32) { int bf = h & 3, k0 = h * 32; SA(bf, k0, 0); SA(bf, k0, 1); SB(bf, k0, 0); } };
  auto STAGE_P2 = [&](int h) { if (h < 32) { int bf = h & 3, k0 = h * 32; SB(bf, k0, 1); SBx(bf, k0); } };

  STAGE_P1(0); STAGE_P2(0);
  STAGE_P1(1); STAGE_P2(1);
  STAGE_P1(2); STAGE_P2(2);
  if (wid < 4) asm volatile("s_waitcnt vmcnt(10)" ::: "memory");
  else         asm volatile("s_waitcnt vmcnt(8)" ::: "memory");
  __builtin_amdgcn_s_barrier();

#pragma unroll 1
  for (int h = 0; h < 32; ++h) {
    int bf = h & 3;
    const short* Ar = lds + bf * 8192;
    const short* Br = lds + 32768 + bf * 10240;
    short8 fa[4], fb[5];

#pragma unroll
    for (int ni = 0; ni < 5; ++ni) {
      int row = wn * 80 + ni * 16 + r;
      fb[ni] = *(const short8*)(Br + row * 32 + ((q ^ ((row >> 1) & 3)) * 8));
    }
#pragma unroll
    for (int mi = 0; mi < 4; ++mi) {
      int row = wm * 128 + mi * 16 + r;
      fa[mi] = *(const short8*)(Ar + row * 32 + ((q ^ ((row >> 1) & 3)) * 8));
    }
    __builtin_amdgcn_sched_barrier(0);
    STAGE_P1(h + 3);
    __builtin_amdgcn_sched_barrier(0);
    __builtin_amdgcn_s_barrier();
    asm volatile("s_waitcnt lgkmcnt(0)");
    __builtin_amdgcn_s_setprio(1);
#pragma unroll
    for (int mi = 0; mi < 4; ++mi)
#pragma unroll
      for (int ni = 0; ni < 5; ++ni)
        acc[mi][ni] = __builtin_amdgcn_mfma_f32_16x16x32_bf16(fa[mi], fb[ni], acc[mi][ni], 0, 0, 0);
    __builtin_amdgcn_s_setprio(0);

#pragma unroll
    for (int mi = 0; mi < 4; ++mi) {
      int row = wm * 128 + (4 + mi) * 16 + r;
      fa[mi] = *(const short8*)(Ar + row * 32 + ((q ^ ((row >> 1) & 3)) * 8));
    }
    __builtin_amdgcn_sched_barrier(0);
    STAGE_P2(h + 3);
    __builtin_amdgcn_sched_barrier(0);
    __builtin_amdgcn_s_barrier();
    asm volatile("s_waitcnt lgkmcnt(0)");
    __builtin_amdgcn_s_setprio(1);
#pragma unroll
    for (int mi = 0; mi < 4; ++mi)
#pragma unroll
      for (int ni = 0; ni < 5; ++ni)
        acc[4 + mi][ni] = __builtin_amdgcn_mfma_f32_16x16x32_bf16(fa[mi], fb[ni], acc[4 + mi][ni], 0, 0, 0);
    __builtin_amdgcn_s_setprio(0);

    if (h <= 28) {
      if (wid < 4) asm volatile("s_waitcnt vmcnt(10)" ::: "memory");
      else         asm volatile("s_waitcnt vmcnt(8)" ::: "memory");
    } else if (h == 29) {
      if (wid < 4) asm volatile("s_waitcnt vmcnt(5)" ::: "memory");
      else         asm volatile("s_waitcnt vmcnt(4)" ::: "memory");
    } else if (h == 30) {
      asm volatile("s_waitcnt vmcnt(0)" ::: "memory");
    }
    if (h < 31) __builtin_amdgcn_s_barrier();
  }

  float al[5], be[5];
#pragma unroll
  for (int ni = 0; ni < 5; ++ni) {
    int cc = n0 + wn * 80 + ni * 16 + r;
    al[ni] = alp[cc]; be[ni] = bet[cc];
  }
#pragma unroll
  for (int mi = 0; mi < 8; ++mi) {
#pragma unroll
    for (int j = 0; j < 4; ++j) {
      float v[5];
      float m = -3.0e38f;
#pragma unroll
      for (int ni = 0; ni < 5; ++ni) { v[ni] = acc[mi][ni][j] * al[ni] + be[ni]; m = fmaxf(m, v[ni]); }
#pragma unroll
      for (int off = 1; off < 16; off <<= 1) m = fmaxf(m, __shfl_xor(m, off, 64));
      float ssum = 0.f;
#pragma unroll
      for (int ni = 0; ni < 5; ++ni) { v[ni] = __expf(v[ni] - m); ssum += v[ni]; }
#pragma unroll
      for (int off = 1; off < 16; off <<= 1) ssum += __shfl_xor(ssum, off, 64);
      float inv = 1.f / ssum;
      int row = m0 + wm * 128 + mi * 16 + q * 4 + j;
      size_t rb = (size_t)row * NC_ + n0 + wn * 80 + r;
#pragma unroll
      for (int ni = 0; ni < 5; ++ni)
        Pb[rb + ni * 16] = f2bf(v[ni] * inv);
    }
  }
}

// ---------------- fallback score GEMM (fp32 A, reg-staged) ----------------
__global__ __launch_bounds__(256) void k_score_f32(
    const float* __restrict__ hs, const unsigned short* __restrict__ Mt,
    const float* __restrict__ alphav, const float* __restrict__ betav,
    unsigned short* __restrict__ P) {
  int id = blockIdx.x;
  int x = id & 7, idp = id >> 3;
  int n_t = idp & 7;
  int pid = (idp >> 3) * 8 + x;
  int b = pid >> 5, m_t = pid & 31;
  int m0 = m_t * 128, n0 = n_t * 160;
  const float* Af = hs + (size_t)b * LQ_ * D_;
  const unsigned short* Bb = Mt + (size_t)b * NC_ * D_;
  const float* alp = alphav + b * NC_;
  const float* bet = betav + b * NC_;
  unsigned short* Pb = P + (size_t)b * LQ_ * NC_;
  __shared__ short As[128 * 64];
  __shared__ short Bs[160 * 64];
  int t = threadIdx.x, lane = t & 63, wid = t >> 6;
  int wm = wid >> 1, wn = wid & 1;
  int srow = lane >> 3;
  int schunk = (lane & 7) ^ srow;
  f4 acc[4][5] = {};
  for (int k0 = 0; k0 < D_; k0 += 64) {
    __syncthreads();
    for (int i = wid; i < 20; i += 4)
      gload16(Bb + (size_t)(n0 + i * 8 + srow) * D_ + k0 + schunk * 8, (char*)Bs + i * 1024);
    int arow = t >> 3, ac = t & 7;
    int awc = ac ^ (arow & 7);
#pragma unroll
    for (int p = 0; p < 4; ++p) {
      int row = p * 32 + arow;
      const float* src = Af + (size_t)(m0 + row) * D_ + k0 + ac * 8;
      f4 v0 = *(const f4*)src;
      f4 v1 = *(const f4*)(src + 4);
      us8 u;
#pragma unroll
      for (int j = 0; j < 4; ++j) { u[j] = f2bf(v0[j]); u[4 + j] = f2bf(v1[j]); }
      *(us8*)(As + row * 64 + awc * 8) = u;
    }
    __syncthreads();
#pragma unroll
    for (int kk = 0; kk < 2; ++kk) {
      int co = ((kk * 4 + (lane >> 4)) ^ (lane & 7)) * 8;
      short8 fa[4], fb[5];
#pragma unroll
      for (int mi = 0; mi < 4; ++mi)
        fa[mi] = *(const short8*)(As + (wm * 64 + mi * 16 + (lane & 15)) * 64 + co);
#pragma unroll
      for (int ni = 0; ni < 5; ++ni)
        fb[ni] = *(const short8*)(Bs + (wn * 80 + ni * 16 + (lane & 15)) * 64 + co);
#pragma unroll
      for (int mi = 0; mi < 4; ++mi)
#pragma unroll
        for (int ni = 0; ni < 5; ++ni)
          acc[mi][ni] = __builtin_amdgcn_mfma_f32_16x16x32_bf16(fa[mi], fb[ni], acc[mi][ni], 0, 0, 0);
    }
  }
  float al[5], be[5];
#pragma unroll
  for (int ni = 0; ni < 5; ++ni) {
    int cc = n0 + wn * 80 + ni * 16 + (lane & 15);
    al[ni] = alp[cc]; be[ni] = bet[cc];
  }
#pragma unroll
  for (int mi = 0; mi < 4; ++mi) {
#pragma unroll
    for (int j = 0; j < 4; ++j) {
      float v[5];
      float m = -3.0e38f;
#pragma unroll
      for (int ni = 0; ni < 5; ++ni) { v[ni] = acc[mi][ni][j] * al[ni] + be[ni]; m = fmaxf(m, v[ni]); }
#pragma unroll
      for (int off = 1; off < 16; off <<= 1) m = fmaxf(m, __shfl_xor(m, off, 64));
      float ssum = 0.f;
#pragma unroll
      for (int ni = 0; ni < 5; ++ni) { v[ni] = __expf(v[ni] - m); ssum += v[ni]; }
#pragma unroll
      for (int off = 1; off < 16; off <<= 1) ssum += __shfl_xor(ssum, off, 64);
      float inv = 1.f / ssum;
      int row = m0 + wm * 64 + mi * 16 + (lane >> 4) * 4 + j;
      size_t rb = (size_t)row * NC_ + n0 + wn * 80 + (lane & 15);
#pragma unroll
      for (int ni = 0; ni < 5; ++ni)
        Pb[rb + ni * 16] = f2bf(v[ni] * inv);
    }
  }
}

// ---------------- out GEMM 256x256 (UNCHANGED from R11) ----------------
__global__ __launch_bounds__(512, 2) void k_out_big(
    const unsigned short* __restrict__ P, const unsigned short* __restrict__ Ut,
    const float* __restrict__ bo, float* __restrict__ out) {
  extern __shared__ short lds[];
  int id = blockIdx.x;
  int x = id & 7, idp = id >> 3;
  int nt = idp & 3;
  int pid = (idp >> 2) * 8 + x;
  int b = pid >> 4, mt = pid & 15;
  int m0 = mt * 256, n0 = nt * 256;

  const unsigned short* Ab = P + (size_t)b * LQ_ * NC_;
  const unsigned short* Bb = Ut + (size_t)b * D_ * NC_;
  float* ob = out + (size_t)b * LQ_ * D_;

  int t = threadIdx.x, lane = t & 63, wid = t >> 6;
  int wm = wid >> 2, wn = wid & 3;
  int r = lane & 15, q = lane >> 4;
  f4 acc[8][4] = {};
  const int T = NC_ / 32;   // 40

  auto SA = [&](int bf, int k0, int p) {
    int cb = p * 512 + wid * 64;
    int cc = cb + lane;
    int row = cc >> 2, gc = (cc & 3) ^ ((row >> 1) & 3);
    gload16(Ab + (size_t)(m0 + row) * NC_ + k0 + gc * 8, (char*)(lds + bf * 8192) + cb * 16);
  };
  auto SB = [&](int bf, int k0, int p) {
    int cb = p * 512 + wid * 64;
    int cc = cb + lane;
    int row = cc >> 2, gc = (cc & 3) ^ ((row >> 1) & 3);
    gload16(Bb + (size_t)(n0 + row) * NC_ + k0 + gc * 8, (char*)(lds + 32768 + bf * 8192) + cb * 16);
  };
  auto STAGE_P1 = [&](int h) { if (h < T) { int bf = h & 3, k0 = h * 32; SA(bf, k0, 0); SA(bf, k0, 1); } };
  auto STAGE_P2 = [&](int h) { if (h < T) { int bf = h & 3, k0 = h * 32; SB(bf, k0, 0); SB(bf, k0, 1); } };

  STAGE_P1(0); STAGE_P2(0);
  STAGE_P1(1); STAGE_P2(1);
  STAGE_P1(2); STAGE_P2(2);
  asm volatile("s_waitcnt vmcnt(8)" ::: "memory");
  __builtin_amdgcn_s_barrier();

#pragma unroll 1
  for (int h = 0; h < T; ++h) {
    int bf = h & 3;
    const short* Ar = lds + bf * 8192;
    const short* Br = lds + 32768 + bf * 8192;
    short8 fa[4], fb[4];

#pragma unroll
    for (int ni = 0; ni < 4; ++ni) {
      int row = wn * 64 + ni * 16 + r;
      fb[ni] = *(const short8*)(Br + row * 32 + ((q ^ ((row >> 1) & 3)) * 8));
    }
#pragma unroll
    for (int mi = 0; mi < 4; ++mi) {
      int row = wm * 128 + mi * 16 + r;
      fa[mi] = *(const short8*)(Ar + row * 32 + ((q ^ ((row >> 1) & 3)) * 8));
    }
    __builtin_amdgcn_sched_barrier(0);
    STAGE_P1(h + 3);
    __builtin_amdgcn_sched_barrier(0);
    __builtin_amdgcn_s_barrier();
    asm volatile("s_waitcnt lgkmcnt(0)");
    __builtin_amdgcn_s_setprio(1);
#pragma unroll
    for (int mi = 0; mi < 4; ++mi)
#pragma unroll
      for (int ni = 0; ni < 4; ++ni)
        acc[mi][ni] = __builtin_amdgcn_mfma_f32_16x16x32_bf16(fa[mi], fb[ni], acc[mi][ni], 0, 0, 0);
    __builtin_amdgcn_s_setprio(0);

#pragma unroll
    for (int mi = 0; mi < 4; ++mi) {
      int row = wm * 128 + (4 + mi) * 16 + r;
      fa[mi] = *(const short8*)(Ar + row * 32 + ((q ^ ((row >> 1) & 3)) * 8));
    }
    __builtin_amdgcn_sched_barrier(0);
    STAGE_P2(h + 3);
    __builtin_amdgcn_sched_barrier(0);
    __builtin_amdgcn_s_barrier();
    asm volatile("s_waitcnt lgkmcnt(0)");
    __builtin_amdgcn_s_setprio(1);
#pragma unroll
    for (int mi = 0; mi < 4; ++mi)
#pragma unroll
      for (int ni = 0; ni < 4; ++ni)
        acc[4 + mi][ni] = __builtin_amdgcn_mfma_f32_16x16x32_bf16(fa[mi], fb[ni], acc[4 + mi][ni], 0, 0, 0);
    __builtin_amdgcn_s_setprio(0);

    if (h <= T - 4) {
      asm volatile("s_waitcnt vmcnt(8)" ::: "memory");
    } else if (h == T - 3) {
      asm volatile("s_waitcnt vmcnt(4)" ::: "memory");
    } else if (h == T - 2) {
      asm volatile("s_waitcnt vmcnt(0)" ::: "memory");
    }
    if (h < T - 1) __builtin_amdgcn_s_barrier();
  }

#pragma unroll
  for (int ni = 0; ni < 4; ++ni) {
    int col = n0 + wn * 64 + ni * 16 + r;
    float bov = bo[col];
#pragma unroll
    for (int mi = 0; mi < 8; ++mi)
#pragma unroll
      for (int j = 0; j < 4; ++j) {
        int row = m0 + wm * 128 + mi * 16 + q * 4 + j;
        ob[(size_t)row * D_ + col] = acc[mi][ni][j] + bov;
      }
  }
}

extern "C" void kernel_launch(void* const* d_in, const int* in_sizes, int n_in,
                              void* d_out, int out_size, void* d_ws, size_t ws_size,
                              hipStream_t stream) {
  const float* hs  = (const float*)d_in[0];
  const float* ehs = (const float*)d_in[1];
  const float* Wq  = (const float*)d_in[2];
  const float* Wk  = (const float*)d_in[3];
  const float* Wv  = (const float*)d_in[4];
  const float* Wo  = (const float*)d_in[5];
  const float* bo  = (const float*)d_in[6];
  const float* Ak  = (const float*)d_in[7];
  const float* Bk  = (const float*)d_in[8];
  const float* Av  = (const float*)d_in[9];
  const float* Bv  = (const float*)d_in[10];
  const float* Ao  = (const float*)d_in[11];
  const float* Bo  = (const float*)d_in[12];
  const float* csf = (const float*)d_in[13];
  const int*   sb  = (const int*)d_in[14];
  const int*   sn  = (const int*)d_in[15];
  float* out = (float*)d_out;

  hipFuncSetAttribute(reinterpret_cast<const void*>(k_score_big),
                      hipFuncAttributeMaxDynamicSharedMemorySize, 147456);
  hipFuncSetAttribute(reinterpret_cast<const void*>(k_out_big),
                      hipFuncAttributeMaxDynamicSharedMemorySize, 131072);

  char* ws = (char*)d_ws;
  unsigned short* P  = (unsigned short*)ws;                   // 83,886,080
  unsigned short* Mt = (unsigned short*)(ws + 83886080);      // 20,971,520
  unsigned short* Ut = (unsigned short*)(ws + 104857600);     // 20,971,520
  const size_t NEED_HSB = 125829120ULL + 67108864ULL + 81920ULL; // 193,019,904
  bool useHsb = ws_size >= NEED_HSB;
  unsigned short* hsb = useHsb ? (unsigned short*)(ws + 125829120) : nullptr;
  char* tail = useHsb ? (ws + 192937984) : (ws + 125829120);
  float* alphav = (float*)tail;
  float* betav  = (float*)(tail + 40960);
  // temporaries overlapped into P's region (all dead before k_score writes P):
  unsigned short* kvb   = (unsigned short*)(ws + 0);          //  2,621,440
  unsigned short* wEb   = (unsigned short*)(ws + 2621440);    //  6,291,456
  unsigned short* wqTb  = (unsigned short*)(ws + 8912896);    //  2,097,152
  float*          aT    = (float*)(ws + 11010048);            //  2,359,296
  unsigned short* ehsb  = (unsigned short*)(ws + 13369344);   //  1,310,720
  float*          part  = (float*)(ws + 14680064);            //  2,097,152
  float*          hssum = (float*)(ws + 16777216);            //     32,768

  float* akT = aT;
  float* avT = aT + 196608;
  float* aoT = aT + 393216;

  const float LS = 16.0f / 192.0f;

  // hs row-sums (deterministic two-stage) + bf16 conversion of hs
  k_hssum<<<dim3(64, 8), 256, 0, stream>>>(hs, part, hsb);
  k_hsred<<<32, 256, 0, stream>>>(part, hssum);

  // transposes (Wq -> bf16 wqTb; LoRA-A -> fp32) + ehs -> bf16 padded
  k_tr4<<<dim3(32, 32, 4), 256, 0, stream>>>(Wq, Ak, Av, Ao, wqTb, akT, avT, aoT);
  k_ehsb<<<dim3(SP_, B_), 256, 0, stream>>>(ehs, ehsb);

  // W_eff (k,v,o) -> bf16 wEb in one launch
  k_weff<<<dim3(16, 16, 3), 256, 0, stream>>>(Bk, Bv, Bo, akT, avT, aoT, Wk, Wv, Wo, wEb, LS);

  // kv = ehsb @ wEb[k|v]^T  (bf16, 64 blocks)
  k_kv<<<64, 512, 0, stream>>>(ehsb, wEb, kvb);

  // Mt + Ut panels, one block per (b,h) each
  k_mtut<<<256, 512, 0, stream>>>(kvb, wqTb, wEb, Mt, Ut);

  // per-(b,h,s) column mean (qmean fused) + subject alpha/beta
  k_mubeta<<<dim3(16, 8), 128, 0, stream>>>(hssum, Wq, kvb, sb, sn, csf, alphav, betav);

  // big fused GEMMs (unchanged R11)
  if (useHsb)
    k_score_big<<<512, 512, 147456, stream>>>(hsb, Mt, alphav, betav, P);
  else
    k_score_f32<<<2048, 256, 0, stream>>>(hs, Mt, alphav, betav, P);
  k_out_big<<<512, 512, 131072, stream>>>(P, Ut, bo, out);

  (void)in_sizes; (void)n_in; (void)out_size; (void)ws_size;
}

// Round 14
// 331.127 us; speedup vs baseline: 1.1812x; 1.0395x over previous
//
#include <hip/hip_runtime.h>
#include <stdint.h>

#define B_     8
#define LQ_    4096
#define S_     77
#define SP_    80
#define D_     1024
#define H_     16
#define HD_    64
#define NC_    1280   // H_*SP_
#define NSUBJ_ 32

typedef __attribute__((ext_vector_type(4))) float  f4;
typedef __attribute__((ext_vector_type(8))) short  short8;
typedef __attribute__((ext_vector_type(8))) unsigned short us8;
typedef __attribute__((ext_vector_type(4))) unsigned short us4;

__device__ __forceinline__ unsigned short f2bf(float f) {
  union { float f; unsigned u; } x; x.f = f;
  unsigned r = x.u + 0x7FFFu + ((x.u >> 16) & 1u);
  return (unsigned short)(r >> 16);
}
__device__ __forceinline__ float bf2f(unsigned short v) {
  union { unsigned u; float f; } x; x.u = ((unsigned)v) << 16;
  return x.f;
}

__device__ __forceinline__ void gload16(const void* g, void* s) {
  __builtin_amdgcn_global_load_lds((const __attribute__((address_space(1))) void*)g,
                                   (__attribute__((address_space(3))) void*)s, 16, 0, 0);
}

// ---------------- hssum partials + hs -> bf16 convert ----------------
__global__ __launch_bounds__(256) void k_hssum(const float* __restrict__ hs,
                                               float* __restrict__ part,
                                               unsigned short* __restrict__ hsb) {
  int b = blockIdx.y;
  size_t base = ((size_t)b * LQ_ + (size_t)blockIdx.x * 64) * D_ + threadIdx.x * 4;
  f4 acc = {0.f, 0.f, 0.f, 0.f};
  for (int l = 0; l < 64; ++l) {
    f4 v = *(const f4*)(hs + base + (size_t)l * D_);
    acc += v;
    if (hsb) {
      us4 o;
#pragma unroll
      for (int j = 0; j < 4; ++j) o[j] = f2bf(v[j]);
      *(us4*)(hsb + base + (size_t)l * D_) = o;
    }
  }
  *(f4*)(part + (size_t)blockIdx.x * (B_ * D_) + b * D_ + threadIdx.x * 4) = acc;
}

__global__ __launch_bounds__(256) void k_hsred(const float* __restrict__ part,
                                               float* __restrict__ hssum) {
  int i = blockIdx.x * 256 + threadIdx.x;   // [0, 8192)
  float s = 0.f;
  for (int x = 0; x < 64; ++x) s += part[(size_t)x * (B_ * D_) + i];
  hssum[i] = s;
}

// ---------------- k_prep: all small format conversions in ONE launch ----------------
// z=0: Wq^T -> wqTb bf16 [1024][1024]
// z=1..3: Ak/Av/Ao^T -> aTb bf16 [z-1][1024][192]
// z=4: ehs -> ehsb bf16 padded [8][80][1024] (rows 77..79 zero)
// z=5..7: Bk/Bv/Bo -> bxb bf16 [z-5][1024][192]
__global__ __launch_bounds__(256) void k_prep(
    const float* __restrict__ Wq, const float* __restrict__ Ak,
    const float* __restrict__ Av, const float* __restrict__ Ao,
    const float* __restrict__ ehs,
    const float* __restrict__ Bk, const float* __restrict__ Bv, const float* __restrict__ Bo,
    unsigned short* __restrict__ wqTb, unsigned short* __restrict__ aTb,
    unsigned short* __restrict__ ehsb, unsigned short* __restrict__ bxb) {
  int z = blockIdx.z;
  int t = threadIdx.x;
  if (z == 4) {
    if (blockIdx.y >= 20) return;            // 640 rows
    int gr = blockIdx.y * 32 + (t >> 3);
    int col = blockIdx.x * 32 + (t & 7) * 4;
    int b = gr / SP_, s = gr - b * SP_;
    us4 o = {0, 0, 0, 0};
    if (s < S_) {
      f4 v = *(const f4*)(ehs + ((size_t)b * S_ + s) * D_ + col);
#pragma unroll
      for (int j = 0; j < 4; ++j) o[j] = f2bf(v[j]);
    }
    *(us4*)(ehsb + (size_t)gr * D_ + col) = o;
    return;
  }
  if (z >= 5) {
    if (blockIdx.x >= 6) return;             // 192 cols
    const float* in = z == 5 ? Bk : (z == 6 ? Bv : Bo);
    unsigned short* outp = bxb + (size_t)(z - 5) * 1024 * 192;
    int rr = blockIdx.y * 32 + (t >> 3);
    int c = blockIdx.x * 32 + (t & 7) * 4;
    f4 v = *(const f4*)(in + (size_t)rr * 192 + c);
    us4 o;
#pragma unroll
    for (int j = 0; j < 4; ++j) o[j] = f2bf(v[j]);
    *(us4*)(outp + (size_t)rr * 192 + c) = o;
    return;
  }
  // z = 0..3: transpose
  const float* in = z == 0 ? Wq : (z == 1 ? Ak : (z == 2 ? Av : Ao));
  int R = z == 0 ? 1024 : 192;
  int c0 = blockIdx.x * 32, r0 = blockIdx.y * 32;
  if (r0 >= R) return;
  __shared__ float tile[32][33];
  int tx = t & 31, ty = t >> 5;
#pragma unroll
  for (int k = 0; k < 4; ++k)
    tile[ty + 8 * k][tx] = in[(size_t)(r0 + ty + 8 * k) * 1024 + c0 + tx];
  __syncthreads();
  unsigned short* outp = z == 0 ? wqTb : (aTb + (size_t)(z - 1) * 1024 * 192);
#pragma unroll
  for (int k = 0; k < 4; ++k)
    outp[(size_t)(c0 + ty + 8 * k) * R + r0 + tx] = f2bf(tile[tx][ty + 8 * k]);
}

// ---------------- W_eff = W + LS*(Bx@Ax) -> bf16 wEb. 128x128 tile, BK=64 ----------------
__global__ __launch_bounds__(256) void k_weff_big(
    const unsigned short* __restrict__ bxb, const unsigned short* __restrict__ aTb,
    const float* __restrict__ Wk, const float* __restrict__ Wv, const float* __restrict__ Wo,
    unsigned short* __restrict__ wEb, float alpha) {
  __shared__ short As[128 * 64];
  __shared__ short Bs[128 * 64];
  int z = blockIdx.z;
  const unsigned short* Ab = bxb + (size_t)z * 1024 * 192;
  const unsigned short* Bb = aTb + (size_t)z * 1024 * 192;
  const float* Dm = z == 0 ? Wk : (z == 1 ? Wv : Wo);
  int m0 = blockIdx.x * 128, n0 = blockIdx.y * 128;
  int t = threadIdx.x, lane = t & 63, w = t >> 6;
  int wm = w >> 1, wn = w & 1;
  int r = lane & 15, q = lane >> 4;
  f4 acc[4][4] = {};

  for (int k0 = 0; k0 < 192; k0 += 64) {
    __syncthreads();
#pragma unroll
    for (int p = 0; p < 8; ++p) {
      int cb = p * 256 + w * 64;             // wave-uniform; A: 0..1023, B: 1024..2047
      int cc = cb + lane;
      if (cb < 1024) {
        int row = cc >> 3, gc = (cc & 7) ^ (row & 7);
        gload16(Ab + (size_t)(m0 + row) * 192 + k0 + gc * 8, (char*)As + cb * 16);
      } else {
        int bc = cc - 1024, row = bc >> 3, gc = (bc & 7) ^ (row & 7);
        gload16(Bb + (size_t)(n0 + row) * 192 + k0 + gc * 8, (char*)Bs + (cb - 1024) * 16);
      }
    }
    __syncthreads();
#pragma unroll
    for (int kk = 0; kk < 2; ++kk) {
      short8 fa[4], fb[4];
#pragma unroll
      for (int mi = 0; mi < 4; ++mi) {
        int row = wm * 64 + mi * 16 + r;
        fa[mi] = *(const short8*)(As + row * 64 + (((kk * 4 + q) ^ (row & 7)) * 8));
      }
#pragma unroll
      for (int ni = 0; ni < 4; ++ni) {
        int row = wn * 64 + ni * 16 + r;
        fb[ni] = *(const short8*)(Bs + row * 64 + (((kk * 4 + q) ^ (row & 7)) * 8));
      }
#pragma unroll
      for (int mi = 0; mi < 4; ++mi)
#pragma unroll
        for (int ni = 0; ni < 4; ++ni)
          acc[mi][ni] = __builtin_amdgcn_mfma_f32_16x16x32_bf16(fa[mi], fb[ni], acc[mi][ni], 0, 0, 0);
    }
  }
#pragma unroll
  for (int mi = 0; mi < 4; ++mi)
#pragma unroll
    for (int ni = 0; ni < 4; ++ni)
#pragma unroll
      for (int j = 0; j < 4; ++j) {
        int row = m0 + wm * 64 + mi * 16 + q * 4 + j;
        int col = n0 + wn * 64 + ni * 16 + r;
        float val = acc[mi][ni][j] * alpha + Dm[(size_t)row * 1024 + col];
        wEb[(size_t)z * 1048576 + (size_t)row * 1024 + col] = f2bf(val);
      }
}

// ---------------- kv = ehsb @ wEb[k|v]^T  (bf16, 256 blocks, tile 80x64) ----------------
__global__ __launch_bounds__(256) void k_kv(const unsigned short* __restrict__ ehsb,
                                            const unsigned short* __restrict__ wEb,
                                            unsigned short* __restrict__ kvb) {
  __shared__ short As[80 * 64];    // 10 KB
  __shared__ short Bs[64 * 64];    //  8 KB
  int b = blockIdx.x >> 5, nt = blockIdx.x & 31;
  int n0 = nt * 64;
  const unsigned short* Ab = ehsb + (size_t)b * SP_ * D_;
  int t = threadIdx.x, lane = t & 63, w = t >> 6;   // 4 waves, wave n-slice 16
  int r = lane & 15, q = lane >> 4;
  f4 acc[5] = {{0,0,0,0},{0,0,0,0},{0,0,0,0},{0,0,0,0},{0,0,0,0}};

  for (int k0 = 0; k0 < 1024; k0 += 64) {
    __syncthreads();
    // 1152 chunks: A 0..639, B 640..1151 (640 % 64 == 0: wave-uniform regions)
#pragma unroll
    for (int p = 0; p < 5; ++p) {
      int cb = p * 256 + w * 64;
      if (cb < 1152) {
        int cc = cb + lane;
        if (cb < 640) {
          int row = cc >> 3, gc = (cc & 7) ^ (row & 7);
          gload16(Ab + (size_t)row * D_ + k0 + gc * 8, (char*)As + cb * 16);
        } else {
          int bc = cc - 640, row = bc >> 3, gc = (bc & 7) ^ (row & 7);
          gload16(wEb + (size_t)(n0 + row) * D_ + k0 + gc * 8, (char*)Bs + (cb - 640) * 16);
        }
      }
    }
    __syncthreads();
#pragma unroll
    for (int kk = 0; kk < 2; ++kk) {
      short8 fa[5], fb;
      {
        int row = w * 16 + r;
        fb = *(const short8*)(Bs + row * 64 + (((kk * 4 + q) ^ (row & 7)) * 8));
      }
#pragma unroll
      for (int mi = 0; mi < 5; ++mi) {
        int row = mi * 16 + r;
        fa[mi] = *(const short8*)(As + row * 64 + (((kk * 4 + q) ^ (row & 7)) * 8));
      }
#pragma unroll
      for (int mi = 0; mi < 5; ++mi)
        acc[mi] = __builtin_amdgcn_mfma_f32_16x16x32_bf16(fa[mi], fb, acc[mi], 0, 0, 0);
    }
  }
#pragma unroll
  for (int mi = 0; mi < 5; ++mi)
#pragma unroll
    for (int j = 0; j < 4; ++j) {
      int s = mi * 16 + q * 4 + j;
      int col = n0 + w * 16 + r;
      kvb[((size_t)b * SP_ + s) * 2048 + col] = f2bf(acc[mi][j]);
    }
}

// ---------------- Mt + Ut: one block per (b,h) panel (UNCHANGED R12) ----------------
__global__ __launch_bounds__(512) void k_mtut(const unsigned short* __restrict__ kvb,
                                              const unsigned short* __restrict__ wqTb,
                                              const unsigned short* __restrict__ wEb,
                                              unsigned short* __restrict__ Mt,
                                              unsigned short* __restrict__ Ut) {
  __shared__ short Ss[80 * 64];
  __shared__ short Ls[256 * 64];
  int z = blockIdx.x;
  bool mt = z < 128;
  int zz = mt ? z : z - 128;
  int b = zz >> 4, h = zz & 15;
  const unsigned short* small_src = kvb + (size_t)b * SP_ * 2048 + (mt ? h * 64 : 1024 + h * 64);
  const unsigned short* large_src = mt ? (wqTb + h * 64) : (wEb + (size_t)2048 * 1024 + h * 64);
  int t = threadIdx.x, lane = t & 63, w = t >> 6;
  int r = lane & 15, q = lane >> 4;

#pragma unroll
  for (int p = 0; p < 2; ++p) {
    int cb = p * 512 + w * 64;
    if (cb < 640) {
      int cc = cb + lane, row = cc >> 3, gc = (cc & 7) ^ (row & 7);
      gload16(small_src + (size_t)row * 2048 + gc * 8, (char*)Ss + cb * 16);
    }
  }

  for (int mc = 0; mc < 4; ++mc) {
    __syncthreads();
#pragma unroll
    for (int p = 0; p < 4; ++p) {
      int cb = p * 512 + w * 64;
      int cc = cb + lane, row = cc >> 3, gc = (cc & 7) ^ (row & 7);
      gload16(large_src + (size_t)(mc * 256 + row) * 1024 + gc * 8, (char*)Ls + cb * 16);
    }
    __syncthreads();

    if (mt) {
      f4 acc[5][2] = {};
#pragma unroll
      for (int kk = 0; kk < 2; ++kk) {
        int co = ((kk * 4 + q) ^ (r & 7)) * 8;
        short8 fa[5], fb[2];
#pragma unroll
        for (int mi = 0; mi < 5; ++mi)
          fa[mi] = *(const short8*)(Ss + (mi * 16 + r) * 64 + co);
#pragma unroll
        for (int ni = 0; ni < 2; ++ni)
          fb[ni] = *(const short8*)(Ls + (w * 32 + ni * 16 + r) * 64 + co);
#pragma unroll
        for (int mi = 0; mi < 5; ++mi)
#pragma unroll
          for (int ni = 0; ni < 2; ++ni)
            acc[mi][ni] = __builtin_amdgcn_mfma_f32_16x16x32_bf16(fa[mi], fb[ni], acc[mi][ni], 0, 0, 0);
      }
#pragma unroll
      for (int mi = 0; mi < 5; ++mi)
#pragma unroll
        for (int ni = 0; ni < 2; ++ni)
#pragma unroll
          for (int j = 0; j < 4; ++j) {
            int s = mi * 16 + q * 4 + j;
            int e = mc * 256 + w * 32 + ni * 16 + r;
            Mt[((size_t)b * NC_ + h * SP_ + s) * 1024 + e] = f2bf(acc[mi][ni][j] * 0.125f);
          }
    } else {
      f4 acc[2][5] = {};
#pragma unroll
      for (int kk = 0; kk < 2; ++kk) {
        int co = ((kk * 4 + q) ^ (r & 7)) * 8;
        short8 fa[2], fb[5];
#pragma unroll
        for (int mi = 0; mi < 2; ++mi)
          fa[mi] = *(const short8*)(Ls + (w * 32 + mi * 16 + r) * 64 + co);
#pragma unroll
        for (int ni = 0; ni < 5; ++ni)
          fb[ni] = *(const short8*)(Ss + (ni * 16 + r) * 64 + co);
#pragma unroll
        for (int mi = 0; mi < 2; ++mi)
#pragma unroll
          for (int ni = 0; ni < 5; ++ni)
            acc[mi][ni] = __builtin_amdgcn_mfma_f32_16x16x32_bf16(fa[mi], fb[ni], acc[mi][ni], 0, 0, 0);
      }
#pragma unroll
      for (int mi = 0; mi < 2; ++mi)
#pragma unroll
        for (int ni = 0; ni < 5; ++ni)
#pragma unroll
          for (int j = 0; j < 4; ++j) {
            int e = mc * 256 + w * 32 + mi * 16 + q * 4 + j;
            int col = h * SP_ + ni * 16 + r;
            Ut[((size_t)b * D_ + e) * NC_ + col] = f2bf(acc[mi][ni][j]);
          }
    }
  }
}

// ---------------- mu/alpha/beta per (b,h,s) (UNCHANGED R12) ----------------
__global__ void k_mubeta(const float* __restrict__ hssum, const float* __restrict__ Wq,
                         const unsigned short* __restrict__ kvb,
                         const int* __restrict__ sb, const int* __restrict__ sn,
                         const float* __restrict__ csf_p,
                         float* __restrict__ alphav, float* __restrict__ betav) {
  int h = blockIdx.x, b = blockIdx.y;
  int t = threadIdx.x;
  __shared__ float qp[64];
  {
    int hd = t >> 1, half = t & 1;
    const float* wr = Wq + (size_t)(h * 64 + hd) * D_ + half * 512;
    const float* hp = hssum + b * D_ + half * 512;
    float s = 0.f;
    for (int d = 0; d < 512; d += 4) {
      f4 w = *(const f4*)(wr + d);
      f4 x = *(const f4*)(hp + d);
      s += w[0] * x[0] + w[1] * x[1] + w[2] * x[2] + w[3] * x[3];
    }
    s += __shfl_xor(s, 1, 64);
    if (half == 0) qp[hd] = s * (1.f / 4096.f);
  }
  __syncthreads();
  int s = t;
  if (s >= SP_) return;
  const unsigned short* kp = kvb + ((size_t)(b * SP_ + s)) * 2048 + h * HD_;
  float mu = 0.f;
#pragma unroll
  for (int hd = 0; hd < HD_; hd += 4) {
    us4 kv = *(const us4*)(kp + hd);
#pragma unroll
    for (int j = 0; j < 4; ++j) mu += qp[hd + j] * bf2f(kv[j]);
  }
  mu *= 0.125f;
  bool subj = false;
  for (int i = 0; i < NSUBJ_; ++i) subj = subj || (sb[i] == b && sn[i] == s);
  float csf = *csf_p;
  int c = b * NC_ + h * SP_ + s;
  alphav[c] = subj ? csf : 1.f;
  betav[c] = (s >= S_) ? -1e30f : (subj ? -mu * csf : 0.f);
}

// ---------------- score GEMM 256x320 (UNCHANGED from R11) ----------------
__global__ __launch_bounds__(512, 2) void k_score_big(
    const unsigned short* __restrict__ hsb, const unsigned short* __restrict__ Mt,
    const float* __restrict__ alphav, const float* __restrict__ betav,
    unsigned short* __restrict__ P) {
  extern __shared__ short lds[];
  int id = blockIdx.x;
  int x = id & 7, idp = id >> 3;
  int nt = idp & 3;
  int pid = (idp >> 2) * 8 + x;
  int b = pid >> 4, mt = pid & 15;
  int m0 = mt * 256, n0 = nt * 320;

  const unsigned short* Ab = hsb + (size_t)b * LQ_ * D_;
  const unsigned short* Bb = Mt + (size_t)b * NC_ * D_;
  const float* alp = alphav + b * NC_;
  const float* bet = betav + b * NC_;
  unsigned short* Pb = P + (size_t)b * LQ_ * NC_;

  int t = threadIdx.x, lane = t & 63, wid = t >> 6;
  int wm = wid >> 2, wn = wid & 3;
  int r = lane & 15, q = lane >> 4;
  f4 acc[8][5] = {};

  auto SA = [&](int bf, int k0, int p) {
    int cb = p * 512 + wid * 64;
    int cc = cb + lane;
    int row = cc >> 2, gc = (cc & 3) ^ ((row >> 1) & 3);
    gload16(Ab + (size_t)(m0 + row) * D_ + k0 + gc * 8, (char*)(lds + bf * 8192) + cb * 16);
  };
  auto SB = [&](int bf, int k0, int p) {
    int cb = p * 512 + wid * 64;
    int cc = cb + lane;
    int row = cc >> 2, gc = (cc & 3) ^ ((row >> 1) & 3);
    gload16(Bb + (size_t)(n0 + row) * D_ + k0 + gc * 8, (char*)(lds + 32768 + bf * 10240) + cb * 16);
  };
  auto SBx = [&](int bf, int k0) {
    if (wid < 4) {
      int cb = 1024 + wid * 64;
      int cc = cb + lane;
      int row = cc >> 2, gc = (cc & 3) ^ ((row >> 1) & 3);
      gload16(Bb + (size_t)(n0 + row) * D_ + k0 + gc * 8, (char*)(lds + 32768 + bf * 10240) + cb * 16);
    }
  };
  auto STAGE_P1 = [&](int h) { if (h < 32) { int bf = h & 3, k0 = h * 32; SA(bf, k0, 0); SA(bf, k0, 1); SB(bf, k0, 0); } };
  auto STAGE_P2 = [&](int h) { if (h < 32) { int bf = h & 3, k0 = h * 32; SB(bf, k0, 1); SBx(bf, k0); } };

  STAGE_P1(0); STAGE_P2(0);
  STAGE_P1(1); STAGE_P2(1);
  STAGE_P1(2); STAGE_P2(2);
  if (wid < 4) asm volatile("s_waitcnt vmcnt(10)" ::: "memory");
  else         asm volatile("s_waitcnt vmcnt(8)" ::: "memory");
  __builtin_amdgcn_s_barrier();

#pragma unroll 1
  for (int h = 0; h < 32; ++h) {
    int bf = h & 3;
    const short* Ar = lds + bf * 8192;
    const short* Br = lds + 32768 + bf * 10240;
    short8 fa[4], fb[5];

#pragma unroll
    for (int ni = 0; ni < 5; ++ni) {
      int row = wn * 80 + ni * 16 + r;
      fb[ni] = *(const short8*)(Br + row * 32 + ((q ^ ((row >> 1) & 3)) * 8));
    }
#pragma unroll
    for (int mi = 0; mi < 4; ++mi) {
      int row = wm * 128 + mi * 16 + r;
      fa[mi] = *(const short8*)(Ar + row * 32 + ((q ^ ((row >> 1) & 3)) * 8));
    }
    __builtin_amdgcn_sched_barrier(0);
    STAGE_P1(h + 3);
    __builtin_amdgcn_sched_barrier(0);
    __builtin_amdgcn_s_barrier();
    asm volatile("s_waitcnt lgkmcnt(0)");
    __builtin_amdgcn_s_setprio(1);
#pragma unroll
    for (int mi = 0; mi < 4; ++mi)
#pragma unroll
      for (int ni = 0; ni < 5; ++ni)
        acc[mi][ni] = __builtin_amdgcn_mfma_f32_16x16x32_bf16(fa[mi], fb[ni], acc[mi][ni], 0, 0, 0);
    __builtin_amdgcn_s_setprio(0);

#pragma unroll
    for (int mi = 0; mi < 4; ++mi) {
      int row = wm * 128 + (4 + mi) * 16 + r;
      fa[mi] = *(const short8*)(Ar + row * 32 + ((q ^ ((row >> 1) & 3)) * 8));
    }
    __builtin_amdgcn_sched_barrier(0);
    STAGE_P2(h + 3);
    __builtin_amdgcn_sched_barrier(0);
    __builtin_amdgcn_s_barrier();
    asm volatile("s_waitcnt lgkmcnt(0)");
    __builtin_amdgcn_s_setprio(1);
#pragma unroll
    for (int mi = 0; mi < 4; ++mi)
#pragma unroll
      for (int ni = 0; ni < 5; ++ni)
        acc[4 + mi][ni] = __builtin_amdgcn_mfma_f32_16x16x32_bf16(fa[mi], fb[ni], acc[4 + mi][ni], 0, 0, 0);
    __builtin_amdgcn_s_setprio(0);

    if (h <= 28) {
      if (wid < 4) asm volatile("s_waitcnt vmcnt(10)" ::: "memory");
      else         asm volatile("s_waitcnt vmcnt(8)" ::: "memory");
    } else if (h == 29) {
      if (wid < 4) asm volatile("s_waitcnt vmcnt(5)" ::: "memory");
      else         asm volatile("s_waitcnt vmcnt(4)" ::: "memory");
    } else if (h == 30) {
      asm volatile("s_waitcnt vmcnt(0)" ::: "memory");
    }
    if (h < 31) __builtin_amdgcn_s_barrier();
  }

  float al[5], be[5];
#pragma unroll
  for (int ni = 0; ni < 5; ++ni) {
    int cc = n0 + wn * 80 + ni * 16 + r;
    al[ni] = alp[cc]; be[ni] = bet[cc];
  }
#pragma unroll
  for (int mi = 0; mi < 8; ++mi) {
#pragma unroll
    for (int j = 0; j < 4; ++j) {
      float v[5];
      float m = -3.0e38f;
#pragma unroll
      for (int ni = 0; ni < 5; ++ni) { v[ni] = acc[mi][ni][j] * al[ni] + be[ni]; m = fmaxf(m, v[ni]); }
#pragma unroll
      for (int off = 1; off < 16; off <<= 1) m = fmaxf(m, __shfl_xor(m, off, 64));
      float ssum = 0.f;
#pragma unroll
      for (int ni = 0; ni < 5; ++ni) { v[ni] = __expf(v[ni] - m); ssum += v[ni]; }
#pragma unroll
      for (int off = 1; off < 16; off <<= 1) ssum += __shfl_xor(ssum, off, 64);
      float inv = 1.f / ssum;
      int row = m0 + wm * 128 + mi * 16 + q * 4 + j;
      size_t rb = (size_t)row * NC_ + n0 + wn * 80 + r;
#pragma unroll
      for (int ni = 0; ni < 5; ++ni)
        Pb[rb + ni * 16] = f2bf(v[ni] * inv);
    }
  }
}

// ---------------- fallback score GEMM (fp32 A, reg-staged) ----------------
__global__ __launch_bounds__(256) void k_score_f32(
    const float* __restrict__ hs, const unsigned short* __restrict__ Mt,
    const float* __restrict__ alphav, const float* __restrict__ betav,
    unsigned short* __restrict__ P) {
  int id = blockIdx.x;
  int x = id & 7, idp = id >> 3;
  int n_t = idp & 7;
  int pid = (idp >> 3) * 8 + x;
  int b = pid >> 5, m_t = pid & 31;
  int m0 = m_t * 128, n0 = n_t * 160;
  const float* Af = hs + (size_t)b * LQ_ * D_;
  const unsigned short* Bb = Mt + (size_t)b * NC_ * D_;
  const float* alp = alphav + b * NC_;
  const float* bet = betav + b * NC_;
  unsigned short* Pb = P + (size_t)b * LQ_ * NC_;
  __shared__ short As[128 * 64];
  __shared__ short Bs[160 * 64];
  int t = threadIdx.x, lane = t & 63, wid = t >> 6;
  int wm = wid >> 1, wn = wid & 1;
  int srow = lane >> 3;
  int schunk = (lane & 7) ^ srow;
  f4 acc[4][5] = {};
  for (int k0 = 0; k0 < D_; k0 += 64) {
    __syncthreads();
    for (int i = wid; i < 20; i += 4)
      gload16(Bb + (size_t)(n0 + i * 8 + srow) * D_ + k0 + schunk * 8, (char*)Bs + i * 1024);
    int arow = t >> 3, ac = t & 7;
    int awc = ac ^ (arow & 7);
#pragma unroll
    for (int p = 0; p < 4; ++p) {
      int row = p * 32 + arow;
      const float* src = Af + (size_t)(m0 + row) * D_ + k0 + ac * 8;
      f4 v0 = *(const f4*)src;
      f4 v1 = *(const f4*)(src + 4);
      us8 u;
#pragma unroll
      for (int j = 0; j < 4; ++j) { u[j] = f2bf(v0[j]); u[4 + j] = f2bf(v1[j]); }
      *(us8*)(As + row * 64 + awc * 8) = u;
    }
    __syncthreads();
#pragma unroll
    for (int kk = 0; kk < 2; ++kk) {
      int co = ((kk * 4 + (lane >> 4)) ^ (lane & 7)) * 8;
      short8 fa[4], fb[5];
#pragma unroll
      for (int mi = 0; mi < 4; ++mi)
        fa[mi] = *(const short8*)(As + (wm * 64 + mi * 16 + (lane & 15)) * 64 + co);
#pragma unroll
      for (int ni = 0; ni < 5; ++ni)
        fb[ni] = *(const short8*)(Bs + (wn * 80 + ni * 16 + (lane & 15)) * 64 + co);
#pragma unroll
      for (int mi = 0; mi < 4; ++mi)
#pragma unroll
        for (int ni = 0; ni < 5; ++ni)
          acc[mi][ni] = __builtin_amdgcn_mfma_f32_16x16x32_bf16(fa[mi], fb[ni], acc[mi][ni], 0, 0, 0);
    }
  }
  float al[5], be[5];
#pragma unroll
  for (int ni = 0; ni < 5; ++ni) {
    int cc = n0 + wn * 80 + ni * 16 + (lane & 15);
    al[ni] = alp[cc]; be[ni] = bet[cc];
  }
#pragma unroll
  for (int mi = 0; mi < 4; ++mi) {
#pragma unroll
    for (int j = 0; j < 4; ++j) {
      float v[5];
      float m = -3.0e38f;
#pragma unroll
      for (int ni = 0; ni < 5; ++ni) { v[ni] = acc[mi][ni][j] * al[ni] + be[ni]; m = fmaxf(m, v[ni]); }
#pragma unroll
      for (int off = 1; off < 16; off <<= 1) m = fmaxf(m, __shfl_xor(m, off, 64));
      float ssum = 0.f;
#pragma unroll
      for (int ni = 0; ni < 5; ++ni) { v[ni] = __expf(v[ni] - m); ssum += v[ni]; }
#pragma unroll
      for (int off = 1; off < 16; off <<= 1) ssum += __shfl_xor(ssum, off, 64);
      float inv = 1.f / ssum;
      int row = m0 + wm * 64 + mi * 16 + (lane >> 4) * 4 + j;
      size_t rb = (size_t)row * NC_ + n0 + wn * 80 + (lane & 15);
#pragma unroll
      for (int ni = 0; ni < 5; ++ni)
        Pb[rb + ni * 16] = f2bf(v[ni] * inv);
    }
  }
}

// ---------------- out GEMM 256x256 (UNCHANGED from R11) ----------------
__global__ __launch_bounds__(512, 2) void k_out_big(
    const unsigned short* __restrict__ P, const unsigned short* __restrict__ Ut,
    const float* __restrict__ bo, float* __restrict__ out) {
  extern __shared__ short lds[];
  int id = blockIdx.x;
  int x = id & 7, idp = id >> 3;
  int nt = idp & 3;
  int pid = (idp >> 2) * 8 + x;
  int b = pid >> 4, mt = pid & 15;
  int m0 = mt * 256, n0 = nt * 256;

  const unsigned short* Ab = P + (size_t)b * LQ_ * NC_;
  const unsigned short* Bb = Ut + (size_t)b * D_ * NC_;
  float* ob = out + (size_t)b * LQ_ * D_;

  int t = threadIdx.x, lane = t & 63, wid = t >> 6;
  int wm = wid >> 2, wn = wid & 3;
  int r = lane & 15, q = lane >> 4;
  f4 acc[8][4] = {};
  const int T = NC_ / 32;   // 40

  auto SA = [&](int bf, int k0, int p) {
    int cb = p * 512 + wid * 64;
    int cc = cb + lane;
    int row = cc >> 2, gc = (cc & 3) ^ ((row >> 1) & 3);
    gload16(Ab + (size_t)(m0 + row) * NC_ + k0 + gc * 8, (char*)(lds + bf * 8192) + cb * 16);
  };
  auto SB = [&](int bf, int k0, int p) {
    int cb = p * 512 + wid * 64;
    int cc = cb + lane;
    int row = cc >> 2, gc = (cc & 3) ^ ((row >> 1) & 3);
    gload16(Bb + (size_t)(n0 + row) * NC_ + k0 + gc * 8, (char*)(lds + 32768 + bf * 8192) + cb * 16);
  };
  auto STAGE_P1 = [&](int h) { if (h < T) { int bf = h & 3, k0 = h * 32; SA(bf, k0, 0); SA(bf, k0, 1); } };
  auto STAGE_P2 = [&](int h) { if (h < T) { int bf = h & 3, k0 = h * 32; SB(bf, k0, 0); SB(bf, k0, 1); } };

  STAGE_P1(0); STAGE_P2(0);
  STAGE_P1(1); STAGE_P2(1);
  STAGE_P1(2); STAGE_P2(2);
  asm volatile("s_waitcnt vmcnt(8)" ::: "memory");
  __builtin_amdgcn_s_barrier();

#pragma unroll 1
  for (int h = 0; h < T; ++h) {
    int bf = h & 3;
    const short* Ar = lds + bf * 8192;
    const short* Br = lds + 32768 + bf * 8192;
    short8 fa[4], fb[4];

#pragma unroll
    for (int ni = 0; ni < 4; ++ni) {
      int row = wn * 64 + ni * 16 + r;
      fb[ni] = *(const short8*)(Br + row * 32 + ((q ^ ((row >> 1) & 3)) * 8));
    }
#pragma unroll
    for (int mi = 0; mi < 4; ++mi) {
      int row = wm * 128 + mi * 16 + r;
      fa[mi] = *(const short8*)(Ar + row * 32 + ((q ^ ((row >> 1) & 3)) * 8));
    }
    __builtin_amdgcn_sched_barrier(0);
    STAGE_P1(h + 3);
    __builtin_amdgcn_sched_barrier(0);
    __builtin_amdgcn_s_barrier();
    asm volatile("s_waitcnt lgkmcnt(0)");
    __builtin_amdgcn_s_setprio(1);
#pragma unroll
    for (int mi = 0; mi < 4; ++mi)
#pragma unroll
      for (int ni = 0; ni < 4; ++ni)
        acc[mi][ni] = __builtin_amdgcn_mfma_f32_16x16x32_bf16(fa[mi], fb[ni], acc[mi][ni], 0, 0, 0);
    __builtin_amdgcn_s_setprio(0);

#pragma unroll
    for (int mi = 0; mi < 4; ++mi) {
      int row = wm * 128 + (4 + mi) * 16 + r;
      fa[mi] = *(const short8*)(Ar + row * 32 + ((q ^ ((row >> 1) & 3)) * 8));
    }
    __builtin_amdgcn_sched_barrier(0);
    STAGE_P2(h + 3);
    __builtin_amdgcn_sched_barrier(0);
    __builtin_amdgcn_s_barrier();
    asm volatile("s_waitcnt lgkmcnt(0)");
    __builtin_amdgcn_s_setprio(1);
#pragma unroll
    for (int mi = 0; mi < 4; ++mi)
#pragma unroll
      for (int ni = 0; ni < 4; ++ni)
        acc[4 + mi][ni] = __builtin_amdgcn_mfma_f32_16x16x32_bf16(fa[mi], fb[ni], acc[4 + mi][ni], 0, 0, 0);
    __builtin_amdgcn_s_setprio(0);

    if (h <= T - 4) {
      asm volatile("s_waitcnt vmcnt(8)" ::: "memory");
    } else if (h == T - 3) {
      asm volatile("s_waitcnt vmcnt(4)" ::: "memory");
    } else if (h == T - 2) {
      asm volatile("s_waitcnt vmcnt(0)" ::: "memory");
    }
    if (h < T - 1) __builtin_amdgcn_s_barrier();
  }

#pragma unroll
  for (int ni = 0; ni < 4; ++ni) {
    int col = n0 + wn * 64 + ni * 16 + r;
    float bov = bo[col];
#pragma unroll
    for (int mi = 0; mi < 8; ++mi)
#pragma unroll
      for (int j = 0; j < 4; ++j) {
        int row = m0 + wm * 128 + mi * 16 + q * 4 + j;
        ob[(size_t)row * D_ + col] = acc[mi][ni][j] + bov;
      }
  }
}

extern "C" void kernel_launch(void* const* d_in, const int* in_sizes, int n_in,
                              void* d_out, int out_size, void* d_ws, size_t ws_size,
                              hipStream_t stream) {
  const float* hs  = (const float*)d_in[0];
  const float* ehs = (const float*)d_in[1];
  const float* Wq  = (const float*)d_in[2];
  const float* Wk  = (const float*)d_in[3];
  const float* Wv  = (const float*)d_in[4];
  const float* Wo  = (const float*)d_in[5];
  const float* bo  = (const float*)d_in[6];
  const float* Ak  = (const float*)d_in[7];
  const float* Bk  = (const float*)d_in[8];
  const float* Av  = (const float*)d_in[9];
  const float* Bv  = (const float*)d_in[10];
  const float* Ao  = (const float*)d_in[11];
  const float* Bo  = (const float*)d_in[12];
  const float* csf = (const float*)d_in[13];
  const int*   sb  = (const int*)d_in[14];
  const int*   sn  = (const int*)d_in[15];
  float* out = (float*)d_out;

  hipFuncSetAttribute(reinterpret_cast<const void*>(k_score_big),
                      hipFuncAttributeMaxDynamicSharedMemorySize, 147456);
  hipFuncSetAttribute(reinterpret_cast<const void*>(k_out_big),
                      hipFuncAttributeMaxDynamicSharedMemorySize, 131072);

  char* ws = (char*)d_ws;
  unsigned short* P  = (unsigned short*)ws;                   // 83,886,080
  unsigned short* Mt = (unsigned short*)(ws + 83886080);      // 20,971,520
  unsigned short* Ut = (unsigned short*)(ws + 104857600);     // 20,971,520
  const size_t NEED_HSB = 125829120ULL + 67108864ULL + 81920ULL; // 193,019,904
  bool useHsb = ws_size >= NEED_HSB;
  unsigned short* hsb = useHsb ? (unsigned short*)(ws + 125829120) : nullptr;
  char* tail = useHsb ? (ws + 192937984) : (ws + 125829120);
  float* alphav = (float*)tail;
  float* betav  = (float*)(tail + 40960);
  // temporaries overlapped into P's region (all dead before k_score writes P):
  unsigned short* kvb   = (unsigned short*)(ws + 0);          //  2,621,440
  unsigned short* wEb   = (unsigned short*)(ws + 2621440);    //  6,291,456
  unsigned short* wqTb  = (unsigned short*)(ws + 8912896);    //  2,097,152
  unsigned short* aTb   = (unsigned short*)(ws + 11010048);   //  1,179,648
  unsigned short* bxb   = (unsigned short*)(ws + 12189696);   //  1,179,648
  unsigned short* ehsb  = (unsigned short*)(ws + 13369344);   //  1,310,720
  float*          part  = (float*)(ws + 14680064);            //  2,097,152
  float*          hssum = (float*)(ws + 16777216);            //     32,768

  const float LS = 16.0f / 192.0f;

  // hs row-sums (deterministic two-stage) + bf16 conversion of hs
  k_hssum<<<dim3(64, 8), 256, 0, stream>>>(hs, part, hsb);
  k_hsred<<<32, 256, 0, stream>>>(part, hssum);

  // all conversions/transposes in one launch
  k_prep<<<dim3(32, 32, 8), 256, 0, stream>>>(Wq, Ak, Av, Ao, ehs, Bk, Bv, Bo,
                                              wqTb, aTb, ehsb, bxb);

  // W_eff (k,v,o) via proper bf16 GEMM
  k_weff_big<<<dim3(8, 8, 3), 256, 0, stream>>>(bxb, aTb, Wk, Wv, Wo, wEb, LS);

  // kv = ehsb @ wEb[k|v]^T  (bf16, 256 blocks)
  k_kv<<<256, 256, 0, stream>>>(ehsb, wEb, kvb);

  // Mt + Ut panels, one block per (b,h) each
  k_mtut<<<256, 512, 0, stream>>>(kvb, wqTb, wEb, Mt, Ut);

  // per-(b,h,s) column mean (qmean fused) + subject alpha/beta
  k_mubeta<<<dim3(16, 8), 128, 0, stream>>>(hssum, Wq, kvb, sb, sn, csf, alphav, betav);

  // big fused GEMMs (unchanged R11)
  if (useHsb)
    k_score_big<<<512, 512, 147456, stream>>>(hsb, Mt, alphav, betav, P);
  else
    k_score_f32<<<2048, 256, 0, stream>>>(hs, Mt, alphav, betav, P);
  k_out_big<<<512, 512, 131072, stream>>>(P, Ut, bo, out);

  (void)in_sizes; (void)n_in; (void)out_size; (void)ws_size;
}